// Round 2
// baseline (2016.667 us; speedup 1.0000x reference)
//
#include <hip/hip_runtime.h>
#include <math.h>

// MixedAttentionLayer — fp32 compute, bf16 staging. Footprint ~119 MB of d_ws.
// Pipeline:
//   small: qc/kc/vc (+T), Vca/Vcb, Wfa/Wfb/bfa/bfb, osc, A_sc
//   k_path1 (fused): qkv GEMM (qp/kp in LDS only) -> vp/ql/kl (bf16), E=exp(cac scores),
//                    occden, cap-softmax -> A_cp -> {w50, eden}
//   k_klsum, k_occnum(->atomic occraw), k_occfin, gated(A_cc)
//   k_kv: kv = kl^T@vp (split-K partials in E region), k_kvred
//   k_outs_conv: OS=(ql@kv)*zfac + dwconv5x5(vp)+b -> T (bf16, KL region)
//   k_selfgate: A_sp via T@Wfa/Wfb -> {h2t, h2den}
//   k_final: tiny MLPs -> out[512]

constexpr int DD = 256;
constexpr int MM = 50;
constexpr float SCL = 0.0625f; // 256^-0.5

// ---- byte offsets in d_ws ----
constexpr size_t B_VPH = 0;                      // 16,777,216 bf16 = 32 MiB
constexpr size_t B_QLH = (size_t)32 << 20;
constexpr size_t B_KLH = (size_t)64 << 20;       // later reused as T (bf16)
constexpr size_t B_E   = (size_t)96 << 20;       // 4,194,304 f32 = 16 MiB; later PKV
constexpr size_t B_SM  = (size_t)112 << 20;      // small fp32 region

// ---- float offsets within SM region ----
constexpr size_t KLSUM  = 0;          // 256  (zeroed)
constexpr size_t OCCDEN = 256;        // 64   (zeroed)
constexpr size_t W50    = 320;        // 64   (zeroed)
constexpr size_t EDENC  = 384;        // 8    (zeroed)
constexpr size_t H2T    = 392;        // 256  (zeroed)
constexpr size_t H2DEN  = 648;        // 8    (zeroed)
constexpr size_t OCCRAW = 656;        // 12800 (zeroed)
constexpr size_t ZEND   = 13456;
constexpr size_t QC     = 13456;      // 12800
constexpr size_t KC     = QC + 12800;
constexpr size_t VC     = KC + 12800;
constexpr size_t QCT    = VC + 12800;   // 16384
constexpr size_t KCT    = QCT + 16384;  // 16384
constexpr size_t VCA    = KCT + 16384;  // 12800
constexpr size_t VCB    = VCA + 12800;  // 12800
constexpr size_t WFA    = VCB + 12800;  // 65536
constexpr size_t WFB    = WFA + 65536;  // 65536
constexpr size_t BFA    = WFB + 65536;  // 256
constexpr size_t BFB    = BFA + 256;    // 256
constexpr size_t KVM    = BFB + 256;    // 65536
constexpr size_t OSCB   = KVM + 65536;  // 12800
constexpr size_t OCCB   = OSCB + 12800; // 12800
constexpr size_t ASC    = OCCB + 12800; // 64
constexpr size_t ACC50  = ASC + 64;     // 64
constexpr size_t SMEND  = ACC50 + 64;
constexpr size_t WS_NEEDED = B_SM + SMEND * sizeof(float);

__device__ __forceinline__ float sigmoidf_(float x){ return 1.0f / (1.0f + expf(-x)); }

__device__ __forceinline__ float bf2f(unsigned short u){
  return __uint_as_float(((unsigned int)u) << 16);
}
__device__ __forceinline__ unsigned short f2bf(float f){
  unsigned int x = __float_as_uint(f);
  unsigned int r = (x + 0x7fffu + ((x >> 16) & 1u)) >> 16;
  return (unsigned short)r;
}

__device__ __forceinline__ float waveAllSum(float v){
  #pragma unroll
  for (int m = 1; m < 64; m <<= 1) v += __shfl_xor(v, m, 64);
  return v;
}

// ---------- qc/kc/vc + transposes ----------
__global__ void __launch_bounds__(256) k_cqkv(const float* __restrict__ x, const float* __restrict__ Wqkv,
                                              float* qc, float* kc, float* vc, float* qcT, float* kcT){
  int r = blockIdx.x, j = threadIdx.x;
  __shared__ float xs[256];
  xs[j] = x[r * DD + j];
  __syncthreads();
  float aq = 0.f, ak = 0.f, av = 0.f;
  for (int k = 0; k < DD; k++) {
    float xv = xs[k];
    aq += xv * Wqkv[k * 768 + j];
    ak += xv * Wqkv[k * 768 + 256 + j];
    av += xv * Wqkv[k * 768 + 512 + j];
  }
  qc[r * DD + j] = aq; kc[r * DD + j] = ak; vc[r * DD + j] = av;
  qcT[j * 64 + r] = aq; kcT[j * 64 + r] = ak;
  if (r == 0) {
    for (int c = 50; c < 64; c++) { qcT[j * 64 + c] = 0.f; kcT[j * 64 + c] = 0.f; }
  }
}

// ---------- Vca = vc@Wa, Vcb = vc@Wb ----------
__global__ void __launch_bounds__(256) k_vcab(const float* vc, const float* Wa, const float* Wb,
                                              float* Vca, float* Vcb){
  int r = blockIdx.x, j = threadIdx.x;
  __shared__ float vs[256];
  vs[j] = vc[r * DD + j];
  __syncthreads();
  float a = 0.f, b = 0.f;
  for (int k = 0; k < DD; k++) { float v = vs[k]; a += v * Wa[k * DD + j]; b += v * Wb[k * DD + j]; }
  Vca[r * DD + j] = a; Vcb[r * DD + j] = b;
}

// ---------- Wfa = Wf@Wa, Wfb = Wf@Wb, bfa = bf@Wa+ba, bfb = bf@Wb+bb ----------
__global__ void __launch_bounds__(256) k_wfab(const float* Wf, const float* Wa, const float* Wb,
                                              const float* ba, const float* bb, const float* bf,
                                              float* Wfa, float* Wfb, float* bfa, float* bfb){
  int b = blockIdx.x, j = threadIdx.x;
  __shared__ float rs[256];
  const float* src; const float* Wm;
  if (b < 256)      { src = Wf + b * DD;         Wm = Wa; }
  else if (b < 512) { src = Wf + (b - 256) * DD; Wm = Wb; }
  else if (b == 512){ src = bf;                  Wm = Wa; }
  else              { src = bf;                  Wm = Wb; }
  rs[j] = src[j];
  __syncthreads();
  float a = 0.f;
  for (int k = 0; k < DD; k++) a += rs[k] * Wm[k * DD + j];
  if (b < 256) Wfa[b * DD + j] = a;
  else if (b < 512) Wfb[(b - 256) * DD + j] = a;
  else if (b == 512) bfa[j] = a + ba[j];
  else bfb[j] = a + bb[j];
}

// ---------- osc = softmax(scale*qc@kc^T)@vc ----------
__global__ void __launch_bounds__(256) k_osc(const float* qc, const float* kc, const float* vc, float* osc){
  __shared__ float S[50][64];
  __shared__ float P[50][64];
  int t = threadIdx.x;
  for (int p = t; p < 2500; p += 256) {
    int i = p / 50, jj = p % 50;
    float s = 0.f;
    for (int k = 0; k < DD; k++) s += qc[i * DD + k] * kc[jj * DD + k];
    S[i][jj] = s * SCL;
  }
  __syncthreads();
  if (t < 50) {
    float mx = -1e30f;
    for (int jj = 0; jj < 50; jj++) mx = fmaxf(mx, S[t][jj]);
    float den = 0.f;
    for (int jj = 0; jj < 50; jj++) { float e = expf(S[t][jj] - mx); P[t][jj] = e; den += e; }
    float inv = 1.0f / den;
    for (int jj = 0; jj < 50; jj++) P[t][jj] *= inv;
  }
  __syncthreads();
  for (int i = 0; i < 50; i++) {
    float a = 0.f;
    for (int jj = 0; jj < 50; jj++) a += P[i][jj] * vc[jj * DD + t];
    osc[i * DD + t] = a;
  }
}

// ---------- gated() on a 50-row fp32 input -> A[50] ----------
__global__ void __launch_bounds__(256) k_gated(const float* __restrict__ tin,
                                               const float* __restrict__ Wa, const float* __restrict__ Wb,
                                               const float* __restrict__ ba, const float* __restrict__ bb,
                                               const float* __restrict__ Wc, const float* __restrict__ bc,
                                               float* __restrict__ A){
  int r = blockIdx.x, j = threadIdx.x;
  __shared__ float ts[256];
  __shared__ float red[4];
  ts[j] = tin[r * DD + j];
  __syncthreads();
  float u = 0.f, v = 0.f;
  for (int k = 0; k < DD; k++) { float tv = ts[k]; u += tv * Wa[k * DD + j]; v += tv * Wb[k * DD + j]; }
  float g = tanhf(u + ba[j]) * sigmoidf_(v + bb[j]) * Wc[j];
  g = waveAllSum(g);
  int lane = j & 63, wv = j >> 6;
  if (lane == 0) red[wv] = g;
  __syncthreads();
  if (j == 0) A[r] = red[0] + red[1] + red[2] + red[3] + bc[0];
}

// ---------- fused path kernel: qkv GEMM + linear transforms + E + cap gate ----------
__global__ void __launch_bounds__(256) k_path1(
    const float* __restrict__ x, const float* __restrict__ Wqkv,
    const float* __restrict__ sln, const float* __restrict__ kcT, const float* __restrict__ qcT,
    const float* __restrict__ Vca, const float* __restrict__ Vcb,
    const float* __restrict__ ba, const float* __restrict__ bb,
    const float* __restrict__ Wc, const float* __restrict__ bc,
    unsigned short* __restrict__ vph, unsigned short* __restrict__ qlh, unsigned short* __restrict__ klh,
    float* __restrict__ E, float* __restrict__ w50, float* __restrict__ edencp, float* __restrict__ occden){
  __shared__ float xs[16][256];
  __shared__ float qps[16][256];
  __shared__ float kps[16][256];
  __shared__ float w50s[64];
  __shared__ float occs[64];
  __shared__ float edens;
  const int tid = threadIdx.x;
  const int i0 = blockIdx.x * 16;

  if (tid < 64) { w50s[tid] = 0.f; occs[tid] = 0.f; }
  if (tid == 0) edens = 0.f;
  for (int l = tid; l < 4096; l += 256) {
    int r = l >> 8, c = l & 255;
    xs[r][c] = x[(size_t)(MM + i0 + r) * DD + c];
  }
  __syncthreads();

  // ---- phase A: thread j = one column of q,k,v for 16 rows ----
  {
    const int j = tid;
    float accq[16], acck[16], accv[16];
    #pragma unroll
    for (int r = 0; r < 16; r++) { accq[r] = 0.f; acck[r] = 0.f; accv[r] = 0.f; }
    for (int k0 = 0; k0 < 256; k0 += 4) {
      float wq[4], wk[4], wv_[4];
      #pragma unroll
      for (int kk = 0; kk < 4; kk++) {
        const float* wp = Wqkv + (size_t)(k0 + kk) * 768;
        wq[kk] = wp[j]; wk[kk] = wp[256 + j]; wv_[kk] = wp[512 + j];
      }
      #pragma unroll
      for (int r = 0; r < 16; r++) {
        float4 xr = *(const float4*)&xs[r][k0];
        accq[r] += xr.x * wq[0] + xr.y * wq[1] + xr.z * wq[2] + xr.w * wq[3];
        acck[r] += xr.x * wk[0] + xr.y * wk[1] + xr.z * wk[2] + xr.w * wk[3];
        accv[r] += xr.x * wv_[0] + xr.y * wv_[1] + xr.z * wv_[2] + xr.w * wv_[3];
      }
    }
    #pragma unroll
    for (int r = 0; r < 16; r++) {
      qps[r][j] = accq[r];
      kps[r][j] = acck[r];
      vph[(size_t)(i0 + r) * DD + j] = f2bf(accv[r]);
    }
  }
  __syncthreads();

  // ---- phase B: wave handles 4 rows ----
  const int lane = tid & 63;
  const int wvv = tid >> 6;
  float4 sl4 = ((const float4*)sln)[lane];
  float4 rsp;
  rsp.x = 1.0f / log1pf(expf(sl4.x)); rsp.y = 1.0f / log1pf(expf(sl4.y));
  rsp.z = 1.0f / log1pf(expf(sl4.z)); rsp.w = 1.0f / log1pf(expf(sl4.w));
  float4 ba4 = ((const float4*)ba)[lane];
  float4 bb4 = ((const float4*)bb)[lane];
  float4 wc4 = ((const float4*)Wc)[lane];
  float bcv = bc[0];

  float p[4];
  float occacc = 0.f;
  for (int rr = 0; rr < 4; rr++) {
    const int r = wvv * 4 + rr;
    const int row = i0 + r;
    float4 q4 = *(const float4*)&qps[r][lane * 4];
    float4 k4 = *(const float4*)&kps[r][lane * 4];
    float4 lq, lk;
    lq.x = (fmaxf(q4.x, 0.f) + 1e-6f) * rsp.x; lq.y = (fmaxf(q4.y, 0.f) + 1e-6f) * rsp.y;
    lq.z = (fmaxf(q4.z, 0.f) + 1e-6f) * rsp.z; lq.w = (fmaxf(q4.w, 0.f) + 1e-6f) * rsp.w;
    lk.x = (fmaxf(k4.x, 0.f) + 1e-6f) * rsp.x; lk.y = (fmaxf(k4.y, 0.f) + 1e-6f) * rsp.y;
    lk.z = (fmaxf(k4.z, 0.f) + 1e-6f) * rsp.z; lk.w = (fmaxf(k4.w, 0.f) + 1e-6f) * rsp.w;
    float4 q3, k3;
    q3.x = lq.x*lq.x*lq.x; q3.y = lq.y*lq.y*lq.y; q3.z = lq.z*lq.z*lq.z; q3.w = lq.w*lq.w*lq.w;
    k3.x = lk.x*lk.x*lk.x; k3.y = lk.y*lk.y*lk.y; k3.z = lk.z*lk.z*lk.z; k3.w = lk.w*lk.w*lk.w;
    float n1q = lq.x*lq.x + lq.y*lq.y + lq.z*lq.z + lq.w*lq.w;
    float n3q = q3.x*q3.x + q3.y*q3.y + q3.z*q3.z + q3.w*q3.w;
    float n1k = lk.x*lk.x + lk.y*lk.y + lk.z*lk.z + lk.w*lk.w;
    float n3k = k3.x*k3.x + k3.y*k3.y + k3.z*k3.z + k3.w*k3.w;
    n1q = waveAllSum(n1q); n3q = waveAllSum(n3q);
    n1k = waveAllSum(n1k); n3k = waveAllSum(n3k);
    float fq = sqrtf(n1q / n3q);
    float fk = sqrtf(n1k / n3k);
    ushort4 qo, ko;
    qo.x = f2bf(q3.x * fq); qo.y = f2bf(q3.y * fq); qo.z = f2bf(q3.z * fq); qo.w = f2bf(q3.w * fq);
    ko.x = f2bf(k3.x * fk); ko.y = f2bf(k3.y * fk); ko.z = f2bf(k3.z * fk); ko.w = f2bf(k3.w * fk);
    *(ushort4*)&qlh[(size_t)row * DD + lane * 4] = qo;
    *(ushort4*)&klh[(size_t)row * DD + lane * 4] = ko;
    // scores: cap (qp vs kc), cac (kp vs qc); lane = celltype index
    float scap = 0.f, scac = 0.f;
    for (int d0 = 0; d0 < 256; d0 += 4) {
      float4 qd = *(const float4*)&qps[r][d0];
      float4 kd = *(const float4*)&kps[r][d0];
      scap += qd.x * kcT[(d0+0)*64 + lane] + qd.y * kcT[(d0+1)*64 + lane]
            + qd.z * kcT[(d0+2)*64 + lane] + qd.w * kcT[(d0+3)*64 + lane];
      scac += kd.x * qcT[(d0+0)*64 + lane] + kd.y * qcT[(d0+1)*64 + lane]
            + kd.z * qcT[(d0+2)*64 + lane] + kd.w * qcT[(d0+3)*64 + lane];
    }
    float ecap = (lane < 50) ? expf(scap * SCL) : 0.f;
    float ecac = (lane < 50) ? expf(scac * SCL) : 0.f;
    E[(size_t)row * 64 + lane] = ecac;
    occacc += ecac;
    float den = waveAllSum(ecap);
    p[rr] = ecap / den;
  }
  // gate for 4 rows together (amortizes Vca/Vcb reads)
  float4 u[4], vv[4];
  #pragma unroll
  for (int r = 0; r < 4; r++) { u[r] = ba4; vv[r] = bb4; }
  for (int i = 0; i < 50; i++) {
    float4 va = ((const float4*)(Vca + i * DD))[lane];
    float4 vb = ((const float4*)(Vcb + i * DD))[lane];
    #pragma unroll
    for (int r = 0; r < 4; r++) {
      float pi = __shfl(p[r], i, 64);
      u[r].x += pi * va.x; u[r].y += pi * va.y; u[r].z += pi * va.z; u[r].w += pi * va.w;
      vv[r].x += pi * vb.x; vv[r].y += pi * vb.y; vv[r].z += pi * vb.z; vv[r].w += pi * vb.w;
    }
  }
  float w50acc = 0.f, ewacc = 0.f;
  #pragma unroll
  for (int r = 0; r < 4; r++) {
    float g = tanhf(u[r].x) * sigmoidf_(vv[r].x) * wc4.x
            + tanhf(u[r].y) * sigmoidf_(vv[r].y) * wc4.y
            + tanhf(u[r].z) * sigmoidf_(vv[r].z) * wc4.z
            + tanhf(u[r].w) * sigmoidf_(vv[r].w) * wc4.w;
    g = waveAllSum(g);
    float ew = expf(g + bcv);
    w50acc += ew * p[r];
    if (lane == 0) ewacc += ew;
  }
  atomicAdd(&w50s[lane], w50acc);
  atomicAdd(&occs[lane], occacc);
  if (lane == 0) atomicAdd(&edens, ewacc);
  __syncthreads();
  if (tid < 50) { atomicAdd(&w50[tid], w50s[tid]); atomicAdd(&occden[tid], occs[tid]); }
  if (tid == 0) atomicAdd(edencp, edens);
}

// ---------- klsum ----------
__global__ void __launch_bounds__(256) k_klsum(const unsigned short* __restrict__ klh, float* __restrict__ klsum){
  int d = threadIdx.x;
  float s = 0.f;
  size_t j0 = (size_t)blockIdx.x * 1024;
  for (int j = 0; j < 1024; j++) s += bf2f(klh[(j0 + j) * DD + d]);
  atomicAdd(&klsum[d], s);
}

// ---------- occ numerator: atomic accumulate sum_j E[j][i]*vp[j][d] ----------
__global__ void __launch_bounds__(256) k_occnum(const float* __restrict__ E, const unsigned short* __restrict__ vph,
                                                float* __restrict__ occraw){
  int d = threadIdx.x;
  int j0 = blockIdx.x * 512;
  __shared__ float Es[32][64];
  float acc[52];
  #pragma unroll
  for (int i = 0; i < 52; i++) acc[i] = 0.f;
  for (int s = 0; s < 16; s++) {
    for (int l = threadIdx.x; l < 512; l += 256) {
      int jj = l >> 4, cq = l & 15;
      *(float4*)&Es[jj][cq * 4] = ((const float4*)(E + (size_t)(j0 + s * 32 + jj) * 64))[cq];
    }
    __syncthreads();
    for (int jj = 0; jj < 32; jj++) {
      float vv = bf2f(vph[(size_t)(j0 + s * 32 + jj) * DD + d]);
      #pragma unroll
      for (int q = 0; q < 13; q++) {
        float4 e4 = *(const float4*)&Es[jj][q * 4];
        acc[q * 4 + 0] += e4.x * vv; acc[q * 4 + 1] += e4.y * vv;
        acc[q * 4 + 2] += e4.z * vv; acc[q * 4 + 3] += e4.w * vv;
      }
    }
    __syncthreads();
  }
  for (int i = 0; i < 50; i++) atomicAdd(&occraw[i * DD + d], acc[i]);
}

__global__ void __launch_bounds__(256) k_occfin(const float* __restrict__ occraw, const float* __restrict__ occden,
                                                float* __restrict__ occ){
  int i = blockIdx.x, d = threadIdx.x;
  occ[i * DD + d] = occraw[i * DD + d] / occden[i];
}

// ---------- kv = kl^T @ vp (split-K partials into E region) ----------
__global__ void __launch_bounds__(256) k_kv(const unsigned short* __restrict__ klh,
                                            const unsigned short* __restrict__ vph,
                                            float* __restrict__ PKVp){
  __shared__ float As[16][132];
  __shared__ float Bs[16][132];
  int tid = threadIdx.x;
  int ct = blockIdx.x, dt = blockIdx.y, kc_ = blockIdx.z;
  float acc[8][8];
  #pragma unroll
  for (int p = 0; p < 8; p++)
    #pragma unroll
    for (int q = 0; q < 8; q++) acc[p][q] = 0.f;
  int ty = tid >> 4, tx = tid & 15;
  for (int j0 = kc_ * 1024; j0 < kc_ * 1024 + 1024; j0 += 16) {
    for (int l = tid; l < 512; l += 256) {
      int jj = l >> 5, cq = l & 31;
      ushort4 a4 = *(const ushort4*)&klh[(size_t)(j0 + jj) * DD + ct * 128 + cq * 4];
      ushort4 b4 = *(const ushort4*)&vph[(size_t)(j0 + jj) * DD + dt * 128 + cq * 4];
      As[jj][cq*4+0] = bf2f(a4.x); As[jj][cq*4+1] = bf2f(a4.y);
      As[jj][cq*4+2] = bf2f(a4.z); As[jj][cq*4+3] = bf2f(a4.w);
      Bs[jj][cq*4+0] = bf2f(b4.x); Bs[jj][cq*4+1] = bf2f(b4.y);
      Bs[jj][cq*4+2] = bf2f(b4.z); Bs[jj][cq*4+3] = bf2f(b4.w);
    }
    __syncthreads();
    #pragma unroll
    for (int jj = 0; jj < 16; jj++) {
      float4 a0 = *(const float4*)&As[jj][ty * 8];
      float4 a1 = *(const float4*)&As[jj][ty * 8 + 4];
      float4 b0 = *(const float4*)&Bs[jj][tx * 8];
      float4 b1 = *(const float4*)&Bs[jj][tx * 8 + 4];
      float av[8] = {a0.x,a0.y,a0.z,a0.w,a1.x,a1.y,a1.z,a1.w};
      float bv[8] = {b0.x,b0.y,b0.z,b0.w,b1.x,b1.y,b1.z,b1.w};
      #pragma unroll
      for (int p = 0; p < 8; p++)
        #pragma unroll
        for (int q = 0; q < 8; q++) acc[p][q] += av[p] * bv[q];
    }
    __syncthreads();
  }
  float* P = PKVp + (size_t)((kc_ * 2 + ct) * 2 + dt) * 16384;
  #pragma unroll
  for (int p = 0; p < 8; p++) {
    float4 s0 = {acc[p][0], acc[p][1], acc[p][2], acc[p][3]};
    float4 s1 = {acc[p][4], acc[p][5], acc[p][6], acc[p][7]};
    *(float4*)&P[(ty * 8 + p) * 128 + tx * 8] = s0;
    *(float4*)&P[(ty * 8 + p) * 128 + tx * 8 + 4] = s1;
  }
}

__global__ void __launch_bounds__(256) k_kvred(const float* __restrict__ PKVp, float* __restrict__ kv){
  int c = blockIdx.x, d = threadIdx.x;
  int ct = c >> 7, dt = d >> 7, cl = c & 127, dl = d & 127;
  float s = 0.f;
  for (int kc = 0; kc < 64; kc++)
    s += PKVp[(size_t)((kc * 2 + ct) * 2 + dt) * 16384 + cl * 128 + dl];
  kv[c * DD + d] = s;
}

// ---------- fused: OS=(ql@kv)*zfac, + dwconv(vp)+bias -> T (bf16) ----------
__global__ void __launch_bounds__(256) k_outs_conv(const unsigned short* __restrict__ qlh,
                                                   const float* __restrict__ kv, const float* __restrict__ klsum,
                                                   const unsigned short* __restrict__ vph,
                                                   const float* __restrict__ dwcw, const float* __restrict__ dwcb,
                                                   unsigned short* __restrict__ th){
  __shared__ float qls[16][256];
  __shared__ float red[4][16];
  __shared__ float zf[16];
  const int tid = threadIdx.x;
  const int i0 = blockIdx.x * 16;
  for (int l = tid; l < 1024; l += 256) {
    int r = l >> 6, c4 = (l & 63) * 4;
    ushort4 q4 = *(const ushort4*)&qlh[(size_t)(i0 + r) * DD + c4];
    qls[r][c4+0] = bf2f(q4.x); qls[r][c4+1] = bf2f(q4.y);
    qls[r][c4+2] = bf2f(q4.z); qls[r][c4+3] = bf2f(q4.w);
  }
  __syncthreads();
  const int j = tid;
  float acc[16];
  #pragma unroll
  for (int r = 0; r < 16; r++) acc[r] = 0.f;
  for (int k0 = 0; k0 < 256; k0 += 4) {
    float kv0 = kv[(k0+0) * DD + j], kv1 = kv[(k0+1) * DD + j];
    float kv2 = kv[(k0+2) * DD + j], kv3 = kv[(k0+3) * DD + j];
    #pragma unroll
    for (int r = 0; r < 16; r++) {
      float4 q4 = *(const float4*)&qls[r][k0];
      acc[r] += q4.x * kv0 + q4.y * kv1 + q4.z * kv2 + q4.w * kv3;
    }
  }
  // zfac per row
  const int lane = tid & 63, wvv = tid >> 6;
  float ks = klsum[j];
  #pragma unroll
  for (int r = 0; r < 16; r++) {
    float t = qls[r][j] * ks;
    t = waveAllSum(t);
    if (lane == 0) red[wvv][r] = t;
  }
  __syncthreads();
  if (tid < 16) {
    float t = red[0][tid] + red[1][tid] + red[2][tid] + red[3][tid];
    zf[tid] = 1.0f / (t + 1e-6f);
  }
  __syncthreads();
  // conv + write T
  float w[25];
  #pragma unroll
  for (int t = 0; t < 25; t++) w[t] = dwcw[j * 25 + t];
  float bias = dwcb[j];
  const int y = i0 >> 8, x0 = i0 & 255;
  for (int r = 0; r < 16; r++) {
    int xx0 = x0 + r;
    float fm = bias;
    #pragma unroll
    for (int dy = -2; dy <= 2; dy++) {
      int yy = y + dy;
      if ((unsigned)yy > 255u) continue;
      #pragma unroll
      for (int dx = -2; dx <= 2; dx++) {
        int xx = xx0 + dx;
        if ((unsigned)xx > 255u) continue;
        fm += bf2f(vph[(size_t)((yy << 8) + xx) * DD + j]) * w[(dy + 2) * 5 + (dx + 2)];
      }
    }
    float T = acc[r] * zf[r] + fm;
    th[(size_t)(i0 + r) * DD + j] = f2bf(T);
  }
}

// ---------- self-path gate + h2 accumulation ----------
__global__ void __launch_bounds__(256) k_selfgate(const unsigned short* __restrict__ th,
                                                  const float* __restrict__ Wfa, const float* __restrict__ Wfb,
                                                  const float* __restrict__ bfa, const float* __restrict__ bfb,
                                                  const float* __restrict__ Wc, const float* __restrict__ bc,
                                                  float* __restrict__ h2t, float* __restrict__ h2den){
  __shared__ float ts[16][256];
  __shared__ float red[4][16];
  __shared__ float ev[16];
  const int tid = threadIdx.x;
  const int i0 = blockIdx.x * 16;
  for (int l = tid; l < 1024; l += 256) {
    int r = l >> 6, c4 = (l & 63) * 4;
    ushort4 t4 = *(const ushort4*)&th[(size_t)(i0 + r) * DD + c4];
    ts[r][c4+0] = bf2f(t4.x); ts[r][c4+1] = bf2f(t4.y);
    ts[r][c4+2] = bf2f(t4.z); ts[r][c4+3] = bf2f(t4.w);
  }
  __syncthreads();
  const int j = tid;
  float aU[16], aV[16];
  #pragma unroll
  for (int r = 0; r < 16; r++) { aU[r] = 0.f; aV[r] = 0.f; }
  for (int k0 = 0; k0 < 256; k0 += 4) {
    float wa0 = Wfa[(k0+0) * DD + j], wa1 = Wfa[(k0+1) * DD + j];
    float wa2 = Wfa[(k0+2) * DD + j], wa3 = Wfa[(k0+3) * DD + j];
    float wb0 = Wfb[(k0+0) * DD + j], wb1 = Wfb[(k0+1) * DD + j];
    float wb2 = Wfb[(k0+2) * DD + j], wb3 = Wfb[(k0+3) * DD + j];
    #pragma unroll
    for (int r = 0; r < 16; r++) {
      float4 t4 = *(const float4*)&ts[r][k0];
      aU[r] += t4.x * wa0 + t4.y * wa1 + t4.z * wa2 + t4.w * wa3;
      aV[r] += t4.x * wb0 + t4.y * wb1 + t4.z * wb2 + t4.w * wb3;
    }
  }
  float bfaj = bfa[j], bfbj = bfb[j], wcj = Wc[j];
  const int lane = tid & 63, wvv = tid >> 6;
  #pragma unroll
  for (int r = 0; r < 16; r++) {
    float g = tanhf(aU[r] + bfaj) * sigmoidf_(aV[r] + bfbj) * wcj;
    g = waveAllSum(g);
    if (lane == 0) red[wvv][r] = g;
  }
  __syncthreads();
  if (tid < 16) {
    float A = red[0][tid] + red[1][tid] + red[2][tid] + red[3][tid] + bc[0];
    ev[tid] = expf(A);
  }
  __syncthreads();
  float hp = 0.f;
  #pragma unroll
  for (int r = 0; r < 16; r++) hp += ev[r] * ts[r][j];
  atomicAdd(&h2t[j], hp);
  if (tid == 0) {
    float es = 0.f;
    for (int r = 0; r < 16; r++) es += ev[r];
    atomicAdd(h2den, es);
  }
}

// ---------- final tiny MLPs ----------
__global__ void __launch_bounds__(256) k_final(
    const float* __restrict__ A_cc, const float* __restrict__ occ,
    const float* __restrict__ A_sc, const float* __restrict__ osc,
    const float* __restrict__ w50, const float* __restrict__ edencp,
    const float* __restrict__ h2t, const float* __restrict__ h2den,
    const float* __restrict__ vc, const float* __restrict__ Wf, const float* __restrict__ bf,
    const float* __restrict__ W1, const float* __restrict__ b1,
    const float* __restrict__ W2, const float* __restrict__ b2,
    const float* __restrict__ W3a, const float* __restrict__ b3a,
    const float* __restrict__ W3b, const float* __restrict__ b3b,
    float* __restrict__ out){
  int j = threadIdx.x;
  __shared__ float pw[64];
  __shared__ float t1[256], t2[256], h1[256], h2[256], fz[512], z1[256];
  // ===== CROSS =====
  if (j < 64) pw[j] = (j < 50) ? expf(A_cc[j]) : 0.f;
  __syncthreads();
  float den = 0.f;
  for (int i = 0; i < 50; i++) den += pw[i];
  float raw = 0.f;
  for (int i = 0; i < 50; i++) raw += pw[i] * occ[i * DD + j];
  t1[j] = raw / den;
  float r2 = 0.f;
  for (int i = 0; i < 50; i++) r2 += w50[i] * vc[i * DD + j];
  t2[j] = r2 / edencp[0];
  __syncthreads();
  float a1 = 0.f, a2 = 0.f;
  for (int k = 0; k < DD; k++) { a1 += t1[k] * W1[k * DD + j]; a2 += t2[k] * W2[k * DD + j]; }
  h1[j] = fmaxf(a1 + b1[j], 0.f);
  h2[j] = fmaxf(a2 + b2[j], 0.f);
  __syncthreads();
  fz[j] = h1[j]; fz[256 + j] = h2[j];
  __syncthreads();
  float z = 0.f;
  for (int k = 0; k < 512; k++) z += fz[k] * W3a[k * DD + j];
  z1[j] = fmaxf(z + b3a[j], 0.f);
  __syncthreads();
  float o = 0.f;
  for (int k = 0; k < DD; k++) o += z1[k] * W3b[k * DD + j];
  out[j] = fmaxf(o + b3b[j], 0.f);
  __syncthreads();
  // ===== SELF =====
  if (j < 64) pw[j] = (j < 50) ? expf(A_sc[j]) : 0.f;
  __syncthreads();
  den = 0.f;
  for (int i = 0; i < 50; i++) den += pw[i];
  raw = 0.f;
  for (int i = 0; i < 50; i++) raw += pw[i] * osc[i * DD + j];
  t1[j] = raw / den;
  t2[j] = h2t[j] / h2den[0];
  __syncthreads();
  float hs = 0.f;
  for (int k = 0; k < DD; k++) hs += t2[k] * Wf[k * DD + j];
  __syncthreads();
  t2[j] = hs + bf[j];
  __syncthreads();
  a1 = 0.f; a2 = 0.f;
  for (int k = 0; k < DD; k++) { a1 += t1[k] * W1[k * DD + j]; a2 += t2[k] * W2[k * DD + j]; }
  h1[j] = fmaxf(a1 + b1[j], 0.f);
  h2[j] = fmaxf(a2 + b2[j], 0.f);
  __syncthreads();
  fz[j] = h1[j]; fz[256 + j] = h2[j];
  __syncthreads();
  z = 0.f;
  for (int k = 0; k < 512; k++) z += fz[k] * W3a[k * DD + j];
  z1[j] = fmaxf(z + b3a[j], 0.f);
  __syncthreads();
  o = 0.f;
  for (int k = 0; k < DD; k++) o += z1[k] * W3b[k * DD + j];
  out[256 + j] = fmaxf(o + b3b[j], 0.f);
}

extern "C" void kernel_launch(void* const* d_in, const int* in_sizes, int n_in,
                              void* d_out, int out_size, void* d_ws, size_t ws_size,
                              hipStream_t stream) {
  if (ws_size < WS_NEEDED) return;  // diagnostic guard: clean absmax-fail instead of page fault
  const float* x   = (const float*)d_in[0];
  const float* Wqkv= (const float*)d_in[1];
  const float* sln = (const float*)d_in[2];
  const float* dwcw= (const float*)d_in[3];
  const float* dwcb= (const float*)d_in[4];
  const float* Wa  = (const float*)d_in[5];
  const float* ba  = (const float*)d_in[6];
  const float* Wb  = (const float*)d_in[7];
  const float* bb  = (const float*)d_in[8];
  const float* Wc  = (const float*)d_in[9];
  const float* bc  = (const float*)d_in[10];
  const float* W1  = (const float*)d_in[11];
  const float* b1  = (const float*)d_in[12];
  const float* W2  = (const float*)d_in[13];
  const float* b2  = (const float*)d_in[14];
  const float* W3a = (const float*)d_in[15];
  const float* b3a = (const float*)d_in[16];
  const float* W3b = (const float*)d_in[17];
  const float* b3b = (const float*)d_in[18];
  const float* Wf  = (const float*)d_in[19];
  const float* bf  = (const float*)d_in[20];

  char* wsb = (char*)d_ws;
  unsigned short* VPH = (unsigned short*)(wsb + B_VPH);
  unsigned short* QLH = (unsigned short*)(wsb + B_QLH);
  unsigned short* KLH = (unsigned short*)(wsb + B_KLH);   // also T
  float* EB = (float*)(wsb + B_E);                        // also PKV
  float* SM = (float*)(wsb + B_SM);
  float* outp = (float*)d_out;

  hipMemsetAsync((void*)SM, 0, ZEND * sizeof(float), stream);

  k_cqkv<<<50, 256, 0, stream>>>(x, Wqkv, SM + QC, SM + KC, SM + VC, SM + QCT, SM + KCT);
  k_vcab<<<50, 256, 0, stream>>>(SM + VC, Wa, Wb, SM + VCA, SM + VCB);
  k_wfab<<<514, 256, 0, stream>>>(Wf, Wa, Wb, ba, bb, bf, SM + WFA, SM + WFB, SM + BFA, SM + BFB);
  k_osc<<<1, 256, 0, stream>>>(SM + QC, SM + KC, SM + VC, SM + OSCB);
  k_gated<<<50, 256, 0, stream>>>(SM + OSCB, Wa, Wb, ba, bb, Wc, bc, SM + ASC);

  k_path1<<<4096, 256, 0, stream>>>(x, Wqkv, sln, SM + KCT, SM + QCT, SM + VCA, SM + VCB,
                                    ba, bb, Wc, bc, VPH, QLH, KLH,
                                    EB, SM + W50, SM + EDENC, SM + OCCDEN);
  k_klsum<<<64, 256, 0, stream>>>(KLH, SM + KLSUM);
  k_occnum<<<128, 256, 0, stream>>>(EB, VPH, SM + OCCRAW);
  k_occfin<<<50, 256, 0, stream>>>(SM + OCCRAW, SM + OCCDEN, SM + OCCB);
  k_gated<<<50, 256, 0, stream>>>(SM + OCCB, Wa, Wb, ba, bb, Wc, bc, SM + ACC50);

  k_kv<<<dim3(2, 2, 64), 256, 0, stream>>>(KLH, VPH, EB);   // PKV into E region (E dead)
  k_kvred<<<256, 256, 0, stream>>>(EB, SM + KVM);

  k_outs_conv<<<4096, 256, 0, stream>>>(QLH, SM + KVM, SM + KLSUM, VPH, dwcw, dwcb, KLH); // T -> KLH
  k_selfgate<<<4096, 256, 0, stream>>>(KLH, SM + WFA, SM + WFB, SM + BFA, SM + BFB,
                                       Wc, bc, SM + H2T, SM + H2DEN);

  k_final<<<1, 256, 0, stream>>>(SM + ACC50, SM + OCCB, SM + ASC, SM + OSCB,
                                 SM + W50, SM + EDENC, SM + H2T, SM + H2DEN,
                                 SM + VC, Wf, bf, W1, b1, W2, b2, W3a, b3a, W3b, b3b, outp);
}

// Round 3
// 1435.477 us; speedup vs baseline: 1.4049x; 1.4049x over previous
//
#include <hip/hip_runtime.h>
#include <math.h>

// MixedAttentionLayer — MFMA bf16 for the 4 big GEMMs, fp32 elsewhere.
// R2 baseline: 2017us, k_path1 827us @ MfmaUtil=0. This round: qkv GEMM,
// cap/cac scores, T@Wfa/Wfb, ql@kv all on v_mfma_f32_16x16x32_bf16.

constexpr int DD = 256;
constexpr int MM = 50;
constexpr float SCL = 0.0625f; // 256^-0.5

// ---- byte offsets in d_ws ----
constexpr size_t B_VPH = 0;                      // 32 MiB bf16 vp
constexpr size_t B_QLH = (size_t)32 << 20;       // 32 MiB bf16 ql
constexpr size_t B_KLH = (size_t)64 << 20;       // 32 MiB bf16 kl, later T
constexpr size_t B_E   = (size_t)96 << 20;       // 16 MiB f32 E; later PKV
constexpr size_t B_SM  = (size_t)112 << 20;      // small fp32 region
constexpr size_t B_X   = B_SM + ((size_t)2 << 20); // bf16 prep region

// ---- float offsets within SM region ----
constexpr size_t KLSUM  = 0;
constexpr size_t OCCDEN = 256;
constexpr size_t W50    = 320;
constexpr size_t EDENC  = 384;
constexpr size_t H2T    = 392;
constexpr size_t H2DEN  = 648;
constexpr size_t OCCRAW = 656;
constexpr size_t ZEND   = 13456;
constexpr size_t QC     = 13456;
constexpr size_t KC     = QC + 12800;
constexpr size_t VC     = KC + 12800;
constexpr size_t VCA    = VC + 12800;
constexpr size_t VCB    = VCA + 12800;
constexpr size_t WFA    = VCB + 12800;
constexpr size_t WFB    = WFA + 65536;
constexpr size_t BFA    = WFB + 65536;
constexpr size_t BFB    = BFA + 256;
constexpr size_t KVM    = BFB + 256;
constexpr size_t OSCB   = KVM + 65536;
constexpr size_t OCCB   = OSCB + 12800;
constexpr size_t ASC    = OCCB + 12800;
constexpr size_t ACC50  = ASC + 64;
constexpr size_t SMEND  = ACC50 + 64;

// ---- short offsets within X (bf16 prep) region ----
constexpr size_t XT_WQKV = 0;          // 768*256
constexpr size_t XT_WFAT = 196608;     // 256*256  (Wfa^T)
constexpr size_t XT_WFBT = 262144;     // 256*256
constexpr size_t XT_KVT  = 327680;     // 256*256  (kv^T)
constexpr size_t XT_QCH  = 393216;     // 64*256 (qc, rows 50..63 zero)
constexpr size_t XT_KCH  = 409600;     // 64*256
constexpr size_t XT_END  = 425984;
constexpr size_t WS_NEEDED = B_X + XT_END * 2;

typedef short bf16x8 __attribute__((ext_vector_type(8)));
typedef float f32x4 __attribute__((ext_vector_type(4)));

__device__ __forceinline__ float sigmoidf_(float x){ return 1.0f / (1.0f + expf(-x)); }

__device__ __forceinline__ float bf2f(unsigned short u){
  return __uint_as_float(((unsigned int)u) << 16);
}
__device__ __forceinline__ unsigned short f2bf(float f){
  unsigned int x = __float_as_uint(f);
  unsigned int r = (x + 0x7fffu + ((x >> 16) & 1u)) >> 16;
  return (unsigned short)r;
}
__device__ __forceinline__ bf16x8 cvt8(const float* p){
  bf16x8 r;
  #pragma unroll
  for (int i = 0; i < 8; i++) r[i] = (short)f2bf(p[i]);
  return r;
}
__device__ __forceinline__ f32x4 mfma16(bf16x8 a, bf16x8 b, f32x4 c){
  return __builtin_amdgcn_mfma_f32_16x16x32_bf16(a, b, c, 0, 0, 0);
}

__device__ __forceinline__ float waveAllSum(float v){
  #pragma unroll
  for (int m = 1; m < 64; m <<= 1) v += __shfl_xor(v, m, 64);
  return v;
}

// ---------- qc/kc/vc + bf16 padded copies ----------
__global__ void __launch_bounds__(256) k_cqkv(const float* __restrict__ x, const float* __restrict__ Wqkv,
                                              float* qc, float* kc, float* vc,
                                              unsigned short* qch, unsigned short* kch){
  int r = blockIdx.x, j = threadIdx.x;
  __shared__ float xs[256];
  xs[j] = x[r * DD + j];
  __syncthreads();
  float aq = 0.f, ak = 0.f, av = 0.f;
  for (int k = 0; k < DD; k++) {
    float xv = xs[k];
    aq += xv * Wqkv[k * 768 + j];
    ak += xv * Wqkv[k * 768 + 256 + j];
    av += xv * Wqkv[k * 768 + 512 + j];
  }
  qc[r * DD + j] = aq; kc[r * DD + j] = ak; vc[r * DD + j] = av;
  qch[r * DD + j] = f2bf(aq); kch[r * DD + j] = f2bf(ak);
  if (r == 0) {
    for (int c = 50; c < 64; c++) { qch[c * DD + j] = 0; kch[c * DD + j] = 0; }
  }
}

// ---------- Wqkv^T bf16 ----------
__global__ void __launch_bounds__(256) k_wqkvT(const float* __restrict__ Wqkv, unsigned short* __restrict__ WT){
  int n = blockIdx.x, k = threadIdx.x;
  WT[(size_t)n * 256 + k] = f2bf(Wqkv[(size_t)k * 768 + n]);
}

// ---------- Vca = vc@Wa, Vcb = vc@Wb ----------
__global__ void __launch_bounds__(256) k_vcab(const float* vc, const float* Wa, const float* Wb,
                                              float* Vca, float* Vcb){
  int r = blockIdx.x, j = threadIdx.x;
  __shared__ float vs[256];
  vs[j] = vc[r * DD + j];
  __syncthreads();
  float a = 0.f, b = 0.f;
  for (int k = 0; k < DD; k++) { float v = vs[k]; a += v * Wa[k * DD + j]; b += v * Wb[k * DD + j]; }
  Vca[r * DD + j] = a; Vcb[r * DD + j] = b;
}

// ---------- Wfa = Wf@Wa (+ bf16 transposed), etc ----------
__global__ void __launch_bounds__(256) k_wfab(const float* Wf, const float* Wa, const float* Wb,
                                              const float* ba, const float* bb, const float* bf,
                                              float* Wfa, float* Wfb, float* bfa, float* bfb,
                                              unsigned short* WfaTh, unsigned short* WfbTh){
  int b = blockIdx.x, j = threadIdx.x;
  __shared__ float rs[256];
  const float* src; const float* Wm;
  if (b < 256)      { src = Wf + b * DD;         Wm = Wa; }
  else if (b < 512) { src = Wf + (b - 256) * DD; Wm = Wb; }
  else if (b == 512){ src = bf;                  Wm = Wa; }
  else              { src = bf;                  Wm = Wb; }
  rs[j] = src[j];
  __syncthreads();
  float a = 0.f;
  for (int k = 0; k < DD; k++) a += rs[k] * Wm[k * DD + j];
  if (b < 256)      { Wfa[b * DD + j] = a; WfaTh[(size_t)j * DD + b] = f2bf(a); }
  else if (b < 512) { Wfb[(b - 256) * DD + j] = a; WfbTh[(size_t)j * DD + (b - 256)] = f2bf(a); }
  else if (b == 512) bfa[j] = a + ba[j];
  else bfb[j] = a + bb[j];
}

// ---------- osc = softmax(scale*qc@kc^T)@vc ----------
__global__ void __launch_bounds__(256) k_osc(const float* qc, const float* kc, const float* vc, float* osc){
  __shared__ float S[50][64];
  __shared__ float P[50][64];
  int t = threadIdx.x;
  for (int p = t; p < 2500; p += 256) {
    int i = p / 50, jj = p % 50;
    float s = 0.f;
    for (int k = 0; k < DD; k++) s += qc[i * DD + k] * kc[jj * DD + k];
    S[i][jj] = s * SCL;
  }
  __syncthreads();
  if (t < 50) {
    float mx = -1e30f;
    for (int jj = 0; jj < 50; jj++) mx = fmaxf(mx, S[t][jj]);
    float den = 0.f;
    for (int jj = 0; jj < 50; jj++) { float e = expf(S[t][jj] - mx); P[t][jj] = e; den += e; }
    float inv = 1.0f / den;
    for (int jj = 0; jj < 50; jj++) P[t][jj] *= inv;
  }
  __syncthreads();
  for (int i = 0; i < 50; i++) {
    float a = 0.f;
    for (int jj = 0; jj < 50; jj++) a += P[i][jj] * vc[jj * DD + t];
    osc[i * DD + t] = a;
  }
}

// ---------- gated() on 50 rows ----------
__global__ void __launch_bounds__(256) k_gated(const float* __restrict__ tin,
                                               const float* __restrict__ Wa, const float* __restrict__ Wb,
                                               const float* __restrict__ ba, const float* __restrict__ bb,
                                               const float* __restrict__ Wc, const float* __restrict__ bc,
                                               float* __restrict__ A){
  int r = blockIdx.x, j = threadIdx.x;
  __shared__ float ts[256];
  __shared__ float red[4];
  ts[j] = tin[r * DD + j];
  __syncthreads();
  float u = 0.f, v = 0.f;
  for (int k = 0; k < DD; k++) { float tv = ts[k]; u += tv * Wa[k * DD + j]; v += tv * Wb[k * DD + j]; }
  float g = tanhf(u + ba[j]) * sigmoidf_(v + bb[j]) * Wc[j];
  g = waveAllSum(g);
  int lane = j & 63, wv = j >> 6;
  if (lane == 0) red[wv] = g;
  __syncthreads();
  if (j == 0) A[r] = red[0] + red[1] + red[2] + red[3] + bc[0];
}

// ---------- fused path kernel: MFMA qkv GEMM + MFMA scores + transforms + gate ----------
__global__ void __launch_bounds__(256) k_path1(
    const float* __restrict__ x, const unsigned short* __restrict__ WqkvTh,
    const float* __restrict__ sln,
    const unsigned short* __restrict__ kch, const unsigned short* __restrict__ qch,
    const float* __restrict__ Vca, const float* __restrict__ Vcb,
    const float* __restrict__ ba, const float* __restrict__ bb,
    const float* __restrict__ Wc, const float* __restrict__ bc,
    unsigned short* __restrict__ vph, unsigned short* __restrict__ qlh, unsigned short* __restrict__ klh,
    float* __restrict__ E, float* __restrict__ w50, float* __restrict__ edencp, float* __restrict__ occden){
  __shared__ unsigned short xsh[16][264];
  __shared__ float qps[16][260];
  __shared__ float kps[16][260];
  __shared__ float scap[16][68];
  __shared__ float scac[16][68];
  __shared__ float w50s[64];
  __shared__ float occs[64];
  __shared__ float edens;
  const int tid = threadIdx.x;
  const int i0 = blockIdx.x * 16;
  const int lane = tid & 63;
  const int wvv = tid >> 6;
  const int cn = lane & 15;          // MFMA col / A-row
  const int m0 = (lane >> 4) * 4;    // MFMA C row base
  const int kq = (lane >> 4) * 8;    // MFMA A/B k sub-offset

  if (tid < 64) { w50s[tid] = 0.f; occs[tid] = 0.f; }
  if (tid == 0) edens = 0.f;
  for (int l = tid; l < 4096; l += 256) {
    int r = l >> 8, c = l & 255;
    xsh[r][c] = f2bf(x[(size_t)(MM + i0 + r) * DD + c]);
  }
  __syncthreads();

  // ---- GEMM: [16 x 256] @ [256 x 768] via mfma 16x16x32 ----
  bf16x8 af[8];
  #pragma unroll
  for (int k0 = 0; k0 < 8; k0++)
    af[k0] = *(const bf16x8*)&xsh[cn][k0 * 32 + kq];
  #pragma unroll 1
  for (int tt = 0; tt < 12; tt++) {
    const int t = wvv + 4 * tt;       // n-tile 0..47
    const size_t nrow = (size_t)(t * 16 + cn) * 256;
    f32x4 acc = {0.f, 0.f, 0.f, 0.f};
    #pragma unroll
    for (int k0 = 0; k0 < 8; k0++) {
      bf16x8 b = *(const bf16x8*)&WqkvTh[nrow + k0 * 32 + kq];
      acc = mfma16(af[k0], b, acc);
    }
    if (t < 16) {
      int c = t * 16 + cn;
      #pragma unroll
      for (int i = 0; i < 4; i++) qps[m0 + i][c] = acc[i];
    } else if (t < 32) {
      int c = (t - 16) * 16 + cn;
      #pragma unroll
      for (int i = 0; i < 4; i++) kps[m0 + i][c] = acc[i];
    } else {
      int c = (t - 32) * 16 + cn;
      #pragma unroll
      for (int i = 0; i < 4; i++) vph[(size_t)(i0 + m0 + i) * DD + c] = f2bf(acc[i]);
    }
  }
  __syncthreads();

  // ---- scores via MFMA: cap = qp@kc^T, cac = kp@qc^T (16x64 each) ----
  {
    bf16x8 aq[8], ak[8];
    #pragma unroll
    for (int k0 = 0; k0 < 8; k0++) {
      aq[k0] = cvt8(&qps[cn][k0 * 32 + kq]);
      ak[k0] = cvt8(&kps[cn][k0 * 32 + kq]);
    }
    const int n0 = wvv * 16;
    f32x4 accp = {0.f,0.f,0.f,0.f}, accc = {0.f,0.f,0.f,0.f};
    #pragma unroll
    for (int k0 = 0; k0 < 8; k0++) {
      bf16x8 bk = *(const bf16x8*)&kch[(size_t)(n0 + cn) * DD + k0 * 32 + kq];
      bf16x8 bq = *(const bf16x8*)&qch[(size_t)(n0 + cn) * DD + k0 * 32 + kq];
      accp = mfma16(aq[k0], bk, accp);
      accc = mfma16(ak[k0], bq, accc);
    }
    #pragma unroll
    for (int i = 0; i < 4; i++) {
      scap[m0 + i][n0 + cn] = accp[i];
      scac[m0 + i][n0 + cn] = accc[i];
    }
  }
  __syncthreads();

  // ---- phase B: wave handles 4 rows ----
  float4 sl4 = ((const float4*)sln)[lane];
  float4 rsp;
  rsp.x = 1.0f / log1pf(expf(sl4.x)); rsp.y = 1.0f / log1pf(expf(sl4.y));
  rsp.z = 1.0f / log1pf(expf(sl4.z)); rsp.w = 1.0f / log1pf(expf(sl4.w));
  float4 ba4 = ((const float4*)ba)[lane];
  float4 bb4 = ((const float4*)bb)[lane];
  float4 wc4 = ((const float4*)Wc)[lane];
  float bcv = bc[0];

  float p[4];
  float occacc = 0.f;
  for (int rr = 0; rr < 4; rr++) {
    const int r = wvv * 4 + rr;
    const int row = i0 + r;
    float4 q4 = *(const float4*)&qps[r][lane * 4];
    float4 k4 = *(const float4*)&kps[r][lane * 4];
    float4 lq, lk;
    lq.x = (fmaxf(q4.x, 0.f) + 1e-6f) * rsp.x; lq.y = (fmaxf(q4.y, 0.f) + 1e-6f) * rsp.y;
    lq.z = (fmaxf(q4.z, 0.f) + 1e-6f) * rsp.z; lq.w = (fmaxf(q4.w, 0.f) + 1e-6f) * rsp.w;
    lk.x = (fmaxf(k4.x, 0.f) + 1e-6f) * rsp.x; lk.y = (fmaxf(k4.y, 0.f) + 1e-6f) * rsp.y;
    lk.z = (fmaxf(k4.z, 0.f) + 1e-6f) * rsp.z; lk.w = (fmaxf(k4.w, 0.f) + 1e-6f) * rsp.w;
    float4 q3, k3;
    q3.x = lq.x*lq.x*lq.x; q3.y = lq.y*lq.y*lq.y; q3.z = lq.z*lq.z*lq.z; q3.w = lq.w*lq.w*lq.w;
    k3.x = lk.x*lk.x*lk.x; k3.y = lk.y*lk.y*lk.y; k3.z = lk.z*lk.z*lk.z; k3.w = lk.w*lk.w*lk.w;
    float n1q = lq.x*lq.x + lq.y*lq.y + lq.z*lq.z + lq.w*lq.w;
    float n3q = q3.x*q3.x + q3.y*q3.y + q3.z*q3.z + q3.w*q3.w;
    float n1k = lk.x*lk.x + lk.y*lk.y + lk.z*lk.z + lk.w*lk.w;
    float n3k = k3.x*k3.x + k3.y*k3.y + k3.z*k3.z + k3.w*k3.w;
    n1q = waveAllSum(n1q); n3q = waveAllSum(n3q);
    n1k = waveAllSum(n1k); n3k = waveAllSum(n3k);
    float fq = sqrtf(n1q / n3q);
    float fk = sqrtf(n1k / n3k);
    ushort4 qo, ko;
    qo.x = f2bf(q3.x * fq); qo.y = f2bf(q3.y * fq); qo.z = f2bf(q3.z * fq); qo.w = f2bf(q3.w * fq);
    ko.x = f2bf(k3.x * fk); ko.y = f2bf(k3.y * fk); ko.z = f2bf(k3.z * fk); ko.w = f2bf(k3.w * fk);
    *(ushort4*)&qlh[(size_t)row * DD + lane * 4] = qo;
    *(ushort4*)&klh[(size_t)row * DD + lane * 4] = ko;
    float scapv = scap[r][lane] * SCL;
    float scacv = scac[r][lane] * SCL;
    float ecap = (lane < 50) ? expf(scapv) : 0.f;
    float ecac = (lane < 50) ? expf(scacv) : 0.f;
    E[(size_t)row * 64 + lane] = ecac;
    occacc += ecac;
    float den = waveAllSum(ecap);
    p[rr] = ecap / den;
  }
  float4 u[4], vv[4];
  #pragma unroll
  for (int r = 0; r < 4; r++) { u[r] = ba4; vv[r] = bb4; }
  for (int i = 0; i < 50; i++) {
    float4 va = ((const float4*)(Vca + i * DD))[lane];
    float4 vb = ((const float4*)(Vcb + i * DD))[lane];
    #pragma unroll
    for (int r = 0; r < 4; r++) {
      float pi = __shfl(p[r], i, 64);
      u[r].x += pi * va.x; u[r].y += pi * va.y; u[r].z += pi * va.z; u[r].w += pi * va.w;
      vv[r].x += pi * vb.x; vv[r].y += pi * vb.y; vv[r].z += pi * vb.z; vv[r].w += pi * vb.w;
    }
  }
  float w50acc = 0.f, ewacc = 0.f;
  #pragma unroll
  for (int r = 0; r < 4; r++) {
    float g = tanhf(u[r].x) * sigmoidf_(vv[r].x) * wc4.x
            + tanhf(u[r].y) * sigmoidf_(vv[r].y) * wc4.y
            + tanhf(u[r].z) * sigmoidf_(vv[r].z) * wc4.z
            + tanhf(u[r].w) * sigmoidf_(vv[r].w) * wc4.w;
    g = waveAllSum(g);
    float ew = expf(g + bcv);
    w50acc += ew * p[r];
    if (lane == 0) ewacc += ew;
  }
  atomicAdd(&w50s[lane], w50acc);
  atomicAdd(&occs[lane], occacc);
  if (lane == 0) atomicAdd(&edens, ewacc);
  __syncthreads();
  if (tid < 50) { atomicAdd(&w50[tid], w50s[tid]); atomicAdd(&occden[tid], occs[tid]); }
  if (tid == 0) atomicAdd(edencp, edens);
}

// ---------- klsum ----------
__global__ void __launch_bounds__(256) k_klsum(const unsigned short* __restrict__ klh, float* __restrict__ klsum){
  int d = threadIdx.x;
  float s = 0.f;
  size_t j0 = (size_t)blockIdx.x * 1024;
  for (int j = 0; j < 1024; j++) s += bf2f(klh[(j0 + j) * DD + d]);
  atomicAdd(&klsum[d], s);
}

// ---------- occ numerator ----------
__global__ void __launch_bounds__(256) k_occnum(const float* __restrict__ E, const unsigned short* __restrict__ vph,
                                                float* __restrict__ occraw){
  int d = threadIdx.x;
  int j0 = blockIdx.x * 512;
  __shared__ float Es[32][64];
  float acc[52];
  #pragma unroll
  for (int i = 0; i < 52; i++) acc[i] = 0.f;
  for (int s = 0; s < 16; s++) {
    for (int l = threadIdx.x; l < 512; l += 256) {
      int jj = l >> 4, cq = l & 15;
      *(float4*)&Es[jj][cq * 4] = ((const float4*)(E + (size_t)(j0 + s * 32 + jj) * 64))[cq];
    }
    __syncthreads();
    for (int jj = 0; jj < 32; jj++) {
      float vv = bf2f(vph[(size_t)(j0 + s * 32 + jj) * DD + d]);
      #pragma unroll
      for (int q = 0; q < 13; q++) {
        float4 e4 = *(const float4*)&Es[jj][q * 4];
        acc[q * 4 + 0] += e4.x * vv; acc[q * 4 + 1] += e4.y * vv;
        acc[q * 4 + 2] += e4.z * vv; acc[q * 4 + 3] += e4.w * vv;
      }
    }
    __syncthreads();
  }
  for (int i = 0; i < 50; i++) atomicAdd(&occraw[i * DD + d], acc[i]);
}

__global__ void __launch_bounds__(256) k_occfin(const float* __restrict__ occraw, const float* __restrict__ occden,
                                                float* __restrict__ occ){
  int i = blockIdx.x, d = threadIdx.x;
  occ[i * DD + d] = occraw[i * DD + d] / occden[i];
}

// ---------- kv = kl^T @ vp (split-K fp32, partials into E region) ----------
__global__ void __launch_bounds__(256) k_kv(const unsigned short* __restrict__ klh,
                                            const unsigned short* __restrict__ vph,
                                            float* __restrict__ PKVp){
  __shared__ float As[16][132];
  __shared__ float Bs[16][132];
  int tid = threadIdx.x;
  int ct = blockIdx.x, dt = blockIdx.y, kc_ = blockIdx.z;
  float acc[8][8];
  #pragma unroll
  for (int p = 0; p < 8; p++)
    #pragma unroll
    for (int q = 0; q < 8; q++) acc[p][q] = 0.f;
  int ty = tid >> 4, tx = tid & 15;
  for (int j0 = kc_ * 1024; j0 < kc_ * 1024 + 1024; j0 += 16) {
    for (int l = tid; l < 512; l += 256) {
      int jj = l >> 5, cq = l & 31;
      ushort4 a4 = *(const ushort4*)&klh[(size_t)(j0 + jj) * DD + ct * 128 + cq * 4];
      ushort4 b4 = *(const ushort4*)&vph[(size_t)(j0 + jj) * DD + dt * 128 + cq * 4];
      As[jj][cq*4+0] = bf2f(a4.x); As[jj][cq*4+1] = bf2f(a4.y);
      As[jj][cq*4+2] = bf2f(a4.z); As[jj][cq*4+3] = bf2f(a4.w);
      Bs[jj][cq*4+0] = bf2f(b4.x); Bs[jj][cq*4+1] = bf2f(b4.y);
      Bs[jj][cq*4+2] = bf2f(b4.z); Bs[jj][cq*4+3] = bf2f(b4.w);
    }
    __syncthreads();
    #pragma unroll
    for (int jj = 0; jj < 16; jj++) {
      float4 a0 = *(const float4*)&As[jj][ty * 8];
      float4 a1 = *(const float4*)&As[jj][ty * 8 + 4];
      float4 b0 = *(const float4*)&Bs[jj][tx * 8];
      float4 b1 = *(const float4*)&Bs[jj][tx * 8 + 4];
      float av[8] = {a0.x,a0.y,a0.z,a0.w,a1.x,a1.y,a1.z,a1.w};
      float bv[8] = {b0.x,b0.y,b0.z,b0.w,b1.x,b1.y,b1.z,b1.w};
      #pragma unroll
      for (int p = 0; p < 8; p++)
        #pragma unroll
        for (int q = 0; q < 8; q++) acc[p][q] += av[p] * bv[q];
    }
    __syncthreads();
  }
  float* P = PKVp + (size_t)((kc_ * 2 + ct) * 2 + dt) * 16384;
  #pragma unroll
  for (int p = 0; p < 8; p++) {
    float4 s0 = {acc[p][0], acc[p][1], acc[p][2], acc[p][3]};
    float4 s1 = {acc[p][4], acc[p][5], acc[p][6], acc[p][7]};
    *(float4*)&P[(ty * 8 + p) * 128 + tx * 8] = s0;
    *(float4*)&P[(ty * 8 + p) * 128 + tx * 8 + 4] = s1;
  }
}

__global__ void __launch_bounds__(256) k_kvred(const float* __restrict__ PKVp, float* __restrict__ kv,
                                               unsigned short* __restrict__ kvTh){
  int c = blockIdx.x, d = threadIdx.x;
  int ct = c >> 7, dt = d >> 7, cl = c & 127, dl = d & 127;
  float s = 0.f;
  for (int kc = 0; kc < 64; kc++)
    s += PKVp[(size_t)((kc * 2 + ct) * 2 + dt) * 16384 + cl * 128 + dl];
  kv[c * DD + d] = s;
  kvTh[(size_t)d * DD + c] = f2bf(s);   // kv^T for MFMA B operand
}

// ---------- fused: OS=(ql@kv)*zfac (MFMA) + dwconv(vp)+bias -> T ----------
__global__ void __launch_bounds__(256) k_outs_conv(const unsigned short* __restrict__ qlh,
                                                   const unsigned short* __restrict__ kvTh,
                                                   const float* __restrict__ klsum,
                                                   const unsigned short* __restrict__ vph,
                                                   const float* __restrict__ dwcw, const float* __restrict__ dwcb,
                                                   unsigned short* __restrict__ th){
  __shared__ unsigned short qlsh[16][264];
  __shared__ float OSs[16][260];
  __shared__ float red[4][16];
  __shared__ float zf[16];
  const int tid = threadIdx.x;
  const int i0 = blockIdx.x * 16;
  const int lane = tid & 63;
  const int wvv = tid >> 6;
  const int cn = lane & 15;
  const int m0 = (lane >> 4) * 4;
  const int kq = (lane >> 4) * 8;
  for (int l = tid; l < 1024; l += 256) {
    int r = l >> 6, c4 = (l & 63) * 4;
    *(ushort4*)&qlsh[r][c4] = *(const ushort4*)&qlh[(size_t)(i0 + r) * DD + c4];
  }
  __syncthreads();
  {
    bf16x8 af[8];
    #pragma unroll
    for (int k0 = 0; k0 < 8; k0++) af[k0] = *(const bf16x8*)&qlsh[cn][k0 * 32 + kq];
    #pragma unroll 1
    for (int tt = 0; tt < 4; tt++) {
      const int t = wvv * 4 + tt;
      f32x4 acc = {0.f,0.f,0.f,0.f};
      #pragma unroll
      for (int k0 = 0; k0 < 8; k0++) {
        bf16x8 b = *(const bf16x8*)&kvTh[(size_t)(t * 16 + cn) * DD + k0 * 32 + kq];
        acc = mfma16(af[k0], b, acc);
      }
      #pragma unroll
      for (int i = 0; i < 4; i++) OSs[m0 + i][t * 16 + cn] = acc[i];
    }
  }
  __syncthreads();
  const int j = tid;
  float ks = klsum[j];
  #pragma unroll
  for (int r = 0; r < 16; r++) {
    float t = bf2f(qlsh[r][j]) * ks;
    t = waveAllSum(t);
    if (lane == 0) red[wvv][r] = t;
  }
  __syncthreads();
  if (tid < 16) {
    float t = red[0][tid] + red[1][tid] + red[2][tid] + red[3][tid];
    zf[tid] = 1.0f / (t + 1e-6f);
  }
  __syncthreads();
  float w[25];
  #pragma unroll
  for (int t = 0; t < 25; t++) w[t] = dwcw[j * 25 + t];
  float bias = dwcb[j];
  const int y = i0 >> 8, x0 = i0 & 255;
  for (int r = 0; r < 16; r++) {
    int xx0 = x0 + r;
    float fm = bias;
    #pragma unroll
    for (int dy = -2; dy <= 2; dy++) {
      int yy = y + dy;
      if ((unsigned)yy > 255u) continue;
      #pragma unroll
      for (int dx = -2; dx <= 2; dx++) {
        int xx = xx0 + dx;
        if ((unsigned)xx > 255u) continue;
        fm += bf2f(vph[(size_t)((yy << 8) + xx) * DD + j]) * w[(dy + 2) * 5 + (dx + 2)];
      }
    }
    float T = OSs[r][j] * zf[r] + fm;
    th[(size_t)(i0 + r) * DD + j] = f2bf(T);
  }
}

// ---------- self-path gate (MFMA) + h2 accumulation ----------
__global__ void __launch_bounds__(256) k_selfgate(const unsigned short* __restrict__ th,
                                                  const unsigned short* __restrict__ WfaTh,
                                                  const unsigned short* __restrict__ WfbTh,
                                                  const float* __restrict__ bfa, const float* __restrict__ bfb,
                                                  const float* __restrict__ Wc, const float* __restrict__ bc,
                                                  float* __restrict__ h2t, float* __restrict__ h2den){
  __shared__ unsigned short tsh[16][264];
  __shared__ float aUs[16][260];
  __shared__ float aVs[16][260];
  __shared__ float red[4][16];
  __shared__ float ev[16];
  const int tid = threadIdx.x;
  const int i0 = blockIdx.x * 16;
  const int lane = tid & 63;
  const int wvv = tid >> 6;
  const int cn = lane & 15;
  const int m0 = (lane >> 4) * 4;
  const int kq = (lane >> 4) * 8;
  for (int l = tid; l < 1024; l += 256) {
    int r = l >> 6, c4 = (l & 63) * 4;
    *(ushort4*)&tsh[r][c4] = *(const ushort4*)&th[(size_t)(i0 + r) * DD + c4];
  }
  __syncthreads();
  {
    bf16x8 af[8];
    #pragma unroll
    for (int k0 = 0; k0 < 8; k0++) af[k0] = *(const bf16x8*)&tsh[cn][k0 * 32 + kq];
    #pragma unroll 1
    for (int jb = 0; jb < 8; jb++) {
      const int t = wvv * 4 + (jb & 3);
      const unsigned short* Bt = (jb < 4) ? WfaTh : WfbTh;
      f32x4 acc = {0.f,0.f,0.f,0.f};
      #pragma unroll
      for (int k0 = 0; k0 < 8; k0++) {
        bf16x8 b = *(const bf16x8*)&Bt[(size_t)(t * 16 + cn) * DD + k0 * 32 + kq];
        acc = mfma16(af[k0], b, acc);
      }
      float (*dst)[260] = (jb < 4) ? aUs : aVs;
      #pragma unroll
      for (int i = 0; i < 4; i++) dst[m0 + i][t * 16 + cn] = acc[i];
    }
  }
  __syncthreads();
  const int j = tid;
  float bfaj = bfa[j], bfbj = bfb[j], wcj = Wc[j];
  #pragma unroll
  for (int r = 0; r < 16; r++) {
    float g = tanhf(aUs[r][j] + bfaj) * sigmoidf_(aVs[r][j] + bfbj) * wcj;
    g = waveAllSum(g);
    if (lane == 0) red[wvv][r] = g;
  }
  __syncthreads();
  if (tid < 16) {
    float A = red[0][tid] + red[1][tid] + red[2][tid] + red[3][tid] + bc[0];
    ev[tid] = expf(A);
  }
  __syncthreads();
  float hp = 0.f;
  #pragma unroll
  for (int r = 0; r < 16; r++) hp += ev[r] * bf2f(tsh[r][j]);
  atomicAdd(&h2t[j], hp);
  if (tid == 0) {
    float es = 0.f;
    for (int r = 0; r < 16; r++) es += ev[r];
    atomicAdd(h2den, es);
  }
}

// ---------- final tiny MLPs ----------
__global__ void __launch_bounds__(256) k_final(
    const float* __restrict__ A_cc, const float* __restrict__ occ,
    const float* __restrict__ A_sc, const float* __restrict__ osc,
    const float* __restrict__ w50, const float* __restrict__ edencp,
    const float* __restrict__ h2t, const float* __restrict__ h2den,
    const float* __restrict__ vc, const float* __restrict__ Wf, const float* __restrict__ bf,
    const float* __restrict__ W1, const float* __restrict__ b1,
    const float* __restrict__ W2, const float* __restrict__ b2,
    const float* __restrict__ W3a, const float* __restrict__ b3a,
    const float* __restrict__ W3b, const float* __restrict__ b3b,
    float* __restrict__ out){
  int j = threadIdx.x;
  __shared__ float pw[64];
  __shared__ float t1[256], t2[256], h1[256], h2[256], fz[512], z1[256];
  // ===== CROSS =====
  if (j < 64) pw[j] = (j < 50) ? expf(A_cc[j]) : 0.f;
  __syncthreads();
  float den = 0.f;
  for (int i = 0; i < 50; i++) den += pw[i];
  float raw = 0.f;
  for (int i = 0; i < 50; i++) raw += pw[i] * occ[i * DD + j];
  t1[j] = raw / den;
  float r2 = 0.f;
  for (int i = 0; i < 50; i++) r2 += w50[i] * vc[i * DD + j];
  t2[j] = r2 / edencp[0];
  __syncthreads();
  float a1 = 0.f, a2 = 0.f;
  for (int k = 0; k < DD; k++) { a1 += t1[k] * W1[k * DD + j]; a2 += t2[k] * W2[k * DD + j]; }
  h1[j] = fmaxf(a1 + b1[j], 0.f);
  h2[j] = fmaxf(a2 + b2[j], 0.f);
  __syncthreads();
  fz[j] = h1[j]; fz[256 + j] = h2[j];
  __syncthreads();
  float z = 0.f;
  for (int k = 0; k < 512; k++) z += fz[k] * W3a[k * DD + j];
  z1[j] = fmaxf(z + b3a[j], 0.f);
  __syncthreads();
  float o = 0.f;
  for (int k = 0; k < DD; k++) o += z1[k] * W3b[k * DD + j];
  out[j] = fmaxf(o + b3b[j], 0.f);
  __syncthreads();
  // ===== SELF =====
  if (j < 64) pw[j] = (j < 50) ? expf(A_sc[j]) : 0.f;
  __syncthreads();
  den = 0.f;
  for (int i = 0; i < 50; i++) den += pw[i];
  raw = 0.f;
  for (int i = 0; i < 50; i++) raw += pw[i] * osc[i * DD + j];
  t1[j] = raw / den;
  t2[j] = h2t[j] / h2den[0];
  __syncthreads();
  float hs = 0.f;
  for (int k = 0; k < DD; k++) hs += t2[k] * Wf[k * DD + j];
  __syncthreads();
  t2[j] = hs + bf[j];
  __syncthreads();
  a1 = 0.f; a2 = 0.f;
  for (int k = 0; k < DD; k++) { a1 += t1[k] * W1[k * DD + j]; a2 += t2[k] * W2[k * DD + j]; }
  h1[j] = fmaxf(a1 + b1[j], 0.f);
  h2[j] = fmaxf(a2 + b2[j], 0.f);
  __syncthreads();
  fz[j] = h1[j]; fz[256 + j] = h2[j];
  __syncthreads();
  z = 0.f;
  for (int k = 0; k < 512; k++) z += fz[k] * W3a[k * DD + j];
  z1[j] = fmaxf(z + b3a[j], 0.f);
  __syncthreads();
  o = 0.f;
  for (int k = 0; k < DD; k++) o += z1[k] * W3b[k * DD + j];
  out[256 + j] = fmaxf(o + b3b[j], 0.f);
}

extern "C" void kernel_launch(void* const* d_in, const int* in_sizes, int n_in,
                              void* d_out, int out_size, void* d_ws, size_t ws_size,
                              hipStream_t stream) {
  if (ws_size < WS_NEEDED) return;
  const float* x   = (const float*)d_in[0];
  const float* Wqkv= (const float*)d_in[1];
  const float* sln = (const float*)d_in[2];
  const float* dwcw= (const float*)d_in[3];
  const float* dwcb= (const float*)d_in[4];
  const float* Wa  = (const float*)d_in[5];
  const float* ba  = (const float*)d_in[6];
  const float* Wb  = (const float*)d_in[7];
  const float* bb  = (const float*)d_in[8];
  const float* Wc  = (const float*)d_in[9];
  const float* bc  = (const float*)d_in[10];
  const float* W1  = (const float*)d_in[11];
  const float* b1  = (const float*)d_in[12];
  const float* W2  = (const float*)d_in[13];
  const float* b2  = (const float*)d_in[14];
  const float* W3a = (const float*)d_in[15];
  const float* b3a = (const float*)d_in[16];
  const float* W3b = (const float*)d_in[17];
  const float* b3b = (const float*)d_in[18];
  const float* Wf  = (const float*)d_in[19];
  const float* bf  = (const float*)d_in[20];

  char* wsb = (char*)d_ws;
  unsigned short* VPH = (unsigned short*)(wsb + B_VPH);
  unsigned short* QLH = (unsigned short*)(wsb + B_QLH);
  unsigned short* KLH = (unsigned short*)(wsb + B_KLH);   // also T
  float* EB = (float*)(wsb + B_E);                        // also PKV
  float* SM = (float*)(wsb + B_SM);
  unsigned short* XT = (unsigned short*)(wsb + B_X);
  float* outp = (float*)d_out;

  hipMemsetAsync((void*)SM, 0, ZEND * sizeof(float), stream);

  k_cqkv<<<50, 256, 0, stream>>>(x, Wqkv, SM + QC, SM + KC, SM + VC, XT + XT_QCH, XT + XT_KCH);
  k_wqkvT<<<768, 256, 0, stream>>>(Wqkv, XT + XT_WQKV);
  k_vcab<<<50, 256, 0, stream>>>(SM + VC, Wa, Wb, SM + VCA, SM + VCB);
  k_wfab<<<514, 256, 0, stream>>>(Wf, Wa, Wb, ba, bb, bf, SM + WFA, SM + WFB, SM + BFA, SM + BFB,
                                  XT + XT_WFAT, XT + XT_WFBT);
  k_osc<<<1, 256, 0, stream>>>(SM + QC, SM + KC, SM + VC, SM + OSCB);
  k_gated<<<50, 256, 0, stream>>>(SM + OSCB, Wa, Wb, ba, bb, Wc, bc, SM + ASC);

  k_path1<<<4096, 256, 0, stream>>>(x, XT + XT_WQKV, sln, XT + XT_KCH, XT + XT_QCH,
                                    SM + VCA, SM + VCB, ba, bb, Wc, bc,
                                    VPH, QLH, KLH, EB, SM + W50, SM + EDENC, SM + OCCDEN);
  k_klsum<<<64, 256, 0, stream>>>(KLH, SM + KLSUM);
  k_occnum<<<128, 256, 0, stream>>>(EB, VPH, SM + OCCRAW);
  k_occfin<<<50, 256, 0, stream>>>(SM + OCCRAW, SM + OCCDEN, SM + OCCB);
  k_gated<<<50, 256, 0, stream>>>(SM + OCCB, Wa, Wb, ba, bb, Wc, bc, SM + ACC50);

  k_kv<<<dim3(2, 2, 64), 256, 0, stream>>>(KLH, VPH, EB);   // PKV into E region (E dead)
  k_kvred<<<256, 256, 0, stream>>>(EB, SM + KVM, XT + XT_KVT);

  k_outs_conv<<<4096, 256, 0, stream>>>(QLH, XT + XT_KVT, SM + KLSUM, VPH, dwcw, dwcb, KLH);
  k_selfgate<<<4096, 256, 0, stream>>>(KLH, XT + XT_WFAT, XT + XT_WFBT, SM + BFA, SM + BFB,
                                       Wc, bc, SM + H2T, SM + H2DEN);

  k_final<<<1, 256, 0, stream>>>(SM + ACC50, SM + OCCB, SM + ASC, SM + OSCB,
                                 SM + W50, SM + EDENC, SM + H2T, SM + H2DEN,
                                 SM + VC, Wf, bf, W1, b1, W2, b2, W3a, b3a, W3b, b3b, outp);
}

// Round 4
// 1290.797 us; speedup vs baseline: 1.5623x; 1.1121x over previous
//
#include <hip/hip_runtime.h>
#include <math.h>

// MixedAttentionLayer — R4: dbuf MFMA qkv GEMM, MFMA gate in path1,
// fused outs+conv+selfgate (T stays in LDS), MFMA split-K kv.

constexpr int DD = 256;
constexpr int MM = 50;
constexpr float SCL = 0.0625f; // 256^-0.5

// ---- byte offsets in d_ws ----
constexpr size_t B_VPH = 0;                      // 32 MiB bf16 vp
constexpr size_t B_QLH = (size_t)32 << 20;       // 32 MiB bf16 ql
constexpr size_t B_KLH = (size_t)64 << 20;       // 32 MiB bf16 kl
constexpr size_t B_E   = (size_t)96 << 20;       // 16 MiB f32 E; later bf16 kv partials
constexpr size_t B_SM  = (size_t)112 << 20;      // small fp32 region
constexpr size_t B_X   = B_SM + ((size_t)2 << 20); // bf16 prep region

// ---- float offsets within SM region ----
constexpr size_t KLSUM  = 0;
constexpr size_t OCCDEN = 256;
constexpr size_t W50    = 320;
constexpr size_t EDENC  = 384;
constexpr size_t H2T    = 392;
constexpr size_t H2DEN  = 648;
constexpr size_t OCCRAW = 656;
constexpr size_t ZEND   = 13456;
constexpr size_t QC     = 13456;
constexpr size_t KC     = QC + 12800;
constexpr size_t VC     = KC + 12800;
constexpr size_t VCA    = VC + 12800;
constexpr size_t VCB    = VCA + 12800;
constexpr size_t WFA    = VCB + 12800;
constexpr size_t WFB    = WFA + 65536;
constexpr size_t BFA    = WFB + 65536;
constexpr size_t BFB    = BFA + 256;
constexpr size_t OSCB   = BFB + 256;
constexpr size_t OCCB   = OSCB + 12800;
constexpr size_t ASC    = OCCB + 12800;
constexpr size_t ACC50  = ASC + 64;
constexpr size_t SMEND  = ACC50 + 64;

// ---- short offsets within X (bf16 prep) region ----
constexpr size_t XT_WQKV = 0;          // 768*256
constexpr size_t XT_WFAT = 196608;     // 256*256  (Wfa^T)
constexpr size_t XT_WFBT = 262144;     // 256*256
constexpr size_t XT_KVT  = 327680;     // 256*256  (kv^T)
constexpr size_t XT_QCH  = 393216;     // 64*256 (qc, rows 50..63 zero)
constexpr size_t XT_KCH  = 409600;     // 64*256
constexpr size_t XT_VCAT = 425984;     // 256*64 (Vca^T, cols 50..63 zero)
constexpr size_t XT_VCBT = 442368;     // 256*64
constexpr size_t XT_END  = 458752;
constexpr size_t WS_NEEDED = B_X + XT_END * 2;

typedef short bf16x8 __attribute__((ext_vector_type(8)));
typedef float f32x4 __attribute__((ext_vector_type(4)));

__device__ __forceinline__ float sigmoidf_(float x){ return 1.0f / (1.0f + expf(-x)); }

__device__ __forceinline__ float bf2f(unsigned short u){
  return __uint_as_float(((unsigned int)u) << 16);
}
__device__ __forceinline__ unsigned short f2bf(float f){
  unsigned int x = __float_as_uint(f);
  unsigned int r = (x + 0x7fffu + ((x >> 16) & 1u)) >> 16;
  return (unsigned short)r;
}
__device__ __forceinline__ bf16x8 cvt8(const float* p){
  bf16x8 r;
  #pragma unroll
  for (int i = 0; i < 8; i++) r[i] = (short)f2bf(p[i]);
  return r;
}
__device__ __forceinline__ f32x4 mfma16(bf16x8 a, bf16x8 b, f32x4 c){
  return __builtin_amdgcn_mfma_f32_16x16x32_bf16(a, b, c, 0, 0, 0);
}
// build a bf16x8 fragment from 8 strided ushorts (row-major source, K = row dim)
__device__ __forceinline__ bf16x8 frag_strided(const unsigned short* base, int stride){
  bf16x8 r;
  #pragma unroll
  for (int i = 0; i < 8; i++) r[i] = (short)base[(size_t)i * stride];
  return r;
}

__device__ __forceinline__ float waveAllSum(float v){
  #pragma unroll
  for (int m = 1; m < 64; m <<= 1) v += __shfl_xor(v, m, 64);
  return v;
}

// ---------- qc/kc/vc + bf16 padded copies ----------
__global__ void __launch_bounds__(256) k_cqkv(const float* __restrict__ x, const float* __restrict__ Wqkv,
                                              float* qc, float* kc, float* vc,
                                              unsigned short* qch, unsigned short* kch){
  int r = blockIdx.x, j = threadIdx.x;
  __shared__ float xs[256];
  xs[j] = x[r * DD + j];
  __syncthreads();
  float aq = 0.f, ak = 0.f, av = 0.f;
  for (int k = 0; k < DD; k++) {
    float xv = xs[k];
    aq += xv * Wqkv[k * 768 + j];
    ak += xv * Wqkv[k * 768 + 256 + j];
    av += xv * Wqkv[k * 768 + 512 + j];
  }
  qc[r * DD + j] = aq; kc[r * DD + j] = ak; vc[r * DD + j] = av;
  qch[r * DD + j] = f2bf(aq); kch[r * DD + j] = f2bf(ak);
  if (r == 0) {
    for (int c = 50; c < 64; c++) { qch[c * DD + j] = 0; kch[c * DD + j] = 0; }
  }
}

// ---------- Wqkv^T bf16 ----------
__global__ void __launch_bounds__(256) k_wqkvT(const float* __restrict__ Wqkv, unsigned short* __restrict__ WT){
  int n = blockIdx.x, k = threadIdx.x;
  WT[(size_t)n * 256 + k] = f2bf(Wqkv[(size_t)k * 768 + n]);
}

// ---------- Vca = vc@Wa, Vcb = vc@Wb (+ bf16 transposed padded) ----------
__global__ void __launch_bounds__(256) k_vcab(const float* vc, const float* Wa, const float* Wb,
                                              float* Vca, float* Vcb,
                                              unsigned short* VcaTh, unsigned short* VcbTh){
  int r = blockIdx.x, j = threadIdx.x;
  __shared__ float vs[256];
  vs[j] = vc[r * DD + j];
  __syncthreads();
  float a = 0.f, b = 0.f;
  for (int k = 0; k < DD; k++) { float v = vs[k]; a += v * Wa[k * DD + j]; b += v * Wb[k * DD + j]; }
  Vca[r * DD + j] = a; Vcb[r * DD + j] = b;
  VcaTh[j * 64 + r] = f2bf(a); VcbTh[j * 64 + r] = f2bf(b);
  if (r == 0) {
    for (int c = 50; c < 64; c++) { VcaTh[j * 64 + c] = 0; VcbTh[j * 64 + c] = 0; }
  }
}

// ---------- Wfa = Wf@Wa (+ bf16 transposed), etc ----------
__global__ void __launch_bounds__(256) k_wfab(const float* Wf, const float* Wa, const float* Wb,
                                              const float* ba, const float* bb, const float* bf,
                                              float* Wfa, float* Wfb, float* bfa, float* bfb,
                                              unsigned short* WfaTh, unsigned short* WfbTh){
  int b = blockIdx.x, j = threadIdx.x;
  __shared__ float rs[256];
  const float* src; const float* Wm;
  if (b < 256)      { src = Wf + b * DD;         Wm = Wa; }
  else if (b < 512) { src = Wf + (b - 256) * DD; Wm = Wb; }
  else if (b == 512){ src = bf;                  Wm = Wa; }
  else              { src = bf;                  Wm = Wb; }
  rs[j] = src[j];
  __syncthreads();
  float a = 0.f;
  for (int k = 0; k < DD; k++) a += rs[k] * Wm[k * DD + j];
  if (b < 256)      { Wfa[b * DD + j] = a; WfaTh[(size_t)j * DD + b] = f2bf(a); }
  else if (b < 512) { Wfb[(b - 256) * DD + j] = a; WfbTh[(size_t)j * DD + (b - 256)] = f2bf(a); }
  else if (b == 512) bfa[j] = a + ba[j];
  else bfb[j] = a + bb[j];
}

// ---------- osc = softmax(scale*qc@kc^T)@vc ----------
__global__ void __launch_bounds__(256) k_osc(const float* qc, const float* kc, const float* vc, float* osc){
  __shared__ float S[50][64];
  __shared__ float P[50][64];
  int t = threadIdx.x;
  for (int p = t; p < 2500; p += 256) {
    int i = p / 50, jj = p % 50;
    float s = 0.f;
    for (int k = 0; k < DD; k++) s += qc[i * DD + k] * kc[jj * DD + k];
    S[i][jj] = s * SCL;
  }
  __syncthreads();
  if (t < 50) {
    float mx = -1e30f;
    for (int jj = 0; jj < 50; jj++) mx = fmaxf(mx, S[t][jj]);
    float den = 0.f;
    for (int jj = 0; jj < 50; jj++) { float e = expf(S[t][jj] - mx); P[t][jj] = e; den += e; }
    float inv = 1.0f / den;
    for (int jj = 0; jj < 50; jj++) P[t][jj] *= inv;
  }
  __syncthreads();
  for (int i = 0; i < 50; i++) {
    float a = 0.f;
    for (int jj = 0; jj < 50; jj++) a += P[i][jj] * vc[jj * DD + t];
    osc[i * DD + t] = a;
  }
}

// ---------- gated() on 50 rows ----------
__global__ void __launch_bounds__(256) k_gated(const float* __restrict__ tin,
                                               const float* __restrict__ Wa, const float* __restrict__ Wb,
                                               const float* __restrict__ ba, const float* __restrict__ bb,
                                               const float* __restrict__ Wc, const float* __restrict__ bc,
                                               float* __restrict__ A){
  int r = blockIdx.x, j = threadIdx.x;
  __shared__ float ts[256];
  __shared__ float red[4];
  ts[j] = tin[r * DD + j];
  __syncthreads();
  float u = 0.f, v = 0.f;
  for (int k = 0; k < DD; k++) { float tv = ts[k]; u += tv * Wa[k * DD + j]; v += tv * Wb[k * DD + j]; }
  float g = tanhf(u + ba[j]) * sigmoidf_(v + bb[j]) * Wc[j];
  g = waveAllSum(g);
  int lane = j & 63, wv = j >> 6;
  if (lane == 0) red[wv] = g;
  __syncthreads();
  if (j == 0) A[r] = red[0] + red[1] + red[2] + red[3] + bc[0];
}

// ---------- fused path kernel ----------
__global__ void __launch_bounds__(256) k_path1(
    const float* __restrict__ x, const unsigned short* __restrict__ WqkvTh,
    const float* __restrict__ sln,
    const unsigned short* __restrict__ kch, const unsigned short* __restrict__ qch,
    const unsigned short* __restrict__ VcaTh, const unsigned short* __restrict__ VcbTh,
    const float* __restrict__ ba, const float* __restrict__ bb,
    const float* __restrict__ Wc, const float* __restrict__ bc,
    unsigned short* __restrict__ vph, unsigned short* __restrict__ qlh, unsigned short* __restrict__ klh,
    float* __restrict__ E, float* __restrict__ w50, float* __restrict__ edencp, float* __restrict__ occden){
  __shared__ unsigned short xsh[16][264];
  __shared__ float qps[16][260];      // later: u (gate pre-act A)
  __shared__ float kps[16][260];      // later: v (gate pre-act B)
  __shared__ float scap[16][68];
  __shared__ float scac[16][68];
  __shared__ unsigned short Psh[16][72];
  __shared__ float occs[64];
  __shared__ float redg[4][16];
  __shared__ float ev[16];
  __shared__ float edens;
  const int tid = threadIdx.x;
  const int i0 = blockIdx.x * 16;
  const int lane = tid & 63;
  const int wvv = tid >> 6;
  const int cn = lane & 15;          // MFMA col / A-row
  const int m0 = (lane >> 4) * 4;    // MFMA C row base
  const int kq = (lane >> 4) * 8;    // MFMA A/B k sub-offset

  if (tid < 64) occs[tid] = 0.f;
  if (tid == 0) edens = 0.f;
  for (int l = tid; l < 4096; l += 256) {
    int r = l >> 8, c = l & 255;
    xsh[r][c] = f2bf(x[(size_t)(MM + i0 + r) * DD + c]);
  }
  __syncthreads();

  // ---- GEMM: [16 x 256] @ [256 x 768], double-buffered B ----
  bf16x8 af[8];
  #pragma unroll
  for (int k0 = 0; k0 < 8; k0++)
    af[k0] = *(const bf16x8*)&xsh[cn][k0 * 32 + kq];
  bf16x8 b0[8], b1[8];
  {
    const size_t nrow = (size_t)(wvv * 16 + cn) * 256;
    #pragma unroll
    for (int k0 = 0; k0 < 8; k0++) b0[k0] = *(const bf16x8*)&WqkvTh[nrow + k0 * 32 + kq];
  }
  #pragma unroll 1
  for (int tt = 0; tt < 12; tt++) {
    const int t = wvv + 4 * tt;       // n-tile 0..47
    if (tt + 1 < 12) {
      const size_t nrow = (size_t)((t + 4) * 16 + cn) * 256;
      #pragma unroll
      for (int k0 = 0; k0 < 8; k0++) b1[k0] = *(const bf16x8*)&WqkvTh[nrow + k0 * 32 + kq];
    }
    f32x4 acc = {0.f, 0.f, 0.f, 0.f};
    #pragma unroll
    for (int k0 = 0; k0 < 8; k0++) acc = mfma16(af[k0], b0[k0], acc);
    if (t < 16) {
      int c = t * 16 + cn;
      #pragma unroll
      for (int i = 0; i < 4; i++) qps[m0 + i][c] = acc[i];
    } else if (t < 32) {
      int c = (t - 16) * 16 + cn;
      #pragma unroll
      for (int i = 0; i < 4; i++) kps[m0 + i][c] = acc[i];
    } else {
      int c = (t - 32) * 16 + cn;
      #pragma unroll
      for (int i = 0; i < 4; i++) vph[(size_t)(i0 + m0 + i) * DD + c] = f2bf(acc[i]);
    }
    #pragma unroll
    for (int k0 = 0; k0 < 8; k0++) b0[k0] = b1[k0];
  }
  __syncthreads();

  // ---- scores via MFMA: cap = qp@kc^T, cac = kp@qc^T ----
  {
    bf16x8 aq[8], ak[8];
    #pragma unroll
    for (int k0 = 0; k0 < 8; k0++) {
      aq[k0] = cvt8(&qps[cn][k0 * 32 + kq]);
      ak[k0] = cvt8(&kps[cn][k0 * 32 + kq]);
    }
    const int n0 = wvv * 16;
    f32x4 accp = {0.f,0.f,0.f,0.f}, accc = {0.f,0.f,0.f,0.f};
    #pragma unroll
    for (int k0 = 0; k0 < 8; k0++) {
      bf16x8 bk = *(const bf16x8*)&kch[(size_t)(n0 + cn) * DD + k0 * 32 + kq];
      bf16x8 bq = *(const bf16x8*)&qch[(size_t)(n0 + cn) * DD + k0 * 32 + kq];
      accp = mfma16(aq[k0], bk, accp);
      accc = mfma16(ak[k0], bq, accc);
    }
    #pragma unroll
    for (int i = 0; i < 4; i++) {
      scap[m0 + i][n0 + cn] = accp[i];
      scac[m0 + i][n0 + cn] = accc[i];
    }
  }
  __syncthreads();

  // ---- phase B: transforms + softmax p (wave owns 4 rows) ----
  float4 sl4 = ((const float4*)sln)[lane];
  float4 rsp;
  rsp.x = 1.0f / log1pf(expf(sl4.x)); rsp.y = 1.0f / log1pf(expf(sl4.y));
  rsp.z = 1.0f / log1pf(expf(sl4.z)); rsp.w = 1.0f / log1pf(expf(sl4.w));
  float occacc = 0.f;
  for (int rr = 0; rr < 4; rr++) {
    const int r = wvv * 4 + rr;
    const int row = i0 + r;
    float4 q4 = *(const float4*)&qps[r][lane * 4];
    float4 k4 = *(const float4*)&kps[r][lane * 4];
    float4 lq, lk;
    lq.x = (fmaxf(q4.x, 0.f) + 1e-6f) * rsp.x; lq.y = (fmaxf(q4.y, 0.f) + 1e-6f) * rsp.y;
    lq.z = (fmaxf(q4.z, 0.f) + 1e-6f) * rsp.z; lq.w = (fmaxf(q4.w, 0.f) + 1e-6f) * rsp.w;
    lk.x = (fmaxf(k4.x, 0.f) + 1e-6f) * rsp.x; lk.y = (fmaxf(k4.y, 0.f) + 1e-6f) * rsp.y;
    lk.z = (fmaxf(k4.z, 0.f) + 1e-6f) * rsp.z; lk.w = (fmaxf(k4.w, 0.f) + 1e-6f) * rsp.w;
    float4 q3, k3;
    q3.x = lq.x*lq.x*lq.x; q3.y = lq.y*lq.y*lq.y; q3.z = lq.z*lq.z*lq.z; q3.w = lq.w*lq.w*lq.w;
    k3.x = lk.x*lk.x*lk.x; k3.y = lk.y*lk.y*lk.y; k3.z = lk.z*lk.z*lk.z; k3.w = lk.w*lk.w*lk.w;
    float n1q = lq.x*lq.x + lq.y*lq.y + lq.z*lq.z + lq.w*lq.w;
    float n3q = q3.x*q3.x + q3.y*q3.y + q3.z*q3.z + q3.w*q3.w;
    float n1k = lk.x*lk.x + lk.y*lk.y + lk.z*lk.z + lk.w*lk.w;
    float n3k = k3.x*k3.x + k3.y*k3.y + k3.z*k3.z + k3.w*k3.w;
    n1q = waveAllSum(n1q); n3q = waveAllSum(n3q);
    n1k = waveAllSum(n1k); n3k = waveAllSum(n3k);
    float fq = sqrtf(n1q / n3q);
    float fk = sqrtf(n1k / n3k);
    ushort4 qo, ko;
    qo.x = f2bf(q3.x * fq); qo.y = f2bf(q3.y * fq); qo.z = f2bf(q3.z * fq); qo.w = f2bf(q3.w * fq);
    ko.x = f2bf(k3.x * fk); ko.y = f2bf(k3.y * fk); ko.z = f2bf(k3.z * fk); ko.w = f2bf(k3.w * fk);
    *(ushort4*)&qlh[(size_t)row * DD + lane * 4] = qo;
    *(ushort4*)&klh[(size_t)row * DD + lane * 4] = ko;
    float ecap = (lane < 50) ? expf(scap[r][lane] * SCL) : 0.f;
    float ecac = (lane < 50) ? expf(scac[r][lane] * SCL) : 0.f;
    E[(size_t)row * 64 + lane] = ecac;
    occacc += ecac;
    float den = waveAllSum(ecap);
    Psh[r][lane] = f2bf(ecap / den);   // p, zero for lane>=50
  }
  atomicAdd(&occs[lane], occacc);
  __syncthreads();

  // ---- gate via MFMA: u = P@Vca, v = P@Vcb (overlay into qps/kps) ----
  {
    bf16x8 ap[2];
    #pragma unroll
    for (int k0 = 0; k0 < 2; k0++) ap[k0] = *(const bf16x8*)&Psh[cn][k0 * 32 + kq];
    #pragma unroll 1
    for (int tt = 0; tt < 4; tt++) {
      const int nt = wvv * 4 + tt;
      f32x4 au = {0.f,0.f,0.f,0.f}, av = {0.f,0.f,0.f,0.f};
      #pragma unroll
      for (int k0 = 0; k0 < 2; k0++) {
        bf16x8 bu = *(const bf16x8*)&VcaTh[(size_t)(nt * 16 + cn) * 64 + k0 * 32 + kq];
        bf16x8 bv = *(const bf16x8*)&VcbTh[(size_t)(nt * 16 + cn) * 64 + k0 * 32 + kq];
        au = mfma16(ap[k0], bu, au);
        av = mfma16(ap[k0], bv, av);
      }
      #pragma unroll
      for (int i = 0; i < 4; i++) {
        qps[m0 + i][nt * 16 + cn] = au[i];
        kps[m0 + i][nt * 16 + cn] = av[i];
      }
    }
  }
  __syncthreads();

  // ---- gate eval: per-row reduce of tanh(u+ba)*sig(v+bb)*Wc ----
  const int j = tid;
  float baj = ba[j], bbj = bb[j], wcj = Wc[j];
  #pragma unroll
  for (int r = 0; r < 16; r++) {
    float g = tanhf(qps[r][j] + baj) * sigmoidf_(kps[r][j] + bbj) * wcj;
    g = waveAllSum(g);
    if (lane == 0) redg[wvv][r] = g;
  }
  __syncthreads();
  if (tid < 16) {
    float A = redg[0][tid] + redg[1][tid] + redg[2][tid] + redg[3][tid] + bc[0];
    ev[tid] = expf(A);
  }
  __syncthreads();
  if (tid < 64) {
    float s = 0.f;
    #pragma unroll
    for (int r = 0; r < 16; r++) s += ev[r] * bf2f(Psh[r][tid]);
    atomicAdd(&w50[tid], s);
    if (tid < 50) atomicAdd(&occden[tid], occs[tid]);
  }
  if (tid == 0) {
    float es = 0.f;
    #pragma unroll
    for (int r = 0; r < 16; r++) es += ev[r];
    atomicAdd(edencp, es);
  }
}

// ---------- klsum ----------
__global__ void __launch_bounds__(256) k_klsum(const unsigned short* __restrict__ klh, float* __restrict__ klsum){
  int d = threadIdx.x;
  float s = 0.f;
  size_t j0 = (size_t)blockIdx.x * 1024;
  for (int j = 0; j < 1024; j++) s += bf2f(klh[(j0 + j) * DD + d]);
  atomicAdd(&klsum[d], s);
}

// ---------- occ numerator ----------
__global__ void __launch_bounds__(256) k_occnum(const float* __restrict__ E, const unsigned short* __restrict__ vph,
                                                float* __restrict__ occraw){
  int d = threadIdx.x;
  int j0 = blockIdx.x * 512;
  __shared__ float Es[32][64];
  float acc[52];
  #pragma unroll
  for (int i = 0; i < 52; i++) acc[i] = 0.f;
  for (int s = 0; s < 16; s++) {
    for (int l = threadIdx.x; l < 512; l += 256) {
      int jj = l >> 4, cq = l & 15;
      *(float4*)&Es[jj][cq * 4] = ((const float4*)(E + (size_t)(j0 + s * 32 + jj) * 64))[cq];
    }
    __syncthreads();
    for (int jj = 0; jj < 32; jj++) {
      float vv = bf2f(vph[(size_t)(j0 + s * 32 + jj) * DD + d]);
      #pragma unroll
      for (int q = 0; q < 13; q++) {
        float4 e4 = *(const float4*)&Es[jj][q * 4];
        acc[q * 4 + 0] += e4.x * vv; acc[q * 4 + 1] += e4.y * vv;
        acc[q * 4 + 2] += e4.z * vv; acc[q * 4 + 3] += e4.w * vv;
      }
    }
    __syncthreads();
  }
  for (int i = 0; i < 50; i++) atomicAdd(&occraw[i * DD + d], acc[i]);
}

__global__ void __launch_bounds__(256) k_occfin(const float* __restrict__ occraw, const float* __restrict__ occden,
                                                float* __restrict__ occ){
  int i = blockIdx.x, d = threadIdx.x;
  occ[i * DD + d] = occraw[i * DD + d] / occden[i];
}

// ---------- kv = kl^T @ vp via MFMA, split-K, bf16 partials into E region ----------
// grid (2 c-bands, 128 z-chunks). Fragments built from row-major klh/vph with strided loads.
__global__ void __launch_bounds__(256, 1) k_kv(const unsigned short* __restrict__ klh,
                                               const unsigned short* __restrict__ vph,
                                               unsigned short* __restrict__ PP){
  const int tid = threadIdx.x;
  const int lane = tid & 63;
  const int wvv = tid >> 6;
  const int cn = lane & 15;
  const int m0 = (lane >> 4) * 4;
  const int kq = (lane >> 4) * 8;
  const int cb = blockIdx.x;          // c band (128 wide)
  const int z  = blockIdx.y;          // j chunk (512 rows)
  f32x4 acc[8][4];
  #pragma unroll
  for (int mt = 0; mt < 8; mt++)
    #pragma unroll
    for (int tl = 0; tl < 4; tl++) acc[mt][tl] = (f32x4){0.f,0.f,0.f,0.f};

  const int jbase = z * 512;
  #pragma unroll 1
  for (int step = 0; step < 16; step++) {
    const int j0 = jbase + step * 32;
    const unsigned short* arow = klh + (size_t)(j0 + kq) * 256 + cb * 128 + cn;
    const unsigned short* brow = vph + (size_t)(j0 + kq) * 256 + (wvv * 4) * 16 + cn;
    bf16x8 afr[8], bfr[4];
    #pragma unroll
    for (int mt = 0; mt < 8; mt++) afr[mt] = frag_strided(arow + mt * 16, 256);
    #pragma unroll
    for (int tl = 0; tl < 4; tl++) bfr[tl] = frag_strided(brow + tl * 16, 256);
    #pragma unroll
    for (int mt = 0; mt < 8; mt++)
      #pragma unroll
      for (int tl = 0; tl < 4; tl++) acc[mt][tl] = mfma16(afr[mt], bfr[tl], acc[mt][tl]);
  }
  unsigned short* P = PP + ((size_t)(cb * 128 + z)) * 32768;
  #pragma unroll
  for (int mt = 0; mt < 8; mt++)
    #pragma unroll
    for (int tl = 0; tl < 4; tl++) {
      const int n = (wvv * 4 + tl) * 16 + cn;
      #pragma unroll
      for (int i = 0; i < 4; i++)
        P[(size_t)(mt * 16 + m0 + i) * 256 + n] = f2bf(acc[mt][tl][i]);
    }
}

// ---------- reduce partials -> kv^T bf16 ----------
__global__ void __launch_bounds__(256) k_kvred(const unsigned short* __restrict__ PP,
                                               unsigned short* __restrict__ kvTh){
  int c = blockIdx.x, d = threadIdx.x;
  int cb = c >> 7, m = c & 127;
  float s = 0.f;
  for (int z = 0; z < 128; z++)
    s += bf2f(PP[((size_t)(cb * 128 + z)) * 32768 + (size_t)m * 256 + d]);
  kvTh[(size_t)d * 256 + c] = f2bf(s);
}

// ---------- fused tail: OS=(ql@kv)*zfac + conv -> T (LDS) -> gate -> h2 ----------
__global__ void __launch_bounds__(256) k_tail(const unsigned short* __restrict__ qlh,
                                              const unsigned short* __restrict__ kvTh,
                                              const float* __restrict__ klsum,
                                              const unsigned short* __restrict__ vph,
                                              const float* __restrict__ dwcw, const float* __restrict__ dwcb,
                                              const unsigned short* __restrict__ WfaTh,
                                              const unsigned short* __restrict__ WfbTh,
                                              const float* __restrict__ bfa, const float* __restrict__ bfb,
                                              const float* __restrict__ Wc, const float* __restrict__ bc,
                                              float* __restrict__ h2t, float* __restrict__ h2den){
  __shared__ unsigned short ABsh[16][264];  // ql staging, later T (bf16)
  __shared__ float OSs[16][260];            // OS, later aU
  __shared__ float aVs[16][260];
  __shared__ float red[4][16];
  __shared__ float zf[16];
  __shared__ float ev[16];
  const int tid = threadIdx.x;
  const int i0 = blockIdx.x * 16;
  const int lane = tid & 63;
  const int wvv = tid >> 6;
  const int cn = lane & 15;
  const int m0 = (lane >> 4) * 4;
  const int kq = (lane >> 4) * 8;
  for (int l = tid; l < 1024; l += 256) {
    int r = l >> 6, c4 = (l & 63) * 4;
    *(ushort4*)&ABsh[r][c4] = *(const ushort4*)&qlh[(size_t)(i0 + r) * DD + c4];
  }
  __syncthreads();
  // OS = ql @ kv
  {
    bf16x8 afq[8];
    #pragma unroll
    for (int k0 = 0; k0 < 8; k0++) afq[k0] = *(const bf16x8*)&ABsh[cn][k0 * 32 + kq];
    #pragma unroll 1
    for (int tt = 0; tt < 4; tt++) {
      const int nt = wvv * 4 + tt;
      f32x4 acc = {0.f,0.f,0.f,0.f};
      #pragma unroll
      for (int k0 = 0; k0 < 8; k0++) {
        bf16x8 b = *(const bf16x8*)&kvTh[(size_t)(nt * 16 + cn) * 256 + k0 * 32 + kq];
        acc = mfma16(afq[k0], b, acc);
      }
      #pragma unroll
      for (int i = 0; i < 4; i++) OSs[m0 + i][nt * 16 + cn] = acc[i];
    }
  }
  // zfac (reads ql staging)
  const int j = tid;
  float ks = klsum[j];
  #pragma unroll
  for (int r = 0; r < 16; r++) {
    float t = bf2f(ABsh[r][j]) * ks;
    t = waveAllSum(t);
    if (lane == 0) red[wvv][r] = t;
  }
  __syncthreads();
  if (tid < 16) {
    float t = red[0][tid] + red[1][tid] + red[2][tid] + red[3][tid];
    zf[tid] = 1.0f / (t + 1e-6f);
  }
  __syncthreads();
  // conv + T (overwrite ABsh; keep fp32 copy in regs)
  float w[25];
  #pragma unroll
  for (int t = 0; t < 25; t++) w[t] = dwcw[j * 25 + t];
  float bias = dwcb[j];
  const int y = i0 >> 8, x0 = i0 & 255;
  float Tf[16];
  for (int r = 0; r < 16; r++) {
    int xx0 = x0 + r;
    float fm = bias;
    #pragma unroll
    for (int dy = -2; dy <= 2; dy++) {
      int yy = y + dy;
      if ((unsigned)yy > 255u) continue;
      #pragma unroll
      for (int dx = -2; dx <= 2; dx++) {
        int xx = xx0 + dx;
        if ((unsigned)xx > 255u) continue;
        fm += bf2f(vph[(size_t)((yy << 8) + xx) * DD + j]) * w[(dy + 2) * 5 + (dx + 2)];
      }
    }
    Tf[r] = OSs[r][j] * zf[r] + fm;
    ABsh[r][j] = f2bf(Tf[r]);
  }
  __syncthreads();
  // aU = T@Wfa (into OSs), aV = T@Wfb
  {
    bf16x8 aft[8];
    #pragma unroll
    for (int k0 = 0; k0 < 8; k0++) aft[k0] = *(const bf16x8*)&ABsh[cn][k0 * 32 + kq];
    #pragma unroll 1
    for (int jb = 0; jb < 8; jb++) {
      const int nt = wvv * 4 + (jb & 3);
      const unsigned short* Bt = (jb < 4) ? WfaTh : WfbTh;
      f32x4 acc = {0.f,0.f,0.f,0.f};
      #pragma unroll
      for (int k0 = 0; k0 < 8; k0++) {
        bf16x8 b = *(const bf16x8*)&Bt[(size_t)(nt * 16 + cn) * 256 + k0 * 32 + kq];
        acc = mfma16(aft[k0], b, acc);
      }
      float (*dst)[260] = (jb < 4) ? OSs : aVs;
      #pragma unroll
      for (int i = 0; i < 4; i++) dst[m0 + i][nt * 16 + cn] = acc[i];
    }
  }
  __syncthreads();
  // gate
  float bfaj = bfa[j], bfbj = bfb[j], wcj = Wc[j];
  #pragma unroll
  for (int r = 0; r < 16; r++) {
    float g = tanhf(OSs[r][j] + bfaj) * sigmoidf_(aVs[r][j] + bfbj) * wcj;
    g = waveAllSum(g);
    if (lane == 0) red[wvv][r] = g;
  }
  __syncthreads();
  if (tid < 16) {
    float A = red[0][tid] + red[1][tid] + red[2][tid] + red[3][tid] + bc[0];
    ev[tid] = expf(A);
  }
  __syncthreads();
  float hp = 0.f;
  #pragma unroll
  for (int r = 0; r < 16; r++) hp += ev[r] * Tf[r];
  atomicAdd(&h2t[j], hp);
  if (tid == 0) {
    float es = 0.f;
    #pragma unroll
    for (int r = 0; r < 16; r++) es += ev[r];
    atomicAdd(h2den, es);
  }
}

// ---------- final tiny MLPs ----------
__global__ void __launch_bounds__(256) k_final(
    const float* __restrict__ A_cc, const float* __restrict__ occ,
    const float* __restrict__ A_sc, const float* __restrict__ osc,
    const float* __restrict__ w50, const float* __restrict__ edencp,
    const float* __restrict__ h2t, const float* __restrict__ h2den,
    const float* __restrict__ vc, const float* __restrict__ Wf, const float* __restrict__ bf,
    const float* __restrict__ W1, const float* __restrict__ b1,
    const float* __restrict__ W2, const float* __restrict__ b2,
    const float* __restrict__ W3a, const float* __restrict__ b3a,
    const float* __restrict__ W3b, const float* __restrict__ b3b,
    float* __restrict__ out){
  int j = threadIdx.x;
  __shared__ float pw[64];
  __shared__ float t1[256], t2[256], h1[256], h2[256], fz[512], z1[256];
  // ===== CROSS =====
  if (j < 64) pw[j] = (j < 50) ? expf(A_cc[j]) : 0.f;
  __syncthreads();
  float den = 0.f;
  for (int i = 0; i < 50; i++) den += pw[i];
  float raw = 0.f;
  for (int i = 0; i < 50; i++) raw += pw[i] * occ[i * DD + j];
  t1[j] = raw / den;
  float r2 = 0.f;
  for (int i = 0; i < 50; i++) r2 += w50[i] * vc[i * DD + j];
  t2[j] = r2 / edencp[0];
  __syncthreads();
  float a1 = 0.f, a2 = 0.f;
  for (int k = 0; k < DD; k++) { a1 += t1[k] * W1[k * DD + j]; a2 += t2[k] * W2[k * DD + j]; }
  h1[j] = fmaxf(a1 + b1[j], 0.f);
  h2[j] = fmaxf(a2 + b2[j], 0.f);
  __syncthreads();
  fz[j] = h1[j]; fz[256 + j] = h2[j];
  __syncthreads();
  float z = 0.f;
  for (int k = 0; k < 512; k++) z += fz[k] * W3a[k * DD + j];
  z1[j] = fmaxf(z + b3a[j], 0.f);
  __syncthreads();
  float o = 0.f;
  for (int k = 0; k < DD; k++) o += z1[k] * W3b[k * DD + j];
  out[j] = fmaxf(o + b3b[j], 0.f);
  __syncthreads();
  // ===== SELF =====
  if (j < 64) pw[j] = (j < 50) ? expf(A_sc[j]) : 0.f;
  __syncthreads();
  den = 0.f;
  for (int i = 0; i < 50; i++) den += pw[i];
  raw = 0.f;
  for (int i = 0; i < 50; i++) raw += pw[i] * osc[i * DD + j];
  t1[j] = raw / den;
  t2[j] = h2t[j] / h2den[0];
  __syncthreads();
  float hs = 0.f;
  for (int k = 0; k < DD; k++) hs += t2[k] * Wf[k * DD + j];
  __syncthreads();
  t2[j] = hs + bf[j];
  __syncthreads();
  a1 = 0.f; a2 = 0.f;
  for (int k = 0; k < DD; k++) { a1 += t1[k] * W1[k * DD + j]; a2 += t2[k] * W2[k * DD + j]; }
  h1[j] = fmaxf(a1 + b1[j], 0.f);
  h2[j] = fmaxf(a2 + b2[j], 0.f);
  __syncthreads();
  fz[j] = h1[j]; fz[256 + j] = h2[j];
  __syncthreads();
  z = 0.f;
  for (int k = 0; k < 512; k++) z += fz[k] * W3a[k * DD + j];
  z1[j] = fmaxf(z + b3a[j], 0.f);
  __syncthreads();
  o = 0.f;
  for (int k = 0; k < DD; k++) o += z1[k] * W3b[k * DD + j];
  out[256 + j] = fmaxf(o + b3b[j], 0.f);
}

extern "C" void kernel_launch(void* const* d_in, const int* in_sizes, int n_in,
                              void* d_out, int out_size, void* d_ws, size_t ws_size,
                              hipStream_t stream) {
  if (ws_size < WS_NEEDED) return;
  const float* x   = (const float*)d_in[0];
  const float* Wqkv= (const float*)d_in[1];
  const float* sln = (const float*)d_in[2];
  const float* dwcw= (const float*)d_in[3];
  const float* dwcb= (const float*)d_in[4];
  const float* Wa  = (const float*)d_in[5];
  const float* ba  = (const float*)d_in[6];
  const float* Wb  = (const float*)d_in[7];
  const float* bb  = (const float*)d_in[8];
  const float* Wc  = (const float*)d_in[9];
  const float* bc  = (const float*)d_in[10];
  const float* W1  = (const float*)d_in[11];
  const float* b1  = (const float*)d_in[12];
  const float* W2  = (const float*)d_in[13];
  const float* b2  = (const float*)d_in[14];
  const float* W3a = (const float*)d_in[15];
  const float* b3a = (const float*)d_in[16];
  const float* W3b = (const float*)d_in[17];
  const float* b3b = (const float*)d_in[18];
  const float* Wf  = (const float*)d_in[19];
  const float* bf  = (const float*)d_in[20];

  char* wsb = (char*)d_ws;
  unsigned short* VPH = (unsigned short*)(wsb + B_VPH);
  unsigned short* QLH = (unsigned short*)(wsb + B_QLH);
  unsigned short* KLH = (unsigned short*)(wsb + B_KLH);
  float* EB = (float*)(wsb + B_E);                        // E fp32; later bf16 kv partials
  float* SM = (float*)(wsb + B_SM);
  unsigned short* XT = (unsigned short*)(wsb + B_X);
  float* outp = (float*)d_out;

  hipMemsetAsync((void*)SM, 0, ZEND * sizeof(float), stream);

  k_cqkv<<<50, 256, 0, stream>>>(x, Wqkv, SM + QC, SM + KC, SM + VC, XT + XT_QCH, XT + XT_KCH);
  k_wqkvT<<<768, 256, 0, stream>>>(Wqkv, XT + XT_WQKV);
  k_vcab<<<50, 256, 0, stream>>>(SM + VC, Wa, Wb, SM + VCA, SM + VCB, XT + XT_VCAT, XT + XT_VCBT);
  k_wfab<<<514, 256, 0, stream>>>(Wf, Wa, Wb, ba, bb, bf, SM + WFA, SM + WFB, SM + BFA, SM + BFB,
                                  XT + XT_WFAT, XT + XT_WFBT);
  k_osc<<<1, 256, 0, stream>>>(SM + QC, SM + KC, SM + VC, SM + OSCB);
  k_gated<<<50, 256, 0, stream>>>(SM + OSCB, Wa, Wb, ba, bb, Wc, bc, SM + ASC);

  k_path1<<<4096, 256, 0, stream>>>(x, XT + XT_WQKV, sln, XT + XT_KCH, XT + XT_QCH,
                                    XT + XT_VCAT, XT + XT_VCBT, ba, bb, Wc, bc,
                                    VPH, QLH, KLH, EB, SM + W50, SM + EDENC, SM + OCCDEN);
  k_klsum<<<64, 256, 0, stream>>>(KLH, SM + KLSUM);
  k_occnum<<<128, 256, 0, stream>>>(EB, VPH, SM + OCCRAW);
  k_occfin<<<50, 256, 0, stream>>>(SM + OCCRAW, SM + OCCDEN, SM + OCCB);
  k_gated<<<50, 256, 0, stream>>>(SM + OCCB, Wa, Wb, ba, bb, Wc, bc, SM + ACC50);

  k_kv<<<dim3(2, 128), 256, 0, stream>>>(KLH, VPH, (unsigned short*)EB);  // partials over dead E
  k_kvred<<<256, 256, 0, stream>>>((const unsigned short*)EB, XT + XT_KVT);

  k_tail<<<4096, 256, 0, stream>>>(QLH, XT + XT_KVT, SM + KLSUM, VPH, dwcw, dwcb,
                                   XT + XT_WFAT, XT + XT_WFBT, SM + BFA, SM + BFB,
                                   Wc, bc, SM + H2T, SM + H2DEN);

  k_final<<<1, 256, 0, stream>>>(SM + ACC50, SM + OCCB, SM + ASC, SM + OSCB,
                                 SM + W50, SM + EDENC, SM + H2T, SM + H2DEN,
                                 SM + VC, Wf, bf, W1, b1, W2, b2, W3a, b3a, W3b, b3b, outp);
}

// Round 5
// 1074.155 us; speedup vs baseline: 1.8774x; 1.2017x over previous
//
#include <hip/hip_runtime.h>
#include <math.h>

// MixedAttentionLayer — R5: k_tail rewrite (register-tiled conv, wave-local
// row reductions), k_path1 gate-eval re-map, widened reductions, merged prep.

constexpr int DD = 256;
constexpr int MM = 50;
constexpr float SCL = 0.0625f; // 256^-0.5

// ---- byte offsets in d_ws ----
constexpr size_t B_VPH = 0;                      // 32 MiB bf16 vp
constexpr size_t B_QLH = (size_t)32 << 20;       // 32 MiB bf16 ql
constexpr size_t B_KLH = (size_t)64 << 20;       // 32 MiB bf16 kl
constexpr size_t B_E   = (size_t)96 << 20;       // 16 MiB f32 E; later bf16 kv partials
constexpr size_t B_SM  = (size_t)112 << 20;      // small fp32 region
constexpr size_t B_X   = B_SM + ((size_t)2 << 20); // bf16 prep region

// ---- float offsets within SM region ----
constexpr size_t KLSUM  = 0;
constexpr size_t OCCDEN = 256;
constexpr size_t W50    = 320;
constexpr size_t EDENC  = 384;
constexpr size_t H2T    = 392;
constexpr size_t H2DEN  = 648;
constexpr size_t OCCRAW = 656;
constexpr size_t ZEND   = 13456;
constexpr size_t QC     = 13456;
constexpr size_t KC     = QC + 12800;
constexpr size_t VC     = KC + 12800;
constexpr size_t VCA    = VC + 12800;
constexpr size_t VCB    = VCA + 12800;
constexpr size_t WFA    = VCB + 12800;
constexpr size_t WFB    = WFA + 65536;
constexpr size_t BFA    = WFB + 65536;
constexpr size_t BFB    = BFA + 256;
constexpr size_t OSCB   = BFB + 256;
constexpr size_t OCCB   = OSCB + 12800;
constexpr size_t ASC    = OCCB + 12800;
constexpr size_t ACC50  = ASC + 64;
constexpr size_t SMEND  = ACC50 + 64;

// ---- short offsets within X (bf16 prep) region ----
constexpr size_t XT_WQKV = 0;          // 768*256
constexpr size_t XT_WFAT = 196608;     // 256*256  (Wfa^T)
constexpr size_t XT_WFBT = 262144;     // 256*256
constexpr size_t XT_KVT  = 327680;     // 256*256  (kv^T)
constexpr size_t XT_QCH  = 393216;     // 64*256 (qc, rows 50..63 zero)
constexpr size_t XT_KCH  = 409600;     // 64*256
constexpr size_t XT_VCAT = 425984;     // 256*64 (Vca^T, cols 50..63 zero)
constexpr size_t XT_VCBT = 442368;     // 256*64
constexpr size_t XT_END  = 458752;
constexpr size_t WS_NEEDED = B_X + XT_END * 2;

typedef short bf16x8 __attribute__((ext_vector_type(8)));
typedef float f32x4 __attribute__((ext_vector_type(4)));

__device__ __forceinline__ float sigmoidf_(float x){ return 1.0f / (1.0f + expf(-x)); }

__device__ __forceinline__ float bf2f(unsigned short u){
  return __uint_as_float(((unsigned int)u) << 16);
}
__device__ __forceinline__ unsigned short f2bf(float f){
  unsigned int x = __float_as_uint(f);
  unsigned int r = (x + 0x7fffu + ((x >> 16) & 1u)) >> 16;
  return (unsigned short)r;
}
__device__ __forceinline__ bf16x8 cvt8(const float* p){
  bf16x8 r;
  #pragma unroll
  for (int i = 0; i < 8; i++) r[i] = (short)f2bf(p[i]);
  return r;
}
__device__ __forceinline__ f32x4 mfma16(bf16x8 a, bf16x8 b, f32x4 c){
  return __builtin_amdgcn_mfma_f32_16x16x32_bf16(a, b, c, 0, 0, 0);
}
__device__ __forceinline__ bf16x8 frag_strided(const unsigned short* base, int stride){
  bf16x8 r;
  #pragma unroll
  for (int i = 0; i < 8; i++) r[i] = (short)base[(size_t)i * stride];
  return r;
}

__device__ __forceinline__ float waveAllSum(float v){
  #pragma unroll
  for (int m = 1; m < 64; m <<= 1) v += __shfl_xor(v, m, 64);
  return v;
}

// ---------- prep0: Wqkv^T (blocks 0..767) + qc/kc/vc (blocks 768..817) ----------
__global__ void __launch_bounds__(256) k_prep0(const float* __restrict__ x, const float* __restrict__ Wqkv,
                                               float* qc, float* kc, float* vc,
                                               unsigned short* qch, unsigned short* kch,
                                               unsigned short* __restrict__ WT){
  __shared__ float xs[256];
  const int b = blockIdx.x, j = threadIdx.x;
  if (b < 768) {
    WT[(size_t)b * 256 + j] = f2bf(Wqkv[(size_t)j * 768 + b]);
    return;
  }
  const int r = b - 768;
  xs[j] = x[r * DD + j];
  __syncthreads();
  float aq = 0.f, ak = 0.f, av = 0.f;
  for (int k = 0; k < DD; k++) {
    float xv = xs[k];
    aq += xv * Wqkv[k * 768 + j];
    ak += xv * Wqkv[k * 768 + 256 + j];
    av += xv * Wqkv[k * 768 + 512 + j];
  }
  qc[r * DD + j] = aq; kc[r * DD + j] = ak; vc[r * DD + j] = av;
  qch[r * DD + j] = f2bf(aq); kch[r * DD + j] = f2bf(ak);
  if (r == 0) {
    for (int c = 50; c < 64; c++) { qch[c * DD + j] = 0; kch[c * DD + j] = 0; }
  }
}

// ---------- prep1: Vca/Vcb (blocks 0..49) + Wfa/Wfb/bfa/bfb (blocks 50..563) ----------
__global__ void __launch_bounds__(256) k_prep1(const float* vc, const float* Wa, const float* Wb,
                                               const float* ba, const float* bb,
                                               const float* Wf, const float* bf,
                                               float* Vca, float* Vcb,
                                               unsigned short* VcaTh, unsigned short* VcbTh,
                                               float* Wfa, float* Wfb, float* bfa, float* bfb,
                                               unsigned short* WfaTh, unsigned short* WfbTh){
  __shared__ float rs[256];
  const int b = blockIdx.x, j = threadIdx.x;
  if (b < 50) {
    const int r = b;
    rs[j] = vc[r * DD + j];
    __syncthreads();
    float a = 0.f, bv = 0.f;
    for (int k = 0; k < DD; k++) { float v = rs[k]; a += v * Wa[k * DD + j]; bv += v * Wb[k * DD + j]; }
    Vca[r * DD + j] = a; Vcb[r * DD + j] = bv;
    VcaTh[j * 64 + r] = f2bf(a); VcbTh[j * 64 + r] = f2bf(bv);
    if (r == 0) {
      for (int c = 50; c < 64; c++) { VcaTh[j * 64 + c] = 0; VcbTh[j * 64 + c] = 0; }
    }
    return;
  }
  const int bb2 = b - 50;
  const float* src; const float* Wm;
  if (bb2 < 256)      { src = Wf + bb2 * DD;         Wm = Wa; }
  else if (bb2 < 512) { src = Wf + (bb2 - 256) * DD; Wm = Wb; }
  else if (bb2 == 512){ src = bf;                    Wm = Wa; }
  else                { src = bf;                    Wm = Wb; }
  rs[j] = src[j];
  __syncthreads();
  float a = 0.f;
  for (int k = 0; k < DD; k++) a += rs[k] * Wm[k * DD + j];
  if (bb2 < 256)      { Wfa[bb2 * DD + j] = a; WfaTh[(size_t)j * DD + bb2] = f2bf(a); }
  else if (bb2 < 512) { Wfb[(bb2 - 256) * DD + j] = a; WfbTh[(size_t)j * DD + (bb2 - 256)] = f2bf(a); }
  else if (bb2 == 512) bfa[j] = a + ba[j];
  else bfb[j] = a + bb[j];
}

// ---------- osc = softmax(scale*qc@kc^T)@vc ----------
__global__ void __launch_bounds__(256) k_osc(const float* qc, const float* kc, const float* vc, float* osc){
  __shared__ float S[50][64];
  __shared__ float P[50][64];
  int t = threadIdx.x;
  for (int p = t; p < 2500; p += 256) {
    int i = p / 50, jj = p % 50;
    float s = 0.f;
    for (int k = 0; k < DD; k++) s += qc[i * DD + k] * kc[jj * DD + k];
    S[i][jj] = s * SCL;
  }
  __syncthreads();
  if (t < 50) {
    float mx = -1e30f;
    for (int jj = 0; jj < 50; jj++) mx = fmaxf(mx, S[t][jj]);
    float den = 0.f;
    for (int jj = 0; jj < 50; jj++) { float e = expf(S[t][jj] - mx); P[t][jj] = e; den += e; }
    float inv = 1.0f / den;
    for (int jj = 0; jj < 50; jj++) P[t][jj] *= inv;
  }
  __syncthreads();
  for (int i = 0; i < 50; i++) {
    float a = 0.f;
    for (int jj = 0; jj < 50; jj++) a += P[i][jj] * vc[jj * DD + t];
    osc[i * DD + t] = a;
  }
}

// ---------- gated() on 50 rows ----------
__global__ void __launch_bounds__(256) k_gated(const float* __restrict__ tin,
                                               const float* __restrict__ Wa, const float* __restrict__ Wb,
                                               const float* __restrict__ ba, const float* __restrict__ bb,
                                               const float* __restrict__ Wc, const float* __restrict__ bc,
                                               float* __restrict__ A){
  int r = blockIdx.x, j = threadIdx.x;
  __shared__ float ts[256];
  __shared__ float red[4];
  ts[j] = tin[r * DD + j];
  __syncthreads();
  float u = 0.f, v = 0.f;
  for (int k = 0; k < DD; k++) { float tv = ts[k]; u += tv * Wa[k * DD + j]; v += tv * Wb[k * DD + j]; }
  float g = tanhf(u + ba[j]) * sigmoidf_(v + bb[j]) * Wc[j];
  g = waveAllSum(g);
  int lane = j & 63, wv = j >> 6;
  if (lane == 0) red[wv] = g;
  __syncthreads();
  if (j == 0) A[r] = red[0] + red[1] + red[2] + red[3] + bc[0];
}

// ---------- fused path kernel ----------
__global__ void __launch_bounds__(256) k_path1(
    const float* __restrict__ x, const unsigned short* __restrict__ WqkvTh,
    const float* __restrict__ sln,
    const unsigned short* __restrict__ kch, const unsigned short* __restrict__ qch,
    const unsigned short* __restrict__ VcaTh, const unsigned short* __restrict__ VcbTh,
    const float* __restrict__ ba, const float* __restrict__ bb,
    const float* __restrict__ Wc, const float* __restrict__ bc,
    unsigned short* __restrict__ vph, unsigned short* __restrict__ qlh, unsigned short* __restrict__ klh,
    float* __restrict__ E, float* __restrict__ w50, float* __restrict__ edencp, float* __restrict__ occden){
  __shared__ unsigned short xsh[16][264];
  __shared__ float qps[16][260];      // later: u (gate pre-act A)
  __shared__ float kps[16][260];      // later: v (gate pre-act B)
  __shared__ float scap[16][68];
  __shared__ float scac[16][68];
  __shared__ unsigned short Psh[16][72];
  __shared__ float occs[64];
  __shared__ float evp[16];
  __shared__ float edens;
  const int tid = threadIdx.x;
  const int i0 = blockIdx.x * 16;
  const int lane = tid & 63;
  const int wvv = tid >> 6;
  const int cn = lane & 15;
  const int m0 = (lane >> 4) * 4;
  const int kq = (lane >> 4) * 8;

  if (tid < 64) occs[tid] = 0.f;
  if (tid == 0) edens = 0.f;
  for (int l = tid; l < 4096; l += 256) {
    int r = l >> 8, c = l & 255;
    xsh[r][c] = f2bf(x[(size_t)(MM + i0 + r) * DD + c]);
  }
  __syncthreads();

  // ---- GEMM: [16 x 256] @ [256 x 768], double-buffered B ----
  bf16x8 af[8];
  #pragma unroll
  for (int k0 = 0; k0 < 8; k0++)
    af[k0] = *(const bf16x8*)&xsh[cn][k0 * 32 + kq];
  bf16x8 b0[8], b1[8];
  {
    const size_t nrow = (size_t)(wvv * 16 + cn) * 256;
    #pragma unroll
    for (int k0 = 0; k0 < 8; k0++) b0[k0] = *(const bf16x8*)&WqkvTh[nrow + k0 * 32 + kq];
  }
  #pragma unroll 1
  for (int tt = 0; tt < 12; tt++) {
    const int t = wvv + 4 * tt;       // n-tile 0..47
    if (tt + 1 < 12) {
      const size_t nrow = (size_t)((t + 4) * 16 + cn) * 256;
      #pragma unroll
      for (int k0 = 0; k0 < 8; k0++) b1[k0] = *(const bf16x8*)&WqkvTh[nrow + k0 * 32 + kq];
    }
    f32x4 acc = {0.f, 0.f, 0.f, 0.f};
    #pragma unroll
    for (int k0 = 0; k0 < 8; k0++) acc = mfma16(af[k0], b0[k0], acc);
    if (t < 16) {
      int c = t * 16 + cn;
      #pragma unroll
      for (int i = 0; i < 4; i++) qps[m0 + i][c] = acc[i];
    } else if (t < 32) {
      int c = (t - 16) * 16 + cn;
      #pragma unroll
      for (int i = 0; i < 4; i++) kps[m0 + i][c] = acc[i];
    } else {
      int c = (t - 32) * 16 + cn;
      #pragma unroll
      for (int i = 0; i < 4; i++) vph[(size_t)(i0 + m0 + i) * DD + c] = f2bf(acc[i]);
    }
    #pragma unroll
    for (int k0 = 0; k0 < 8; k0++) b0[k0] = b1[k0];
  }
  __syncthreads();

  // ---- scores via MFMA: cap = qp@kc^T, cac = kp@qc^T ----
  {
    bf16x8 aq[8], ak[8];
    #pragma unroll
    for (int k0 = 0; k0 < 8; k0++) {
      aq[k0] = cvt8(&qps[cn][k0 * 32 + kq]);
      ak[k0] = cvt8(&kps[cn][k0 * 32 + kq]);
    }
    const int n0 = wvv * 16;
    f32x4 accp = {0.f,0.f,0.f,0.f}, accc = {0.f,0.f,0.f,0.f};
    #pragma unroll
    for (int k0 = 0; k0 < 8; k0++) {
      bf16x8 bk = *(const bf16x8*)&kch[(size_t)(n0 + cn) * DD + k0 * 32 + kq];
      bf16x8 bq = *(const bf16x8*)&qch[(size_t)(n0 + cn) * DD + k0 * 32 + kq];
      accp = mfma16(aq[k0], bk, accp);
      accc = mfma16(ak[k0], bq, accc);
    }
    #pragma unroll
    for (int i = 0; i < 4; i++) {
      scap[m0 + i][n0 + cn] = accp[i];
      scac[m0 + i][n0 + cn] = accc[i];
    }
  }
  __syncthreads();

  // ---- phase B: transforms + softmax p (wave owns 4 rows) ----
  float4 sl4 = ((const float4*)sln)[lane];
  float4 rsp;
  rsp.x = 1.0f / log1pf(expf(sl4.x)); rsp.y = 1.0f / log1pf(expf(sl4.y));
  rsp.z = 1.0f / log1pf(expf(sl4.z)); rsp.w = 1.0f / log1pf(expf(sl4.w));
  float4 ba4 = ((const float4*)ba)[lane];
  float4 bb4 = ((const float4*)bb)[lane];
  float4 wc4 = ((const float4*)Wc)[lane];
  float bcv = bc[0];
  float occacc = 0.f;
  for (int rr = 0; rr < 4; rr++) {
    const int r = wvv * 4 + rr;
    const int row = i0 + r;
    float4 q4 = *(const float4*)&qps[r][lane * 4];
    float4 k4 = *(const float4*)&kps[r][lane * 4];
    float4 lq, lk;
    lq.x = (fmaxf(q4.x, 0.f) + 1e-6f) * rsp.x; lq.y = (fmaxf(q4.y, 0.f) + 1e-6f) * rsp.y;
    lq.z = (fmaxf(q4.z, 0.f) + 1e-6f) * rsp.z; lq.w = (fmaxf(q4.w, 0.f) + 1e-6f) * rsp.w;
    lk.x = (fmaxf(k4.x, 0.f) + 1e-6f) * rsp.x; lk.y = (fmaxf(k4.y, 0.f) + 1e-6f) * rsp.y;
    lk.z = (fmaxf(k4.z, 0.f) + 1e-6f) * rsp.z; lk.w = (fmaxf(k4.w, 0.f) + 1e-6f) * rsp.w;
    float4 q3, k3;
    q3.x = lq.x*lq.x*lq.x; q3.y = lq.y*lq.y*lq.y; q3.z = lq.z*lq.z*lq.z; q3.w = lq.w*lq.w*lq.w;
    k3.x = lk.x*lk.x*lk.x; k3.y = lk.y*lk.y*lk.y; k3.z = lk.z*lk.z*lk.z; k3.w = lk.w*lk.w*lk.w;
    float n1q = lq.x*lq.x + lq.y*lq.y + lq.z*lq.z + lq.w*lq.w;
    float n3q = q3.x*q3.x + q3.y*q3.y + q3.z*q3.z + q3.w*q3.w;
    float n1k = lk.x*lk.x + lk.y*lk.y + lk.z*lk.z + lk.w*lk.w;
    float n3k = k3.x*k3.x + k3.y*k3.y + k3.z*k3.z + k3.w*k3.w;
    n1q = waveAllSum(n1q); n3q = waveAllSum(n3q);
    n1k = waveAllSum(n1k); n3k = waveAllSum(n3k);
    float fq = sqrtf(n1q / n3q);
    float fk = sqrtf(n1k / n3k);
    ushort4 qo, ko;
    qo.x = f2bf(q3.x * fq); qo.y = f2bf(q3.y * fq); qo.z = f2bf(q3.z * fq); qo.w = f2bf(q3.w * fq);
    ko.x = f2bf(k3.x * fk); ko.y = f2bf(k3.y * fk); ko.z = f2bf(k3.z * fk); ko.w = f2bf(k3.w * fk);
    *(ushort4*)&qlh[(size_t)row * DD + lane * 4] = qo;
    *(ushort4*)&klh[(size_t)row * DD + lane * 4] = ko;
    float ecap = (lane < 50) ? expf(scap[r][lane] * SCL) : 0.f;
    float ecac = (lane < 50) ? expf(scac[r][lane] * SCL) : 0.f;
    E[(size_t)row * 64 + lane] = ecac;
    occacc += ecac;
    float den = waveAllSum(ecap);
    Psh[r][lane] = f2bf(ecap / den);   // p, zero for lane>=50
  }
  atomicAdd(&occs[lane], occacc);
  __syncthreads();

  // ---- gate via MFMA: u = P@Vca, v = P@Vcb (overlay into qps/kps) ----
  {
    bf16x8 ap[2];
    #pragma unroll
    for (int k0 = 0; k0 < 2; k0++) ap[k0] = *(const bf16x8*)&Psh[cn][k0 * 32 + kq];
    #pragma unroll 1
    for (int tt = 0; tt < 4; tt++) {
      const int nt = wvv * 4 + tt;
      f32x4 au = {0.f,0.f,0.f,0.f}, av = {0.f,0.f,0.f,0.f};
      #pragma unroll
      for (int k0 = 0; k0 < 2; k0++) {
        bf16x8 bu = *(const bf16x8*)&VcaTh[(size_t)(nt * 16 + cn) * 64 + k0 * 32 + kq];
        bf16x8 bv = *(const bf16x8*)&VcbTh[(size_t)(nt * 16 + cn) * 64 + k0 * 32 + kq];
        au = mfma16(ap[k0], bu, au);
        av = mfma16(ap[k0], bv, av);
      }
      #pragma unroll
      for (int i = 0; i < 4; i++) {
        qps[m0 + i][nt * 16 + cn] = au[i];
        kps[m0 + i][nt * 16 + cn] = av[i];
      }
    }
  }
  __syncthreads();

  // ---- gate eval: wave owns 4 rows, lane covers cols 4l..4l+3 ----
  #pragma unroll
  for (int rr = 0; rr < 4; rr++) {
    const int r = wvv * 4 + rr;
    float4 u = *(const float4*)&qps[r][lane * 4];
    float4 v = *(const float4*)&kps[r][lane * 4];
    float g = tanhf(u.x + ba4.x) * sigmoidf_(v.x + bb4.x) * wc4.x
            + tanhf(u.y + ba4.y) * sigmoidf_(v.y + bb4.y) * wc4.y
            + tanhf(u.z + ba4.z) * sigmoidf_(v.z + bb4.z) * wc4.z
            + tanhf(u.w + ba4.w) * sigmoidf_(v.w + bb4.w) * wc4.w;
    g = waveAllSum(g);
    if (lane == 0) evp[r] = expf(g + bcv);
  }
  __syncthreads();
  if (tid < 64) {
    float s = 0.f;
    #pragma unroll
    for (int r = 0; r < 16; r++) s += evp[r] * bf2f(Psh[r][tid]);
    atomicAdd(&w50[tid], s);
    if (tid < 50) atomicAdd(&occden[tid], occs[tid]);
  }
  if (tid == 0) {
    float es = 0.f;
    #pragma unroll
    for (int r = 0; r < 16; r++) es += evp[r];
    atomicAdd(edencp, es);
  }
}

// ---------- klsum (256 blocks) ----------
__global__ void __launch_bounds__(256) k_klsum(const unsigned short* __restrict__ klh, float* __restrict__ klsum){
  int d = threadIdx.x;
  float s = 0.f;
  size_t j0 = (size_t)blockIdx.x * 256;
  for (int j = 0; j < 256; j++) s += bf2f(klh[(j0 + j) * DD + d]);
  atomicAdd(&klsum[d], s);
}

// ---------- occ numerator (256 blocks) ----------
__global__ void __launch_bounds__(256) k_occnum(const float* __restrict__ E, const unsigned short* __restrict__ vph,
                                                float* __restrict__ occraw){
  int d = threadIdx.x;
  int j0 = blockIdx.x * 256;
  __shared__ float Es[32][64];
  float acc[52];
  #pragma unroll
  for (int i = 0; i < 52; i++) acc[i] = 0.f;
  for (int s = 0; s < 8; s++) {
    for (int l = threadIdx.x; l < 512; l += 256) {
      int jj = l >> 4, cq = l & 15;
      *(float4*)&Es[jj][cq * 4] = ((const float4*)(E + (size_t)(j0 + s * 32 + jj) * 64))[cq];
    }
    __syncthreads();
    for (int jj = 0; jj < 32; jj++) {
      float vv = bf2f(vph[(size_t)(j0 + s * 32 + jj) * DD + d]);
      #pragma unroll
      for (int q = 0; q < 13; q++) {
        float4 e4 = *(const float4*)&Es[jj][q * 4];
        acc[q * 4 + 0] += e4.x * vv; acc[q * 4 + 1] += e4.y * vv;
        acc[q * 4 + 2] += e4.z * vv; acc[q * 4 + 3] += e4.w * vv;
      }
    }
    __syncthreads();
  }
  for (int i = 0; i < 50; i++) atomicAdd(&occraw[i * DD + d], acc[i]);
}

__global__ void __launch_bounds__(256) k_occfin(const float* __restrict__ occraw, const float* __restrict__ occden,
                                                float* __restrict__ occ){
  int i = blockIdx.x, d = threadIdx.x;
  occ[i * DD + d] = occraw[i * DD + d] / occden[i];
}

// ---------- kv = kl^T @ vp via MFMA, split-K, bf16 partials into E region ----------
__global__ void __launch_bounds__(256, 1) k_kv(const unsigned short* __restrict__ klh,
                                               const unsigned short* __restrict__ vph,
                                               unsigned short* __restrict__ PP){
  const int tid = threadIdx.x;
  const int lane = tid & 63;
  const int wvv = tid >> 6;
  const int cn = lane & 15;
  const int m0 = (lane >> 4) * 4;
  const int kq = (lane >> 4) * 8;
  const int cb = blockIdx.x;          // c band (128 wide)
  const int z  = blockIdx.y;          // j chunk (512 rows)
  f32x4 acc[8][4];
  #pragma unroll
  for (int mt = 0; mt < 8; mt++)
    #pragma unroll
    for (int tl = 0; tl < 4; tl++) acc[mt][tl] = (f32x4){0.f,0.f,0.f,0.f};

  const int jbase = z * 512;
  #pragma unroll 1
  for (int step = 0; step < 16; step++) {
    const int j0 = jbase + step * 32;
    const unsigned short* arow = klh + (size_t)(j0 + kq) * 256 + cb * 128 + cn;
    const unsigned short* brow = vph + (size_t)(j0 + kq) * 256 + (wvv * 4) * 16 + cn;
    bf16x8 afr[8], bfr[4];
    #pragma unroll
    for (int mt = 0; mt < 8; mt++) afr[mt] = frag_strided(arow + mt * 16, 256);
    #pragma unroll
    for (int tl = 0; tl < 4; tl++) bfr[tl] = frag_strided(brow + tl * 16, 256);
    #pragma unroll
    for (int mt = 0; mt < 8; mt++)
      #pragma unroll
      for (int tl = 0; tl < 4; tl++) acc[mt][tl] = mfma16(afr[mt], bfr[tl], acc[mt][tl]);
  }
  unsigned short* P = PP + ((size_t)(cb * 128 + z)) * 32768;
  #pragma unroll
  for (int mt = 0; mt < 8; mt++)
    #pragma unroll
    for (int tl = 0; tl < 4; tl++) {
      const int n = (wvv * 4 + tl) * 16 + cn;
      #pragma unroll
      for (int i = 0; i < 4; i++)
        P[(size_t)(mt * 16 + m0 + i) * 256 + n] = f2bf(acc[mt][tl][i]);
    }
}

// ---------- reduce partials -> kv^T bf16 ----------
__global__ void __launch_bounds__(256) k_kvred(const unsigned short* __restrict__ PP,
                                               unsigned short* __restrict__ kvTh){
  int c = blockIdx.x, d = threadIdx.x;
  int cb = c >> 7, m = c & 127;
  float s = 0.f;
  for (int z = 0; z < 128; z++)
    s += bf2f(PP[((size_t)(cb * 128 + z)) * 32768 + (size_t)m * 256 + d]);
  kvTh[(size_t)d * 256 + c] = f2bf(s);
}

// ---------- fused tail: OS + zfac + conv -> T(LDS) -> gate -> h2 ----------
__global__ void __launch_bounds__(256) k_tail(const unsigned short* __restrict__ qlh,
                                              const unsigned short* __restrict__ kvTh,
                                              const float* __restrict__ klsum,
                                              const unsigned short* __restrict__ vph,
                                              const float* __restrict__ dwcw, const float* __restrict__ dwcb,
                                              const unsigned short* __restrict__ WfaTh,
                                              const unsigned short* __restrict__ WfbTh,
                                              const float* __restrict__ bfa, const float* __restrict__ bfb,
                                              const float* __restrict__ Wc, const float* __restrict__ bc,
                                              float* __restrict__ h2t, float* __restrict__ h2den){
  __shared__ unsigned short Tsh[16][264];   // ql staging, then T bf16
  __shared__ float OSs[16][260];            // OS, later aU
  __shared__ float aVs[16][260];
  __shared__ float zf[16];
  __shared__ float ev[16];
  const int tid = threadIdx.x;
  const int i0 = blockIdx.x * 16;
  const int lane = tid & 63;
  const int wvv = tid >> 6;
  const int cn = lane & 15;
  const int m0 = (lane >> 4) * 4;
  const int kq = (lane >> 4) * 8;
  for (int l = tid; l < 1024; l += 256) {
    int r = l >> 6, c4 = (l & 63) * 4;
    *(ushort4*)&Tsh[r][c4] = *(const ushort4*)&qlh[(size_t)(i0 + r) * DD + c4];
  }
  __syncthreads();
  // OS = ql @ kv
  {
    bf16x8 afq[8];
    #pragma unroll
    for (int k0 = 0; k0 < 8; k0++) afq[k0] = *(const bf16x8*)&Tsh[cn][k0 * 32 + kq];
    #pragma unroll 1
    for (int tt = 0; tt < 4; tt++) {
      const int nt = wvv * 4 + tt;
      f32x4 acc = {0.f,0.f,0.f,0.f};
      #pragma unroll
      for (int k0 = 0; k0 < 8; k0++) {
        bf16x8 b = *(const bf16x8*)&kvTh[(size_t)(nt * 16 + cn) * 256 + k0 * 32 + kq];
        acc = mfma16(afq[k0], b, acc);
      }
      #pragma unroll
      for (int i = 0; i < 4; i++) OSs[m0 + i][nt * 16 + cn] = acc[i];
    }
  }
  // zfac: wave owns rows 4w..4w+3; lane covers cols 4l..4l+3
  {
    float4 ks4 = ((const float4*)klsum)[lane];
    #pragma unroll
    for (int rr = 0; rr < 4; rr++) {
      const int r = wvv * 4 + rr;
      ushort4 q4 = *(const ushort4*)&Tsh[r][lane * 4];
      float s = bf2f(q4.x)*ks4.x + bf2f(q4.y)*ks4.y + bf2f(q4.z)*ks4.z + bf2f(q4.w)*ks4.w;
      s = waveAllSum(s);
      if (lane == 0) zf[r] = 1.0f / (s + 1e-6f);
    }
  }
  __syncthreads();
  // conv: 5 dy-strips, 20 register-buffered loads each, sliding-window FMA
  const int j = tid;
  float w[25];
  #pragma unroll
  for (int t = 0; t < 25; t++) w[t] = dwcw[j * 25 + t];
  const float bias = dwcb[j];
  const int y = i0 >> 8, x0 = i0 & 255;
  float fm[16];
  #pragma unroll
  for (int r = 0; r < 16; r++) fm[r] = bias;
  #pragma unroll
  for (int dy = -2; dy <= 2; dy++) {
    const int yy = y + dy;
    if ((unsigned)yy > 255u) continue;
    float buf[20];
    #pragma unroll
    for (int i = 0; i < 20; i++) {
      const int xx = x0 - 2 + i;
      buf[i] = ((unsigned)xx <= 255u) ? bf2f(vph[(size_t)((yy << 8) + xx) * DD + j]) : 0.f;
    }
    const float* wr = &w[(dy + 2) * 5];
    #pragma unroll
    for (int r = 0; r < 16; r++)
      fm[r] += buf[r] * wr[0] + buf[r+1] * wr[1] + buf[r+2] * wr[2]
             + buf[r+3] * wr[3] + buf[r+4] * wr[4];
  }
  float Tf[16];
  #pragma unroll
  for (int r = 0; r < 16; r++) {
    Tf[r] = OSs[r][j] * zf[r] + fm[r];
    Tsh[r][j] = f2bf(Tf[r]);
  }
  __syncthreads();
  // aU = T@Wfa (into OSs), aV = T@Wfb
  {
    bf16x8 aft[8];
    #pragma unroll
    for (int k0 = 0; k0 < 8; k0++) aft[k0] = *(const bf16x8*)&Tsh[cn][k0 * 32 + kq];
    #pragma unroll 1
    for (int jb = 0; jb < 8; jb++) {
      const int nt = wvv * 4 + (jb & 3);
      const unsigned short* Bt = (jb < 4) ? WfaTh : WfbTh;
      f32x4 acc = {0.f,0.f,0.f,0.f};
      #pragma unroll
      for (int k0 = 0; k0 < 8; k0++) {
        bf16x8 b = *(const bf16x8*)&Bt[(size_t)(nt * 16 + cn) * 256 + k0 * 32 + kq];
        acc = mfma16(aft[k0], b, acc);
      }
      float (*dst)[260] = (jb < 4) ? OSs : aVs;
      #pragma unroll
      for (int i = 0; i < 4; i++) dst[m0 + i][nt * 16 + cn] = acc[i];
    }
  }
  __syncthreads();
  // gate: wave owns 4 rows, lane covers cols 4l..4l+3
  {
    float4 bfa4 = ((const float4*)bfa)[lane];
    float4 bfb4 = ((const float4*)bfb)[lane];
    float4 wc4 = ((const float4*)Wc)[lane];
    const float bcv = bc[0];
    #pragma unroll
    for (int rr = 0; rr < 4; rr++) {
      const int r = wvv * 4 + rr;
      float4 u = *(const float4*)&OSs[r][lane * 4];
      float4 v = *(const float4*)&aVs[r][lane * 4];
      float g = tanhf(u.x + bfa4.x) * sigmoidf_(v.x + bfb4.x) * wc4.x
              + tanhf(u.y + bfa4.y) * sigmoidf_(v.y + bfb4.y) * wc4.y
              + tanhf(u.z + bfa4.z) * sigmoidf_(v.z + bfb4.z) * wc4.z
              + tanhf(u.w + bfa4.w) * sigmoidf_(v.w + bfb4.w) * wc4.w;
      g = waveAllSum(g);
      if (lane == 0) ev[r] = expf(g + bcv);
    }
  }
  __syncthreads();
  float hp = 0.f;
  #pragma unroll
  for (int r = 0; r < 16; r++) hp += ev[r] * Tf[r];
  atomicAdd(&h2t[j], hp);
  if (tid == 0) {
    float es = 0.f;
    #pragma unroll
    for (int r = 0; r < 16; r++) es += ev[r];
    atomicAdd(h2den, es);
  }
}

// ---------- final tiny MLPs ----------
__global__ void __launch_bounds__(256) k_final(
    const float* __restrict__ A_cc, const float* __restrict__ occ,
    const float* __restrict__ A_sc, const float* __restrict__ osc,
    const float* __restrict__ w50, const float* __restrict__ edencp,
    const float* __restrict__ h2t, const float* __restrict__ h2den,
    const float* __restrict__ vc, const float* __restrict__ Wf, const float* __restrict__ bf,
    const float* __restrict__ W1, const float* __restrict__ b1,
    const float* __restrict__ W2, const float* __restrict__ b2,
    const float* __restrict__ W3a, const float* __restrict__ b3a,
    const float* __restrict__ W3b, const float* __restrict__ b3b,
    float* __restrict__ out){
  int j = threadIdx.x;
  __shared__ float pw[64];
  __shared__ float t1[256], t2[256], h1[256], h2[256], fz[512], z1[256];
  // ===== CROSS =====
  if (j < 64) pw[j] = (j < 50) ? expf(A_cc[j]) : 0.f;
  __syncthreads();
  float den = 0.f;
  for (int i = 0; i < 50; i++) den += pw[i];
  float raw = 0.f;
  for (int i = 0; i < 50; i++) raw += pw[i] * occ[i * DD + j];
  t1[j] = raw / den;
  float r2 = 0.f;
  for (int i = 0; i < 50; i++) r2 += w50[i] * vc[i * DD + j];
  t2[j] = r2 / edencp[0];
  __syncthreads();
  float a1 = 0.f, a2 = 0.f;
  for (int k = 0; k < DD; k++) { a1 += t1[k] * W1[k * DD + j]; a2 += t2[k] * W2[k * DD + j]; }
  h1[j] = fmaxf(a1 + b1[j], 0.f);
  h2[j] = fmaxf(a2 + b2[j], 0.f);
  __syncthreads();
  fz[j] = h1[j]; fz[256 + j] = h2[j];
  __syncthreads();
  float z = 0.f;
  for (int k = 0; k < 512; k++) z += fz[k] * W3a[k * DD + j];
  z1[j] = fmaxf(z + b3a[j], 0.f);
  __syncthreads();
  float o = 0.f;
  for (int k = 0; k < DD; k++) o += z1[k] * W3b[k * DD + j];
  out[j] = fmaxf(o + b3b[j], 0.f);
  __syncthreads();
  // ===== SELF =====
  if (j < 64) pw[j] = (j < 50) ? expf(A_sc[j]) : 0.f;
  __syncthreads();
  den = 0.f;
  for (int i = 0; i < 50; i++) den += pw[i];
  raw = 0.f;
  for (int i = 0; i < 50; i++) raw += pw[i] * osc[i * DD + j];
  t1[j] = raw / den;
  t2[j] = h2t[j] / h2den[0];
  __syncthreads();
  float hs = 0.f;
  for (int k = 0; k < DD; k++) hs += t2[k] * Wf[k * DD + j];
  __syncthreads();
  t2[j] = hs + bf[j];
  __syncthreads();
  a1 = 0.f; a2 = 0.f;
  for (int k = 0; k < DD; k++) { a1 += t1[k] * W1[k * DD + j]; a2 += t2[k] * W2[k * DD + j]; }
  h1[j] = fmaxf(a1 + b1[j], 0.f);
  h2[j] = fmaxf(a2 + b2[j], 0.f);
  __syncthreads();
  fz[j] = h1[j]; fz[256 + j] = h2[j];
  __syncthreads();
  z = 0.f;
  for (int k = 0; k < 512; k++) z += fz[k] * W3a[k * DD + j];
  z1[j] = fmaxf(z + b3a[j], 0.f);
  __syncthreads();
  o = 0.f;
  for (int k = 0; k < DD; k++) o += z1[k] * W3b[k * DD + j];
  out[256 + j] = fmaxf(o + b3b[j], 0.f);
}

extern "C" void kernel_launch(void* const* d_in, const int* in_sizes, int n_in,
                              void* d_out, int out_size, void* d_ws, size_t ws_size,
                              hipStream_t stream) {
  if (ws_size < WS_NEEDED) return;
  const float* x   = (const float*)d_in[0];
  const float* Wqkv= (const float*)d_in[1];
  const float* sln = (const float*)d_in[2];
  const float* dwcw= (const float*)d_in[3];
  const float* dwcb= (const float*)d_in[4];
  const float* Wa  = (const float*)d_in[5];
  const float* ba  = (const float*)d_in[6];
  const float* Wb  = (const float*)d_in[7];
  const float* bb  = (const float*)d_in[8];
  const float* Wc  = (const float*)d_in[9];
  const float* bc  = (const float*)d_in[10];
  const float* W1  = (const float*)d_in[11];
  const float* b1  = (const float*)d_in[12];
  const float* W2  = (const float*)d_in[13];
  const float* b2  = (const float*)d_in[14];
  const float* W3a = (const float*)d_in[15];
  const float* b3a = (const float*)d_in[16];
  const float* W3b = (const float*)d_in[17];
  const float* b3b = (const float*)d_in[18];
  const float* Wf  = (const float*)d_in[19];
  const float* bf  = (const float*)d_in[20];

  char* wsb = (char*)d_ws;
  unsigned short* VPH = (unsigned short*)(wsb + B_VPH);
  unsigned short* QLH = (unsigned short*)(wsb + B_QLH);
  unsigned short* KLH = (unsigned short*)(wsb + B_KLH);
  float* EB = (float*)(wsb + B_E);
  float* SM = (float*)(wsb + B_SM);
  unsigned short* XT = (unsigned short*)(wsb + B_X);
  float* outp = (float*)d_out;

  hipMemsetAsync((void*)SM, 0, ZEND * sizeof(float), stream);

  k_prep0<<<818, 256, 0, stream>>>(x, Wqkv, SM + QC, SM + KC, SM + VC,
                                   XT + XT_QCH, XT + XT_KCH, XT + XT_WQKV);
  k_prep1<<<564, 256, 0, stream>>>(SM + VC, Wa, Wb, ba, bb, Wf, bf,
                                   SM + VCA, SM + VCB, XT + XT_VCAT, XT + XT_VCBT,
                                   SM + WFA, SM + WFB, SM + BFA, SM + BFB,
                                   XT + XT_WFAT, XT + XT_WFBT);
  k_osc<<<1, 256, 0, stream>>>(SM + QC, SM + KC, SM + VC, SM + OSCB);
  k_gated<<<50, 256, 0, stream>>>(SM + OSCB, Wa, Wb, ba, bb, Wc, bc, SM + ASC);

  k_path1<<<4096, 256, 0, stream>>>(x, XT + XT_WQKV, sln, XT + XT_KCH, XT + XT_QCH,
                                    XT + XT_VCAT, XT + XT_VCBT, ba, bb, Wc, bc,
                                    VPH, QLH, KLH, EB, SM + W50, SM + EDENC, SM + OCCDEN);
  k_klsum<<<256, 256, 0, stream>>>(KLH, SM + KLSUM);
  k_occnum<<<256, 256, 0, stream>>>(EB, VPH, SM + OCCRAW);
  k_occfin<<<50, 256, 0, stream>>>(SM + OCCRAW, SM + OCCDEN, SM + OCCB);
  k_gated<<<50, 256, 0, stream>>>(SM + OCCB, Wa, Wb, ba, bb, Wc, bc, SM + ACC50);

  k_kv<<<dim3(2, 128), 256, 0, stream>>>(KLH, VPH, (unsigned short*)EB);
  k_kvred<<<256, 256, 0, stream>>>((const unsigned short*)EB, XT + XT_KVT);

  k_tail<<<4096, 256, 0, stream>>>(QLH, XT + XT_KVT, SM + KLSUM, VPH, dwcw, dwcb,
                                   XT + XT_WFAT, XT + XT_WFBT, SM + BFA, SM + BFB,
                                   Wc, bc, SM + H2T, SM + H2DEN);

  k_final<<<1, 256, 0, stream>>>(SM + ACC50, SM + OCCB, SM + ASC, SM + OSCB,
                                 SM + W50, SM + EDENC, SM + H2T, SM + H2DEN,
                                 SM + VC, Wf, bf, W1, b1, W2, b2, W3a, b3a, W3b, b3b, outp);
}

// Round 6
// 1030.288 us; speedup vs baseline: 1.9574x; 1.0426x over previous
//
#include <hip/hip_runtime.h>
#include <math.h>

// MixedAttentionLayer — R6: occupancy diet (bf16 LDS in path1/tail),
// klsum folded into k_kv (ones-MFMA), tiled Wqkv transpose, merged kvred+occfin.

constexpr int DD = 256;
constexpr int MM = 50;
constexpr float SCL = 0.0625f; // 256^-0.5

// ---- byte offsets in d_ws ----
constexpr size_t B_VPH = 0;                      // 32 MiB bf16 vp
constexpr size_t B_QLH = (size_t)32 << 20;       // 32 MiB bf16 ql
constexpr size_t B_KLH = (size_t)64 << 20;       // 32 MiB bf16 kl
constexpr size_t B_E   = (size_t)96 << 20;       // 16 MiB f32 E; later bf16 kv partials
constexpr size_t B_SM  = (size_t)112 << 20;      // small fp32 region
constexpr size_t B_X   = B_SM + ((size_t)2 << 20); // bf16 prep region

// ---- float offsets within SM region ----
constexpr size_t KLSUM  = 0;
constexpr size_t OCCDEN = 256;
constexpr size_t W50    = 320;
constexpr size_t EDENC  = 384;
constexpr size_t H2T    = 392;
constexpr size_t H2DEN  = 648;
constexpr size_t OCCRAW = 656;
constexpr size_t ZEND   = 13456;
constexpr size_t QC     = 13456;
constexpr size_t KC     = QC + 12800;
constexpr size_t VC     = KC + 12800;
constexpr size_t VCA    = VC + 12800;
constexpr size_t VCB    = VCA + 12800;
constexpr size_t WFA    = VCB + 12800;
constexpr size_t WFB    = WFA + 65536;
constexpr size_t BFA    = WFB + 65536;
constexpr size_t BFB    = BFA + 256;
constexpr size_t OSCB   = BFB + 256;
constexpr size_t OCCB   = OSCB + 12800;
constexpr size_t ASC    = OCCB + 12800;
constexpr size_t ACC50  = ASC + 64;
constexpr size_t SMEND  = ACC50 + 64;

// ---- short offsets within X (bf16 prep) region ----
constexpr size_t XT_WQKV = 0;          // 768*256
constexpr size_t XT_WFAT = 196608;     // 256*256  (Wfa^T)
constexpr size_t XT_WFBT = 262144;     // 256*256
constexpr size_t XT_KVT  = 327680;     // 256*256  (kv^T)
constexpr size_t XT_QCH  = 393216;     // 64*256 (qc, rows 50..63 zero)
constexpr size_t XT_KCH  = 409600;     // 64*256
constexpr size_t XT_VCAT = 425984;     // 256*64 (Vca^T, cols 50..63 zero)
constexpr size_t XT_VCBT = 442368;     // 256*64
constexpr size_t XT_END  = 458752;
constexpr size_t WS_NEEDED = B_X + XT_END * 2;

typedef short bf16x8 __attribute__((ext_vector_type(8)));
typedef float f32x4 __attribute__((ext_vector_type(4)));

__device__ __forceinline__ float sigmoidf_(float x){ return 1.0f / (1.0f + expf(-x)); }

__device__ __forceinline__ float bf2f(unsigned short u){
  return __uint_as_float(((unsigned int)u) << 16);
}
__device__ __forceinline__ unsigned short f2bf(float f){
  unsigned int x = __float_as_uint(f);
  unsigned int r = (x + 0x7fffu + ((x >> 16) & 1u)) >> 16;
  return (unsigned short)r;
}
__device__ __forceinline__ f32x4 mfma16(bf16x8 a, bf16x8 b, f32x4 c){
  return __builtin_amdgcn_mfma_f32_16x16x32_bf16(a, b, c, 0, 0, 0);
}
__device__ __forceinline__ bf16x8 frag_strided(const unsigned short* base, int stride){
  bf16x8 r;
  #pragma unroll
  for (int i = 0; i < 8; i++) r[i] = (short)base[(size_t)i * stride];
  return r;
}

__device__ __forceinline__ float waveAllSum(float v){
  #pragma unroll
  for (int m = 1; m < 64; m <<= 1) v += __shfl_xor(v, m, 64);
  return v;
}

// ---------- prep0: tiled Wqkv^T (blocks 0..47) + qc/kc/vc (blocks 48..97) ----------
__global__ void __launch_bounds__(256) k_prep0(const float* __restrict__ x, const float* __restrict__ Wqkv,
                                               float* qc, float* kc, float* vc,
                                               unsigned short* qch, unsigned short* kch,
                                               unsigned short* __restrict__ WT){
  const int b = blockIdx.x, t = threadIdx.x;
  if (b < 48) {
    // transpose tile: n in [64bn,64bn+64), k in [64bk,64bk+64)
    __shared__ unsigned short Tt[64][68];
    const int bn = b % 12, bk = b / 12;
    const int n0 = bn * 64, k0g = bk * 64;
    #pragma unroll
    for (int i = 0; i < 16; i++) {
      const int k_l = (t >> 6) + i * 4;
      const int n_l = t & 63;
      Tt[n_l][k_l] = f2bf(Wqkv[(size_t)(k0g + k_l) * 768 + n0 + n_l]);
    }
    __syncthreads();
    #pragma unroll
    for (int i = 0; i < 4; i++) {
      const int n_l = (t >> 4) + i * 16;
      const int k4 = (t & 15) * 4;
      ushort4 v = *(const ushort4*)&Tt[n_l][k4];
      *(ushort4*)&WT[(size_t)(n0 + n_l) * 256 + k0g + k4] = v;
    }
    return;
  }
  __shared__ float xs[256];
  const int r = b - 48, j = t;
  xs[j] = x[r * DD + j];
  __syncthreads();
  float aq = 0.f, ak = 0.f, av = 0.f;
  for (int k = 0; k < DD; k++) {
    float xv = xs[k];
    aq += xv * Wqkv[k * 768 + j];
    ak += xv * Wqkv[k * 768 + 256 + j];
    av += xv * Wqkv[k * 768 + 512 + j];
  }
  qc[r * DD + j] = aq; kc[r * DD + j] = ak; vc[r * DD + j] = av;
  qch[r * DD + j] = f2bf(aq); kch[r * DD + j] = f2bf(ak);
  if (r == 0) {
    for (int c = 50; c < 64; c++) { qch[c * DD + j] = 0; kch[c * DD + j] = 0; }
  }
}

// ---------- prep1: Vca/Vcb (blocks 0..49) + Wfa/Wfb/bfa/bfb (blocks 50..563) ----------
__global__ void __launch_bounds__(256) k_prep1(const float* vc, const float* Wa, const float* Wb,
                                               const float* ba, const float* bb,
                                               const float* Wf, const float* bf,
                                               float* Vca, float* Vcb,
                                               unsigned short* VcaTh, unsigned short* VcbTh,
                                               float* Wfa, float* Wfb, float* bfa, float* bfb,
                                               unsigned short* WfaTh, unsigned short* WfbTh){
  __shared__ float rs[256];
  const int b = blockIdx.x, j = threadIdx.x;
  if (b < 50) {
    const int r = b;
    rs[j] = vc[r * DD + j];
    __syncthreads();
    float a = 0.f, bv = 0.f;
    for (int k = 0; k < DD; k++) { float v = rs[k]; a += v * Wa[k * DD + j]; bv += v * Wb[k * DD + j]; }
    Vca[r * DD + j] = a; Vcb[r * DD + j] = bv;
    VcaTh[j * 64 + r] = f2bf(a); VcbTh[j * 64 + r] = f2bf(bv);
    if (r == 0) {
      for (int c = 50; c < 64; c++) { VcaTh[j * 64 + c] = 0; VcbTh[j * 64 + c] = 0; }
    }
    return;
  }
  const int bb2 = b - 50;
  const float* src; const float* Wm;
  if (bb2 < 256)      { src = Wf + bb2 * DD;         Wm = Wa; }
  else if (bb2 < 512) { src = Wf + (bb2 - 256) * DD; Wm = Wb; }
  else if (bb2 == 512){ src = bf;                    Wm = Wa; }
  else                { src = bf;                    Wm = Wb; }
  rs[j] = src[j];
  __syncthreads();
  float a = 0.f;
  for (int k = 0; k < DD; k++) a += rs[k] * Wm[k * DD + j];
  if (bb2 < 256)      { Wfa[bb2 * DD + j] = a; WfaTh[(size_t)j * DD + bb2] = f2bf(a); }
  else if (bb2 < 512) { Wfb[(bb2 - 256) * DD + j] = a; WfbTh[(size_t)j * DD + (bb2 - 256)] = f2bf(a); }
  else if (bb2 == 512) bfa[j] = a + ba[j];
  else bfb[j] = a + bb[j];
}

// ---------- osc = softmax(scale*qc@kc^T)@vc ----------
__global__ void __launch_bounds__(256) k_osc(const float* qc, const float* kc, const float* vc, float* osc){
  __shared__ float S[50][64];
  __shared__ float P[50][64];
  int t = threadIdx.x;
  for (int p = t; p < 2500; p += 256) {
    int i = p / 50, jj = p % 50;
    float s = 0.f;
    for (int k = 0; k < DD; k++) s += qc[i * DD + k] * kc[jj * DD + k];
    S[i][jj] = s * SCL;
  }
  __syncthreads();
  if (t < 50) {
    float mx = -1e30f;
    for (int jj = 0; jj < 50; jj++) mx = fmaxf(mx, S[t][jj]);
    float den = 0.f;
    for (int jj = 0; jj < 50; jj++) { float e = expf(S[t][jj] - mx); P[t][jj] = e; den += e; }
    float inv = 1.0f / den;
    for (int jj = 0; jj < 50; jj++) P[t][jj] *= inv;
  }
  __syncthreads();
  for (int i = 0; i < 50; i++) {
    float a = 0.f;
    for (int jj = 0; jj < 50; jj++) a += P[i][jj] * vc[jj * DD + t];
    osc[i * DD + t] = a;
  }
}

// ---------- gated() on 50 rows ----------
__global__ void __launch_bounds__(256) k_gated(const float* __restrict__ tin,
                                               const float* __restrict__ Wa, const float* __restrict__ Wb,
                                               const float* __restrict__ ba, const float* __restrict__ bb,
                                               const float* __restrict__ Wc, const float* __restrict__ bc,
                                               float* __restrict__ A){
  int r = blockIdx.x, j = threadIdx.x;
  __shared__ float ts[256];
  __shared__ float red[4];
  ts[j] = tin[r * DD + j];
  __syncthreads();
  float u = 0.f, v = 0.f;
  for (int k = 0; k < DD; k++) { float tv = ts[k]; u += tv * Wa[k * DD + j]; v += tv * Wb[k * DD + j]; }
  float g = tanhf(u + ba[j]) * sigmoidf_(v + bb[j]) * Wc[j];
  g = waveAllSum(g);
  int lane = j & 63, wv = j >> 6;
  if (lane == 0) red[wv] = g;
  __syncthreads();
  if (j == 0) A[r] = red[0] + red[1] + red[2] + red[3] + bc[0];
}

// ---------- fused path kernel (bf16 LDS: 4 blocks/CU) ----------
__global__ void __launch_bounds__(256) k_path1(
    const float* __restrict__ x, const unsigned short* __restrict__ WqkvTh,
    const float* __restrict__ sln,
    const unsigned short* __restrict__ kch, const unsigned short* __restrict__ qch,
    const unsigned short* __restrict__ VcaTh, const unsigned short* __restrict__ VcbTh,
    const float* __restrict__ ba, const float* __restrict__ bb,
    const float* __restrict__ Wc, const float* __restrict__ bc,
    unsigned short* __restrict__ vph, unsigned short* __restrict__ qlh, unsigned short* __restrict__ klh,
    float* __restrict__ E, float* __restrict__ w50, float* __restrict__ edencp, float* __restrict__ occden){
  __shared__ unsigned short xsh[16][264];
  __shared__ unsigned short qpsb[16][264];   // qp bf16; later u (gate pre-act A)
  __shared__ unsigned short kpsb[16][264];   // kp bf16; later v
  __shared__ float scap[16][68];
  __shared__ float scac[16][68];
  __shared__ unsigned short Psh[16][72];
  __shared__ float occs[64];
  __shared__ float evp[16];
  __shared__ float edens;
  const int tid = threadIdx.x;
  const int i0 = blockIdx.x * 16;
  const int lane = tid & 63;
  const int wvv = tid >> 6;
  const int cn = lane & 15;
  const int m0 = (lane >> 4) * 4;
  const int kq = (lane >> 4) * 8;

  if (tid < 64) occs[tid] = 0.f;
  if (tid == 0) edens = 0.f;
  for (int l = tid; l < 4096; l += 256) {
    int r = l >> 8, c = l & 255;
    xsh[r][c] = f2bf(x[(size_t)(MM + i0 + r) * DD + c]);
  }
  __syncthreads();

  // ---- GEMM: [16 x 256] @ [256 x 768], double-buffered B ----
  bf16x8 af[8];
  #pragma unroll
  for (int k0 = 0; k0 < 8; k0++)
    af[k0] = *(const bf16x8*)&xsh[cn][k0 * 32 + kq];
  bf16x8 b0[8], b1[8];
  {
    const size_t nrow = (size_t)(wvv * 16 + cn) * 256;
    #pragma unroll
    for (int k0 = 0; k0 < 8; k0++) b0[k0] = *(const bf16x8*)&WqkvTh[nrow + k0 * 32 + kq];
  }
  #pragma unroll 1
  for (int tt = 0; tt < 12; tt++) {
    const int t = wvv + 4 * tt;       // n-tile 0..47
    if (tt + 1 < 12) {
      const size_t nrow = (size_t)((t + 4) * 16 + cn) * 256;
      #pragma unroll
      for (int k0 = 0; k0 < 8; k0++) b1[k0] = *(const bf16x8*)&WqkvTh[nrow + k0 * 32 + kq];
    }
    f32x4 acc = {0.f, 0.f, 0.f, 0.f};
    #pragma unroll
    for (int k0 = 0; k0 < 8; k0++) acc = mfma16(af[k0], b0[k0], acc);
    if (t < 16) {
      int c = t * 16 + cn;
      #pragma unroll
      for (int i = 0; i < 4; i++) qpsb[m0 + i][c] = f2bf(acc[i]);
    } else if (t < 32) {
      int c = (t - 16) * 16 + cn;
      #pragma unroll
      for (int i = 0; i < 4; i++) kpsb[m0 + i][c] = f2bf(acc[i]);
    } else {
      int c = (t - 32) * 16 + cn;
      #pragma unroll
      for (int i = 0; i < 4; i++) vph[(size_t)(i0 + m0 + i) * DD + c] = f2bf(acc[i]);
    }
    #pragma unroll
    for (int k0 = 0; k0 < 8; k0++) b0[k0] = b1[k0];
  }
  __syncthreads();

  // ---- scores via MFMA: cap = qp@kc^T, cac = kp@qc^T (A direct from bf16 LDS) ----
  {
    const int n0 = wvv * 16;
    f32x4 accp = {0.f,0.f,0.f,0.f}, accc = {0.f,0.f,0.f,0.f};
    #pragma unroll
    for (int k0 = 0; k0 < 8; k0++) {
      bf16x8 aq = *(const bf16x8*)&qpsb[cn][k0 * 32 + kq];
      bf16x8 ak = *(const bf16x8*)&kpsb[cn][k0 * 32 + kq];
      bf16x8 bk = *(const bf16x8*)&kch[(size_t)(n0 + cn) * DD + k0 * 32 + kq];
      bf16x8 bq = *(const bf16x8*)&qch[(size_t)(n0 + cn) * DD + k0 * 32 + kq];
      accp = mfma16(aq, bk, accp);
      accc = mfma16(ak, bq, accc);
    }
    #pragma unroll
    for (int i = 0; i < 4; i++) {
      scap[m0 + i][n0 + cn] = accp[i];
      scac[m0 + i][n0 + cn] = accc[i];
    }
  }
  __syncthreads();

  // ---- phase B: transforms + softmax p (wave owns 4 rows) ----
  float4 sl4 = ((const float4*)sln)[lane];
  float4 rsp;
  rsp.x = 1.0f / log1pf(expf(sl4.x)); rsp.y = 1.0f / log1pf(expf(sl4.y));
  rsp.z = 1.0f / log1pf(expf(sl4.z)); rsp.w = 1.0f / log1pf(expf(sl4.w));
  float4 ba4 = ((const float4*)ba)[lane];
  float4 bb4 = ((const float4*)bb)[lane];
  float4 wc4 = ((const float4*)Wc)[lane];
  float bcv = bc[0];
  float occacc = 0.f;
  for (int rr = 0; rr < 4; rr++) {
    const int r = wvv * 4 + rr;
    const int row = i0 + r;
    ushort4 qu = *(const ushort4*)&qpsb[r][lane * 4];
    ushort4 ku = *(const ushort4*)&kpsb[r][lane * 4];
    float4 q4 = {bf2f(qu.x), bf2f(qu.y), bf2f(qu.z), bf2f(qu.w)};
    float4 k4 = {bf2f(ku.x), bf2f(ku.y), bf2f(ku.z), bf2f(ku.w)};
    float4 lq, lk;
    lq.x = (fmaxf(q4.x, 0.f) + 1e-6f) * rsp.x; lq.y = (fmaxf(q4.y, 0.f) + 1e-6f) * rsp.y;
    lq.z = (fmaxf(q4.z, 0.f) + 1e-6f) * rsp.z; lq.w = (fmaxf(q4.w, 0.f) + 1e-6f) * rsp.w;
    lk.x = (fmaxf(k4.x, 0.f) + 1e-6f) * rsp.x; lk.y = (fmaxf(k4.y, 0.f) + 1e-6f) * rsp.y;
    lk.z = (fmaxf(k4.z, 0.f) + 1e-6f) * rsp.z; lk.w = (fmaxf(k4.w, 0.f) + 1e-6f) * rsp.w;
    float4 q3, k3;
    q3.x = lq.x*lq.x*lq.x; q3.y = lq.y*lq.y*lq.y; q3.z = lq.z*lq.z*lq.z; q3.w = lq.w*lq.w*lq.w;
    k3.x = lk.x*lk.x*lk.x; k3.y = lk.y*lk.y*lk.y; k3.z = lk.z*lk.z*lk.z; k3.w = lk.w*lk.w*lk.w;
    float n1q = lq.x*lq.x + lq.y*lq.y + lq.z*lq.z + lq.w*lq.w;
    float n3q = q3.x*q3.x + q3.y*q3.y + q3.z*q3.z + q3.w*q3.w;
    float n1k = lk.x*lk.x + lk.y*lk.y + lk.z*lk.z + lk.w*lk.w;
    float n3k = k3.x*k3.x + k3.y*k3.y + k3.z*k3.z + k3.w*k3.w;
    n1q = waveAllSum(n1q); n3q = waveAllSum(n3q);
    n1k = waveAllSum(n1k); n3k = waveAllSum(n3k);
    float fq = sqrtf(n1q / n3q);
    float fk = sqrtf(n1k / n3k);
    ushort4 qo, ko;
    qo.x = f2bf(q3.x * fq); qo.y = f2bf(q3.y * fq); qo.z = f2bf(q3.z * fq); qo.w = f2bf(q3.w * fq);
    ko.x = f2bf(k3.x * fk); ko.y = f2bf(k3.y * fk); ko.z = f2bf(k3.z * fk); ko.w = f2bf(k3.w * fk);
    *(ushort4*)&qlh[(size_t)row * DD + lane * 4] = qo;
    *(ushort4*)&klh[(size_t)row * DD + lane * 4] = ko;
    float ecap = (lane < 50) ? expf(scap[r][lane] * SCL) : 0.f;
    float ecac = (lane < 50) ? expf(scac[r][lane] * SCL) : 0.f;
    E[(size_t)row * 64 + lane] = ecac;
    occacc += ecac;
    float den = waveAllSum(ecap);
    Psh[r][lane] = f2bf(ecap / den);   // p, zero for lane>=50
  }
  atomicAdd(&occs[lane], occacc);
  __syncthreads();

  // ---- gate via MFMA: u = P@Vca, v = P@Vcb (overlay bf16 into qpsb/kpsb) ----
  {
    bf16x8 ap[2];
    #pragma unroll
    for (int k0 = 0; k0 < 2; k0++) ap[k0] = *(const bf16x8*)&Psh[cn][k0 * 32 + kq];
    #pragma unroll 1
    for (int tt = 0; tt < 4; tt++) {
      const int nt = wvv * 4 + tt;
      f32x4 au = {0.f,0.f,0.f,0.f}, av = {0.f,0.f,0.f,0.f};
      #pragma unroll
      for (int k0 = 0; k0 < 2; k0++) {
        bf16x8 bu = *(const bf16x8*)&VcaTh[(size_t)(nt * 16 + cn) * 64 + k0 * 32 + kq];
        bf16x8 bv = *(const bf16x8*)&VcbTh[(size_t)(nt * 16 + cn) * 64 + k0 * 32 + kq];
        au = mfma16(ap[k0], bu, au);
        av = mfma16(ap[k0], bv, av);
      }
      #pragma unroll
      for (int i = 0; i < 4; i++) {
        qpsb[m0 + i][nt * 16 + cn] = f2bf(au[i]);
        kpsb[m0 + i][nt * 16 + cn] = f2bf(av[i]);
      }
    }
  }
  __syncthreads();

  // ---- gate eval: wave owns 4 rows, lane covers cols 4l..4l+3 ----
  #pragma unroll
  for (int rr = 0; rr < 4; rr++) {
    const int r = wvv * 4 + rr;
    ushort4 uu = *(const ushort4*)&qpsb[r][lane * 4];
    ushort4 vv = *(const ushort4*)&kpsb[r][lane * 4];
    float g = tanhf(bf2f(uu.x) + ba4.x) * sigmoidf_(bf2f(vv.x) + bb4.x) * wc4.x
            + tanhf(bf2f(uu.y) + ba4.y) * sigmoidf_(bf2f(vv.y) + bb4.y) * wc4.y
            + tanhf(bf2f(uu.z) + ba4.z) * sigmoidf_(bf2f(vv.z) + bb4.z) * wc4.z
            + tanhf(bf2f(uu.w) + ba4.w) * sigmoidf_(bf2f(vv.w) + bb4.w) * wc4.w;
    g = waveAllSum(g);
    if (lane == 0) evp[r] = expf(g + bcv);
  }
  __syncthreads();
  if (tid < 64) {
    float s = 0.f;
    #pragma unroll
    for (int r = 0; r < 16; r++) s += evp[r] * bf2f(Psh[r][tid]);
    atomicAdd(&w50[tid], s);
    if (tid < 50) atomicAdd(&occden[tid], occs[tid]);
  }
  if (tid == 0) {
    float es = 0.f;
    #pragma unroll
    for (int r = 0; r < 16; r++) es += evp[r];
    atomicAdd(edencp, es);
  }
}

// ---------- occ numerator ----------
__global__ void __launch_bounds__(256) k_occnum(const float* __restrict__ E, const unsigned short* __restrict__ vph,
                                                float* __restrict__ occraw){
  int d = threadIdx.x;
  int j0 = blockIdx.x * 256;
  __shared__ float Es[32][64];
  float acc[52];
  #pragma unroll
  for (int i = 0; i < 52; i++) acc[i] = 0.f;
  for (int s = 0; s < 8; s++) {
    for (int l = threadIdx.x; l < 512; l += 256) {
      int jj = l >> 4, cq = l & 15;
      *(float4*)&Es[jj][cq * 4] = ((const float4*)(E + (size_t)(j0 + s * 32 + jj) * 64))[cq];
    }
    __syncthreads();
    for (int jj = 0; jj < 32; jj++) {
      float vv = bf2f(vph[(size_t)(j0 + s * 32 + jj) * DD + d]);
      #pragma unroll
      for (int q = 0; q < 13; q++) {
        float4 e4 = *(const float4*)&Es[jj][q * 4];
        acc[q * 4 + 0] += e4.x * vv; acc[q * 4 + 1] += e4.y * vv;
        acc[q * 4 + 2] += e4.z * vv; acc[q * 4 + 3] += e4.w * vv;
      }
    }
    __syncthreads();
  }
  for (int i = 0; i < 50; i++) atomicAdd(&occraw[i * DD + d], acc[i]);
}

// ---------- kv = kl^T @ vp via MFMA, split-K + fragment dbuf + klsum via ones-MFMA ----------
__global__ void __launch_bounds__(256, 1) k_kv(const unsigned short* __restrict__ klh,
                                               const unsigned short* __restrict__ vph,
                                               unsigned short* __restrict__ PP,
                                               float* __restrict__ klsum){
  const int tid = threadIdx.x;
  const int lane = tid & 63;
  const int wvv = tid >> 6;
  const int cn = lane & 15;
  const int m0 = (lane >> 4) * 4;
  const int kq = (lane >> 4) * 8;
  const int cb = blockIdx.x;          // c band (128 wide)
  const int z  = blockIdx.y;          // j chunk (512 rows)
  f32x4 acc[8][4];
  f32x4 acc1[8];
  #pragma unroll
  for (int mt = 0; mt < 8; mt++) {
    acc1[mt] = (f32x4){0.f,0.f,0.f,0.f};
    #pragma unroll
    for (int tl = 0; tl < 4; tl++) acc[mt][tl] = (f32x4){0.f,0.f,0.f,0.f};
  }
  bf16x8 ones;
  #pragma unroll
  for (int i = 0; i < 8; i++) ones[i] = (short)0x3F80;

  const int jbase = z * 512;
  bf16x8 afr[8], bfr[4], nafr[8], nbfr[4];
  {
    const unsigned short* arow = klh + (size_t)(jbase + kq) * 256 + cb * 128 + cn;
    const unsigned short* brow = vph + (size_t)(jbase + kq) * 256 + (wvv * 4) * 16 + cn;
    #pragma unroll
    for (int mt = 0; mt < 8; mt++) afr[mt] = frag_strided(arow + mt * 16, 256);
    #pragma unroll
    for (int tl = 0; tl < 4; tl++) bfr[tl] = frag_strided(brow + tl * 16, 256);
  }
  #pragma unroll 1
  for (int step = 0; step < 16; step++) {
    if (step + 1 < 16) {
      const int j0 = jbase + (step + 1) * 32;
      const unsigned short* arow = klh + (size_t)(j0 + kq) * 256 + cb * 128 + cn;
      const unsigned short* brow = vph + (size_t)(j0 + kq) * 256 + (wvv * 4) * 16 + cn;
      #pragma unroll
      for (int mt = 0; mt < 8; mt++) nafr[mt] = frag_strided(arow + mt * 16, 256);
      #pragma unroll
      for (int tl = 0; tl < 4; tl++) nbfr[tl] = frag_strided(brow + tl * 16, 256);
    }
    #pragma unroll
    for (int mt = 0; mt < 8; mt++) {
      acc1[mt] = mfma16(afr[mt], ones, acc1[mt]);
      #pragma unroll
      for (int tl = 0; tl < 4; tl++) acc[mt][tl] = mfma16(afr[mt], bfr[tl], acc[mt][tl]);
    }
    #pragma unroll
    for (int mt = 0; mt < 8; mt++) afr[mt] = nafr[mt];
    #pragma unroll
    for (int tl = 0; tl < 4; tl++) bfr[tl] = nbfr[tl];
  }
  unsigned short* P = PP + ((size_t)(cb * 128 + z)) * 32768;
  #pragma unroll
  for (int mt = 0; mt < 8; mt++)
    #pragma unroll
    for (int tl = 0; tl < 4; tl++) {
      const int n = (wvv * 4 + tl) * 16 + cn;
      #pragma unroll
      for (int i = 0; i < 4; i++)
        P[(size_t)(mt * 16 + m0 + i) * 256 + n] = f2bf(acc[mt][tl][i]);
    }
  // klsum partials: acc1 identical across waves; take wave 0, col 0 lanes
  if (wvv == 0 && cn == 0) {
    #pragma unroll
    for (int mt = 0; mt < 8; mt++)
      #pragma unroll
      for (int i = 0; i < 4; i++)
        atomicAdd(&klsum[cb * 128 + mt * 16 + m0 + i], acc1[mt][i]);
  }
}

// ---------- merged: kvred (blocks 0..255) + occfin (blocks 256..305) ----------
__global__ void __launch_bounds__(256) k_fin2(const unsigned short* __restrict__ PP,
                                              unsigned short* __restrict__ kvTh,
                                              const float* __restrict__ occraw,
                                              const float* __restrict__ occden,
                                              float* __restrict__ occ){
  const int b = blockIdx.x, d = threadIdx.x;
  if (b < 256) {
    int cb = b >> 7, m = b & 127;
    float s = 0.f;
    for (int z = 0; z < 128; z++)
      s += bf2f(PP[((size_t)(cb * 128 + z)) * 32768 + (size_t)m * 256 + d]);
    kvTh[(size_t)d * 256 + b] = f2bf(s);
  } else {
    int i = b - 256;
    occ[i * DD + d] = occraw[i * DD + d] / occden[i];
  }
}

// ---------- fused tail: OS + zfac + conv -> T(LDS) -> gate -> h2 (bf16 LDS: 6 blk/CU) ----------
__global__ void __launch_bounds__(256) k_tail(const unsigned short* __restrict__ qlh,
                                              const unsigned short* __restrict__ kvTh,
                                              const float* __restrict__ klsum,
                                              const unsigned short* __restrict__ vph,
                                              const float* __restrict__ dwcw, const float* __restrict__ dwcb,
                                              const unsigned short* __restrict__ WfaTh,
                                              const unsigned short* __restrict__ WfbTh,
                                              const float* __restrict__ bfa, const float* __restrict__ bfb,
                                              const float* __restrict__ Wc, const float* __restrict__ bc,
                                              float* __restrict__ h2t, float* __restrict__ h2den){
  __shared__ unsigned short Tsh[16][264];   // ql staging, then T bf16
  __shared__ unsigned short OSb[16][264];   // OS bf16, later aU bf16
  __shared__ unsigned short aVb[16][264];
  __shared__ float zf[16];
  __shared__ float ev[16];
  const int tid = threadIdx.x;
  const int i0 = blockIdx.x * 16;
  const int lane = tid & 63;
  const int wvv = tid >> 6;
  const int cn = lane & 15;
  const int m0 = (lane >> 4) * 4;
  const int kq = (lane >> 4) * 8;
  for (int l = tid; l < 1024; l += 256) {
    int r = l >> 6, c4 = (l & 63) * 4;
    *(ushort4*)&Tsh[r][c4] = *(const ushort4*)&qlh[(size_t)(i0 + r) * DD + c4];
  }
  __syncthreads();
  // OS = ql @ kv
  {
    bf16x8 afq[8];
    #pragma unroll
    for (int k0 = 0; k0 < 8; k0++) afq[k0] = *(const bf16x8*)&Tsh[cn][k0 * 32 + kq];
    #pragma unroll 1
    for (int tt = 0; tt < 4; tt++) {
      const int nt = wvv * 4 + tt;
      f32x4 acc = {0.f,0.f,0.f,0.f};
      #pragma unroll
      for (int k0 = 0; k0 < 8; k0++) {
        bf16x8 b = *(const bf16x8*)&kvTh[(size_t)(nt * 16 + cn) * 256 + k0 * 32 + kq];
        acc = mfma16(afq[k0], b, acc);
      }
      #pragma unroll
      for (int i = 0; i < 4; i++) OSb[m0 + i][nt * 16 + cn] = f2bf(acc[i]);
    }
  }
  // zfac: wave owns rows 4w..4w+3; lane covers cols 4l..4l+3
  {
    float4 ks4 = ((const float4*)klsum)[lane];
    #pragma unroll
    for (int rr = 0; rr < 4; rr++) {
      const int r = wvv * 4 + rr;
      ushort4 q4 = *(const ushort4*)&Tsh[r][lane * 4];
      float s = bf2f(q4.x)*ks4.x + bf2f(q4.y)*ks4.y + bf2f(q4.z)*ks4.z + bf2f(q4.w)*ks4.w;
      s = waveAllSum(s);
      if (lane == 0) zf[r] = 1.0f / (s + 1e-6f);
    }
  }
  __syncthreads();
  // conv: 5 dy-strips, 20 register-buffered loads each, sliding-window FMA
  const int j = tid;
  float w[25];
  #pragma unroll
  for (int t = 0; t < 25; t++) w[t] = dwcw[j * 25 + t];
  const float bias = dwcb[j];
  const int y = i0 >> 8, x0 = i0 & 255;
  float fm[16];
  #pragma unroll
  for (int r = 0; r < 16; r++) fm[r] = bias;
  #pragma unroll
  for (int dy = -2; dy <= 2; dy++) {
    const int yy = y + dy;
    if ((unsigned)yy > 255u) continue;
    float buf[20];
    #pragma unroll
    for (int i = 0; i < 20; i++) {
      const int xx = x0 - 2 + i;
      buf[i] = ((unsigned)xx <= 255u) ? bf2f(vph[(size_t)((yy << 8) + xx) * DD + j]) : 0.f;
    }
    const float* wr = &w[(dy + 2) * 5];
    #pragma unroll
    for (int r = 0; r < 16; r++)
      fm[r] += buf[r] * wr[0] + buf[r+1] * wr[1] + buf[r+2] * wr[2]
             + buf[r+3] * wr[3] + buf[r+4] * wr[4];
  }
  float Tf[16];
  #pragma unroll
  for (int r = 0; r < 16; r++) {
    Tf[r] = bf2f(OSb[r][j]) * zf[r] + fm[r];
    Tsh[r][j] = f2bf(Tf[r]);
  }
  __syncthreads();
  // aU = T@Wfa (into OSb), aV = T@Wfb
  {
    bf16x8 aft[8];
    #pragma unroll
    for (int k0 = 0; k0 < 8; k0++) aft[k0] = *(const bf16x8*)&Tsh[cn][k0 * 32 + kq];
    #pragma unroll 1
    for (int jb = 0; jb < 8; jb++) {
      const int nt = wvv * 4 + (jb & 3);
      const unsigned short* Bt = (jb < 4) ? WfaTh : WfbTh;
      f32x4 acc = {0.f,0.f,0.f,0.f};
      #pragma unroll
      for (int k0 = 0; k0 < 8; k0++) {
        bf16x8 b = *(const bf16x8*)&Bt[(size_t)(nt * 16 + cn) * 256 + k0 * 32 + kq];
        acc = mfma16(aft[k0], b, acc);
      }
      unsigned short (*dst)[264] = (jb < 4) ? OSb : aVb;
      #pragma unroll
      for (int i = 0; i < 4; i++) dst[m0 + i][nt * 16 + cn] = f2bf(acc[i]);
    }
  }
  __syncthreads();
  // gate: wave owns 4 rows, lane covers cols 4l..4l+3
  {
    float4 bfa4 = ((const float4*)bfa)[lane];
    float4 bfb4 = ((const float4*)bfb)[lane];
    float4 wc4 = ((const float4*)Wc)[lane];
    const float bcv = bc[0];
    #pragma unroll
    for (int rr = 0; rr < 4; rr++) {
      const int r = wvv * 4 + rr;
      ushort4 uu = *(const ushort4*)&OSb[r][lane * 4];
      ushort4 vv = *(const ushort4*)&aVb[r][lane * 4];
      float g = tanhf(bf2f(uu.x) + bfa4.x) * sigmoidf_(bf2f(vv.x) + bfb4.x) * wc4.x
              + tanhf(bf2f(uu.y) + bfa4.y) * sigmoidf_(bf2f(vv.y) + bfb4.y) * wc4.y
              + tanhf(bf2f(uu.z) + bfa4.z) * sigmoidf_(bf2f(vv.z) + bfb4.z) * wc4.z
              + tanhf(bf2f(uu.w) + bfa4.w) * sigmoidf_(bf2f(vv.w) + bfb4.w) * wc4.w;
      g = waveAllSum(g);
      if (lane == 0) ev[r] = expf(g + bcv);
    }
  }
  __syncthreads();
  float hp = 0.f;
  #pragma unroll
  for (int r = 0; r < 16; r++) hp += ev[r] * Tf[r];
  atomicAdd(&h2t[j], hp);
  if (tid == 0) {
    float es = 0.f;
    #pragma unroll
    for (int r = 0; r < 16; r++) es += ev[r];
    atomicAdd(h2den, es);
  }
}

// ---------- final tiny MLPs ----------
__global__ void __launch_bounds__(256) k_final(
    const float* __restrict__ A_cc, const float* __restrict__ occ,
    const float* __restrict__ A_sc, const float* __restrict__ osc,
    const float* __restrict__ w50, const float* __restrict__ edencp,
    const float* __restrict__ h2t, const float* __restrict__ h2den,
    const float* __restrict__ vc, const float* __restrict__ Wf, const float* __restrict__ bf,
    const float* __restrict__ W1, const float* __restrict__ b1,
    const float* __restrict__ W2, const float* __restrict__ b2,
    const float* __restrict__ W3a, const float* __restrict__ b3a,
    const float* __restrict__ W3b, const float* __restrict__ b3b,
    float* __restrict__ out){
  int j = threadIdx.x;
  __shared__ float pw[64];
  __shared__ float t1[256], t2[256], h1[256], h2[256], fz[512], z1[256];
  // ===== CROSS =====
  if (j < 64) pw[j] = (j < 50) ? expf(A_cc[j]) : 0.f;
  __syncthreads();
  float den = 0.f;
  for (int i = 0; i < 50; i++) den += pw[i];
  float raw = 0.f;
  for (int i = 0; i < 50; i++) raw += pw[i] * occ[i * DD + j];
  t1[j] = raw / den;
  float r2 = 0.f;
  for (int i = 0; i < 50; i++) r2 += w50[i] * vc[i * DD + j];
  t2[j] = r2 / edencp[0];
  __syncthreads();
  float a1 = 0.f, a2 = 0.f;
  for (int k = 0; k < DD; k++) { a1 += t1[k] * W1[k * DD + j]; a2 += t2[k] * W2[k * DD + j]; }
  h1[j] = fmaxf(a1 + b1[j], 0.f);
  h2[j] = fmaxf(a2 + b2[j], 0.f);
  __syncthreads();
  fz[j] = h1[j]; fz[256 + j] = h2[j];
  __syncthreads();
  float z = 0.f;
  for (int k = 0; k < 512; k++) z += fz[k] * W3a[k * DD + j];
  z1[j] = fmaxf(z + b3a[j], 0.f);
  __syncthreads();
  float o = 0.f;
  for (int k = 0; k < DD; k++) o += z1[k] * W3b[k * DD + j];
  out[j] = fmaxf(o + b3b[j], 0.f);
  __syncthreads();
  // ===== SELF =====
  if (j < 64) pw[j] = (j < 50) ? expf(A_sc[j]) : 0.f;
  __syncthreads();
  den = 0.f;
  for (int i = 0; i < 50; i++) den += pw[i];
  raw = 0.f;
  for (int i = 0; i < 50; i++) raw += pw[i] * osc[i * DD + j];
  t1[j] = raw / den;
  t2[j] = h2t[j] / h2den[0];
  __syncthreads();
  float hs = 0.f;
  for (int k = 0; k < DD; k++) hs += t2[k] * Wf[k * DD + j];
  __syncthreads();
  t2[j] = hs + bf[j];
  __syncthreads();
  a1 = 0.f; a2 = 0.f;
  for (int k = 0; k < DD; k++) { a1 += t1[k] * W1[k * DD + j]; a2 += t2[k] * W2[k * DD + j]; }
  h1[j] = fmaxf(a1 + b1[j], 0.f);
  h2[j] = fmaxf(a2 + b2[j], 0.f);
  __syncthreads();
  fz[j] = h1[j]; fz[256 + j] = h2[j];
  __syncthreads();
  z = 0.f;
  for (int k = 0; k < 512; k++) z += fz[k] * W3a[k * DD + j];
  z1[j] = fmaxf(z + b3a[j], 0.f);
  __syncthreads();
  o = 0.f;
  for (int k = 0; k < DD; k++) o += z1[k] * W3b[k * DD + j];
  out[256 + j] = fmaxf(o + b3b[j], 0.f);
}

extern "C" void kernel_launch(void* const* d_in, const int* in_sizes, int n_in,
                              void* d_out, int out_size, void* d_ws, size_t ws_size,
                              hipStream_t stream) {
  if (ws_size < WS_NEEDED) return;
  const float* x   = (const float*)d_in[0];
  const float* Wqkv= (const float*)d_in[1];
  const float* sln = (const float*)d_in[2];
  const float* dwcw= (const float*)d_in[3];
  const float* dwcb= (const float*)d_in[4];
  const float* Wa  = (const float*)d_in[5];
  const float* ba  = (const float*)d_in[6];
  const float* Wb  = (const float*)d_in[7];
  const float* bb  = (const float*)d_in[8];
  const float* Wc  = (const float*)d_in[9];
  const float* bc  = (const float*)d_in[10];
  const float* W1  = (const float*)d_in[11];
  const float* b1  = (const float*)d_in[12];
  const float* W2  = (const float*)d_in[13];
  const float* b2  = (const float*)d_in[14];
  const float* W3a = (const float*)d_in[15];
  const float* b3a = (const float*)d_in[16];
  const float* W3b = (const float*)d_in[17];
  const float* b3b = (const float*)d_in[18];
  const float* Wf  = (const float*)d_in[19];
  const float* bf  = (const float*)d_in[20];

  char* wsb = (char*)d_ws;
  unsigned short* VPH = (unsigned short*)(wsb + B_VPH);
  unsigned short* QLH = (unsigned short*)(wsb + B_QLH);
  unsigned short* KLH = (unsigned short*)(wsb + B_KLH);
  float* EB = (float*)(wsb + B_E);
  float* SM = (float*)(wsb + B_SM);
  unsigned short* XT = (unsigned short*)(wsb + B_X);
  float* outp = (float*)d_out;

  hipMemsetAsync((void*)SM, 0, ZEND * sizeof(float), stream);

  k_prep0<<<98, 256, 0, stream>>>(x, Wqkv, SM + QC, SM + KC, SM + VC,
                                  XT + XT_QCH, XT + XT_KCH, XT + XT_WQKV);
  k_prep1<<<564, 256, 0, stream>>>(SM + VC, Wa, Wb, ba, bb, Wf, bf,
                                   SM + VCA, SM + VCB, XT + XT_VCAT, XT + XT_VCBT,
                                   SM + WFA, SM + WFB, SM + BFA, SM + BFB,
                                   XT + XT_WFAT, XT + XT_WFBT);
  k_osc<<<1, 256, 0, stream>>>(SM + QC, SM + KC, SM + VC, SM + OSCB);
  k_gated<<<50, 256, 0, stream>>>(SM + OSCB, Wa, Wb, ba, bb, Wc, bc, SM + ASC);

  k_path1<<<4096, 256, 0, stream>>>(x, XT + XT_WQKV, sln, XT + XT_KCH, XT + XT_QCH,
                                    XT + XT_VCAT, XT + XT_VCBT, ba, bb, Wc, bc,
                                    VPH, QLH, KLH, EB, SM + W50, SM + EDENC, SM + OCCDEN);
  k_occnum<<<256, 256, 0, stream>>>(EB, VPH, SM + OCCRAW);
  k_kv<<<dim3(2, 128), 256, 0, stream>>>(KLH, VPH, (unsigned short*)EB, SM + KLSUM);
  k_fin2<<<306, 256, 0, stream>>>((const unsigned short*)EB, XT + XT_KVT,
                                  SM + OCCRAW, SM + OCCDEN, SM + OCCB);
  k_gated<<<50, 256, 0, stream>>>(SM + OCCB, Wa, Wb, ba, bb, Wc, bc, SM + ACC50);

  k_tail<<<4096, 256, 0, stream>>>(QLH, XT + XT_KVT, SM + KLSUM, VPH, dwcw, dwcb,
                                   XT + XT_WFAT, XT + XT_WFBT, SM + BFA, SM + BFB,
                                   Wc, bc, SM + H2T, SM + H2DEN);

  k_final<<<1, 256, 0, stream>>>(SM + ACC50, SM + OCCB, SM + ASC, SM + OSCB,
                                 SM + W50, SM + EDENC, SM + H2T, SM + H2DEN,
                                 SM + VC, Wf, bf, W1, b1, W2, b2, W3a, b3a, W3b, b3b, outp);
}

// Round 7
// 971.050 us; speedup vs baseline: 2.0768x; 1.0610x over previous
//
#include <hip/hip_runtime.h>
#include <math.h>

// MixedAttentionLayer — R7: k_kv rewrite (LDS-staged coalesced tiles, 4-band
// grid), atomic partitioning (x8) for w50/occden/eden/h2t/h2den/klsum,
// fin2/final partial reductions. path1/tail structure unchanged from R6.

constexpr int DD = 256;
constexpr int MM = 50;
constexpr float SCL = 0.0625f; // 256^-0.5

// ---- byte offsets in d_ws ----
constexpr size_t B_VPH = 0;                      // 32 MiB bf16 vp
constexpr size_t B_QLH = (size_t)32 << 20;       // 32 MiB bf16 ql
constexpr size_t B_KLH = (size_t)64 << 20;       // 32 MiB bf16 kl
constexpr size_t B_E   = (size_t)96 << 20;       // 16 MiB f32 E; later bf16 kv partials
constexpr size_t B_SM  = (size_t)112 << 20;      // small fp32 region
constexpr size_t B_X   = B_SM + ((size_t)2 << 20); // bf16 prep region

// ---- float offsets within SM region (zeroed part first) ----
constexpr size_t KLSUMR = 0;          // 256   reduced klsum (fin2)
constexpr size_t KLSUMP = 256;        // 8*256 partials
constexpr size_t OCCDENP= 2304;       // 8*64
constexpr size_t W50P   = 2816;       // 8*64
constexpr size_t EDENP  = 3328;       // 8
constexpr size_t H2TP   = 3336;       // 8*256
constexpr size_t H2DENP = 5384;       // 8
constexpr size_t OCCRAW = 5392;       // 12800
constexpr size_t ZEND   = 18192;
constexpr size_t QC     = ZEND;
constexpr size_t KC     = QC + 12800;
constexpr size_t VC     = KC + 12800;
constexpr size_t VCA    = VC + 12800;
constexpr size_t VCB    = VCA + 12800;
constexpr size_t WFA    = VCB + 12800;
constexpr size_t WFB    = WFA + 65536;
constexpr size_t BFA    = WFB + 65536;
constexpr size_t BFB    = BFA + 256;
constexpr size_t OSCB   = BFB + 256;
constexpr size_t OCCB   = OSCB + 12800;
constexpr size_t ASC    = OCCB + 12800;
constexpr size_t ACC50  = ASC + 64;
constexpr size_t SMEND  = ACC50 + 64;

// ---- short offsets within X (bf16 prep) region ----
constexpr size_t XT_WQKV = 0;          // 768*256
constexpr size_t XT_WFAT = 196608;     // 256*256  (Wfa^T)
constexpr size_t XT_WFBT = 262144;     // 256*256
constexpr size_t XT_KVT  = 327680;     // 256*256  (kv^T)
constexpr size_t XT_QCH  = 393216;     // 64*256 (qc, rows 50..63 zero)
constexpr size_t XT_KCH  = 409600;     // 64*256
constexpr size_t XT_VCAT = 425984;     // 256*64 (Vca^T, cols 50..63 zero)
constexpr size_t XT_VCBT = 442368;     // 256*64
constexpr size_t XT_END  = 458752;
constexpr size_t WS_NEEDED = B_X + XT_END * 2;

typedef short bf16x8 __attribute__((ext_vector_type(8)));
typedef float f32x4 __attribute__((ext_vector_type(4)));

__device__ __forceinline__ float sigmoidf_(float x){ return 1.0f / (1.0f + expf(-x)); }

__device__ __forceinline__ float bf2f(unsigned short u){
  return __uint_as_float(((unsigned int)u) << 16);
}
__device__ __forceinline__ unsigned short f2bf(float f){
  unsigned int x = __float_as_uint(f);
  unsigned int r = (x + 0x7fffu + ((x >> 16) & 1u)) >> 16;
  return (unsigned short)r;
}
__device__ __forceinline__ f32x4 mfma16(bf16x8 a, bf16x8 b, f32x4 c){
  return __builtin_amdgcn_mfma_f32_16x16x32_bf16(a, b, c, 0, 0, 0);
}

__device__ __forceinline__ float waveAllSum(float v){
  #pragma unroll
  for (int m = 1; m < 64; m <<= 1) v += __shfl_xor(v, m, 64);
  return v;
}

// ---------- prep0: tiled Wqkv^T (blocks 0..47) + qc/kc/vc (blocks 48..97) ----------
__global__ void __launch_bounds__(256) k_prep0(const float* __restrict__ x, const float* __restrict__ Wqkv,
                                               float* qc, float* kc, float* vc,
                                               unsigned short* qch, unsigned short* kch,
                                               unsigned short* __restrict__ WT){
  const int b = blockIdx.x, t = threadIdx.x;
  if (b < 48) {
    __shared__ unsigned short Tt[64][68];
    const int bn = b % 12, bk = b / 12;
    const int n0 = bn * 64, k0g = bk * 64;
    #pragma unroll
    for (int i = 0; i < 16; i++) {
      const int k_l = (t >> 6) + i * 4;
      const int n_l = t & 63;
      Tt[n_l][k_l] = f2bf(Wqkv[(size_t)(k0g + k_l) * 768 + n0 + n_l]);
    }
    __syncthreads();
    #pragma unroll
    for (int i = 0; i < 4; i++) {
      const int n_l = (t >> 4) + i * 16;
      const int k4 = (t & 15) * 4;
      ushort4 v = *(const ushort4*)&Tt[n_l][k4];
      *(ushort4*)&WT[(size_t)(n0 + n_l) * 256 + k0g + k4] = v;
    }
    return;
  }
  __shared__ float xs[256];
  const int r = b - 48, j = t;
  xs[j] = x[r * DD + j];
  __syncthreads();
  float aq = 0.f, ak = 0.f, av = 0.f;
  for (int k = 0; k < DD; k++) {
    float xv = xs[k];
    aq += xv * Wqkv[k * 768 + j];
    ak += xv * Wqkv[k * 768 + 256 + j];
    av += xv * Wqkv[k * 768 + 512 + j];
  }
  qc[r * DD + j] = aq; kc[r * DD + j] = ak; vc[r * DD + j] = av;
  qch[r * DD + j] = f2bf(aq); kch[r * DD + j] = f2bf(ak);
  if (r == 0) {
    for (int c = 50; c < 64; c++) { qch[c * DD + j] = 0; kch[c * DD + j] = 0; }
  }
}

// ---------- prep1: Vca/Vcb (blocks 0..49) + Wfa/Wfb/bfa/bfb (blocks 50..563) ----------
__global__ void __launch_bounds__(256) k_prep1(const float* vc, const float* Wa, const float* Wb,
                                               const float* ba, const float* bb,
                                               const float* Wf, const float* bf,
                                               float* Vca, float* Vcb,
                                               unsigned short* VcaTh, unsigned short* VcbTh,
                                               float* Wfa, float* Wfb, float* bfa, float* bfb,
                                               unsigned short* WfaTh, unsigned short* WfbTh){
  __shared__ float rs[256];
  const int b = blockIdx.x, j = threadIdx.x;
  if (b < 50) {
    const int r = b;
    rs[j] = vc[r * DD + j];
    __syncthreads();
    float a = 0.f, bv = 0.f;
    for (int k = 0; k < DD; k++) { float v = rs[k]; a += v * Wa[k * DD + j]; bv += v * Wb[k * DD + j]; }
    Vca[r * DD + j] = a; Vcb[r * DD + j] = bv;
    VcaTh[j * 64 + r] = f2bf(a); VcbTh[j * 64 + r] = f2bf(bv);
    if (r == 0) {
      for (int c = 50; c < 64; c++) { VcaTh[j * 64 + c] = 0; VcbTh[j * 64 + c] = 0; }
    }
    return;
  }
  const int bb2 = b - 50;
  const float* src; const float* Wm;
  if (bb2 < 256)      { src = Wf + bb2 * DD;         Wm = Wa; }
  else if (bb2 < 512) { src = Wf + (bb2 - 256) * DD; Wm = Wb; }
  else if (bb2 == 512){ src = bf;                    Wm = Wa; }
  else                { src = bf;                    Wm = Wb; }
  rs[j] = src[j];
  __syncthreads();
  float a = 0.f;
  for (int k = 0; k < DD; k++) a += rs[k] * Wm[k * DD + j];
  if (bb2 < 256)      { Wfa[bb2 * DD + j] = a; WfaTh[(size_t)j * DD + bb2] = f2bf(a); }
  else if (bb2 < 512) { Wfb[(bb2 - 256) * DD + j] = a; WfbTh[(size_t)j * DD + (bb2 - 256)] = f2bf(a); }
  else if (bb2 == 512) bfa[j] = a + ba[j];
  else bfb[j] = a + bb[j];
}

// ---------- osc = softmax(scale*qc@kc^T)@vc ----------
__global__ void __launch_bounds__(256) k_osc(const float* qc, const float* kc, const float* vc, float* osc){
  __shared__ float S[50][64];
  __shared__ float P[50][64];
  int t = threadIdx.x;
  for (int p = t; p < 2500; p += 256) {
    int i = p / 50, jj = p % 50;
    float s = 0.f;
    for (int k = 0; k < DD; k++) s += qc[i * DD + k] * kc[jj * DD + k];
    S[i][jj] = s * SCL;
  }
  __syncthreads();
  if (t < 50) {
    float mx = -1e30f;
    for (int jj = 0; jj < 50; jj++) mx = fmaxf(mx, S[t][jj]);
    float den = 0.f;
    for (int jj = 0; jj < 50; jj++) { float e = expf(S[t][jj] - mx); P[t][jj] = e; den += e; }
    float inv = 1.0f / den;
    for (int jj = 0; jj < 50; jj++) P[t][jj] *= inv;
  }
  __syncthreads();
  for (int i = 0; i < 50; i++) {
    float a = 0.f;
    for (int jj = 0; jj < 50; jj++) a += P[i][jj] * vc[jj * DD + t];
    osc[i * DD + t] = a;
  }
}

// ---------- gated() on 50 rows ----------
__global__ void __launch_bounds__(256) k_gated(const float* __restrict__ tin,
                                               const float* __restrict__ Wa, const float* __restrict__ Wb,
                                               const float* __restrict__ ba, const float* __restrict__ bb,
                                               const float* __restrict__ Wc, const float* __restrict__ bc,
                                               float* __restrict__ A){
  int r = blockIdx.x, j = threadIdx.x;
  __shared__ float ts[256];
  __shared__ float red[4];
  ts[j] = tin[r * DD + j];
  __syncthreads();
  float u = 0.f, v = 0.f;
  for (int k = 0; k < DD; k++) { float tv = ts[k]; u += tv * Wa[k * DD + j]; v += tv * Wb[k * DD + j]; }
  float g = tanhf(u + ba[j]) * sigmoidf_(v + bb[j]) * Wc[j];
  g = waveAllSum(g);
  int lane = j & 63, wv = j >> 6;
  if (lane == 0) red[wv] = g;
  __syncthreads();
  if (j == 0) A[r] = red[0] + red[1] + red[2] + red[3] + bc[0];
}

// ---------- fused path kernel ----------
__global__ void __launch_bounds__(256) k_path1(
    const float* __restrict__ x, const unsigned short* __restrict__ WqkvTh,
    const float* __restrict__ sln,
    const unsigned short* __restrict__ kch, const unsigned short* __restrict__ qch,
    const unsigned short* __restrict__ VcaTh, const unsigned short* __restrict__ VcbTh,
    const float* __restrict__ ba, const float* __restrict__ bb,
    const float* __restrict__ Wc, const float* __restrict__ bc,
    unsigned short* __restrict__ vph, unsigned short* __restrict__ qlh, unsigned short* __restrict__ klh,
    float* __restrict__ E, float* __restrict__ w50p, float* __restrict__ edenp, float* __restrict__ occdenp){
  __shared__ unsigned short xsh[16][264];
  __shared__ unsigned short qpsb[16][264];
  __shared__ unsigned short kpsb[16][264];
  __shared__ float scap[16][68];
  __shared__ float scac[16][68];
  __shared__ unsigned short Psh[16][72];
  __shared__ float occs[64];
  __shared__ float evp[16];
  const int tid = threadIdx.x;
  const int i0 = blockIdx.x * 16;
  const int part = blockIdx.x & 7;
  const int lane = tid & 63;
  const int wvv = tid >> 6;
  const int cn = lane & 15;
  const int m0 = (lane >> 4) * 4;
  const int kq = (lane >> 4) * 8;

  if (tid < 64) occs[tid] = 0.f;
  for (int l = tid; l < 4096; l += 256) {
    int r = l >> 8, c = l & 255;
    xsh[r][c] = f2bf(x[(size_t)(MM + i0 + r) * DD + c]);
  }
  __syncthreads();

  // ---- GEMM: [16 x 256] @ [256 x 768], double-buffered B ----
  bf16x8 af[8];
  #pragma unroll
  for (int k0 = 0; k0 < 8; k0++)
    af[k0] = *(const bf16x8*)&xsh[cn][k0 * 32 + kq];
  bf16x8 b0[8], b1[8];
  {
    const size_t nrow = (size_t)(wvv * 16 + cn) * 256;
    #pragma unroll
    for (int k0 = 0; k0 < 8; k0++) b0[k0] = *(const bf16x8*)&WqkvTh[nrow + k0 * 32 + kq];
  }
  #pragma unroll 1
  for (int tt = 0; tt < 12; tt++) {
    const int t = wvv + 4 * tt;
    if (tt + 1 < 12) {
      const size_t nrow = (size_t)((t + 4) * 16 + cn) * 256;
      #pragma unroll
      for (int k0 = 0; k0 < 8; k0++) b1[k0] = *(const bf16x8*)&WqkvTh[nrow + k0 * 32 + kq];
    }
    f32x4 acc = {0.f, 0.f, 0.f, 0.f};
    #pragma unroll
    for (int k0 = 0; k0 < 8; k0++) acc = mfma16(af[k0], b0[k0], acc);
    if (t < 16) {
      int c = t * 16 + cn;
      #pragma unroll
      for (int i = 0; i < 4; i++) qpsb[m0 + i][c] = f2bf(acc[i]);
    } else if (t < 32) {
      int c = (t - 16) * 16 + cn;
      #pragma unroll
      for (int i = 0; i < 4; i++) kpsb[m0 + i][c] = f2bf(acc[i]);
    } else {
      int c = (t - 32) * 16 + cn;
      #pragma unroll
      for (int i = 0; i < 4; i++) vph[(size_t)(i0 + m0 + i) * DD + c] = f2bf(acc[i]);
    }
    #pragma unroll
    for (int k0 = 0; k0 < 8; k0++) b0[k0] = b1[k0];
  }
  __syncthreads();

  // ---- scores via MFMA ----
  {
    const int n0 = wvv * 16;
    f32x4 accp = {0.f,0.f,0.f,0.f}, accc = {0.f,0.f,0.f,0.f};
    #pragma unroll
    for (int k0 = 0; k0 < 8; k0++) {
      bf16x8 aq = *(const bf16x8*)&qpsb[cn][k0 * 32 + kq];
      bf16x8 ak = *(const bf16x8*)&kpsb[cn][k0 * 32 + kq];
      bf16x8 bk = *(const bf16x8*)&kch[(size_t)(n0 + cn) * DD + k0 * 32 + kq];
      bf16x8 bq = *(const bf16x8*)&qch[(size_t)(n0 + cn) * DD + k0 * 32 + kq];
      accp = mfma16(aq, bk, accp);
      accc = mfma16(ak, bq, accc);
    }
    #pragma unroll
    for (int i = 0; i < 4; i++) {
      scap[m0 + i][n0 + cn] = accp[i];
      scac[m0 + i][n0 + cn] = accc[i];
    }
  }
  __syncthreads();

  // ---- phase B: transforms + softmax p ----
  float4 sl4 = ((const float4*)sln)[lane];
  float4 rsp;
  rsp.x = 1.0f / log1pf(expf(sl4.x)); rsp.y = 1.0f / log1pf(expf(sl4.y));
  rsp.z = 1.0f / log1pf(expf(sl4.z)); rsp.w = 1.0f / log1pf(expf(sl4.w));
  float4 ba4 = ((const float4*)ba)[lane];
  float4 bb4 = ((const float4*)bb)[lane];
  float4 wc4 = ((const float4*)Wc)[lane];
  float bcv = bc[0];
  float occacc = 0.f;
  for (int rr = 0; rr < 4; rr++) {
    const int r = wvv * 4 + rr;
    const int row = i0 + r;
    ushort4 qu = *(const ushort4*)&qpsb[r][lane * 4];
    ushort4 ku = *(const ushort4*)&kpsb[r][lane * 4];
    float4 q4 = {bf2f(qu.x), bf2f(qu.y), bf2f(qu.z), bf2f(qu.w)};
    float4 k4 = {bf2f(ku.x), bf2f(ku.y), bf2f(ku.z), bf2f(ku.w)};
    float4 lq, lk;
    lq.x = (fmaxf(q4.x, 0.f) + 1e-6f) * rsp.x; lq.y = (fmaxf(q4.y, 0.f) + 1e-6f) * rsp.y;
    lq.z = (fmaxf(q4.z, 0.f) + 1e-6f) * rsp.z; lq.w = (fmaxf(q4.w, 0.f) + 1e-6f) * rsp.w;
    lk.x = (fmaxf(k4.x, 0.f) + 1e-6f) * rsp.x; lk.y = (fmaxf(k4.y, 0.f) + 1e-6f) * rsp.y;
    lk.z = (fmaxf(k4.z, 0.f) + 1e-6f) * rsp.z; lk.w = (fmaxf(k4.w, 0.f) + 1e-6f) * rsp.w;
    float4 q3, k3;
    q3.x = lq.x*lq.x*lq.x; q3.y = lq.y*lq.y*lq.y; q3.z = lq.z*lq.z*lq.z; q3.w = lq.w*lq.w*lq.w;
    k3.x = lk.x*lk.x*lk.x; k3.y = lk.y*lk.y*lk.y; k3.z = lk.z*lk.z*lk.z; k3.w = lk.w*lk.w*lk.w;
    float n1q = lq.x*lq.x + lq.y*lq.y + lq.z*lq.z + lq.w*lq.w;
    float n3q = q3.x*q3.x + q3.y*q3.y + q3.z*q3.z + q3.w*q3.w;
    float n1k = lk.x*lk.x + lk.y*lk.y + lk.z*lk.z + lk.w*lk.w;
    float n3k = k3.x*k3.x + k3.y*k3.y + k3.z*k3.z + k3.w*k3.w;
    n1q = waveAllSum(n1q); n3q = waveAllSum(n3q);
    n1k = waveAllSum(n1k); n3k = waveAllSum(n3k);
    float fq = sqrtf(n1q / n3q);
    float fk = sqrtf(n1k / n3k);
    ushort4 qo, ko;
    qo.x = f2bf(q3.x * fq); qo.y = f2bf(q3.y * fq); qo.z = f2bf(q3.z * fq); qo.w = f2bf(q3.w * fq);
    ko.x = f2bf(k3.x * fk); ko.y = f2bf(k3.y * fk); ko.z = f2bf(k3.z * fk); ko.w = f2bf(k3.w * fk);
    *(ushort4*)&qlh[(size_t)row * DD + lane * 4] = qo;
    *(ushort4*)&klh[(size_t)row * DD + lane * 4] = ko;
    float ecap = (lane < 50) ? expf(scap[r][lane] * SCL) : 0.f;
    float ecac = (lane < 50) ? expf(scac[r][lane] * SCL) : 0.f;
    E[(size_t)row * 64 + lane] = ecac;
    occacc += ecac;
    float den = waveAllSum(ecap);
    Psh[r][lane] = f2bf(ecap / den);
  }
  atomicAdd(&occs[lane], occacc);
  __syncthreads();

  // ---- gate via MFMA: u = P@Vca, v = P@Vcb ----
  {
    bf16x8 ap[2];
    #pragma unroll
    for (int k0 = 0; k0 < 2; k0++) ap[k0] = *(const bf16x8*)&Psh[cn][k0 * 32 + kq];
    #pragma unroll 1
    for (int tt = 0; tt < 4; tt++) {
      const int nt = wvv * 4 + tt;
      f32x4 au = {0.f,0.f,0.f,0.f}, av = {0.f,0.f,0.f,0.f};
      #pragma unroll
      for (int k0 = 0; k0 < 2; k0++) {
        bf16x8 bu = *(const bf16x8*)&VcaTh[(size_t)(nt * 16 + cn) * 64 + k0 * 32 + kq];
        bf16x8 bv = *(const bf16x8*)&VcbTh[(size_t)(nt * 16 + cn) * 64 + k0 * 32 + kq];
        au = mfma16(ap[k0], bu, au);
        av = mfma16(ap[k0], bv, av);
      }
      #pragma unroll
      for (int i = 0; i < 4; i++) {
        qpsb[m0 + i][nt * 16 + cn] = f2bf(au[i]);
        kpsb[m0 + i][nt * 16 + cn] = f2bf(av[i]);
      }
    }
  }
  __syncthreads();

  // ---- gate eval ----
  #pragma unroll
  for (int rr = 0; rr < 4; rr++) {
    const int r = wvv * 4 + rr;
    ushort4 uu = *(const ushort4*)&qpsb[r][lane * 4];
    ushort4 vv = *(const ushort4*)&kpsb[r][lane * 4];
    float g = tanhf(bf2f(uu.x) + ba4.x) * sigmoidf_(bf2f(vv.x) + bb4.x) * wc4.x
            + tanhf(bf2f(uu.y) + ba4.y) * sigmoidf_(bf2f(vv.y) + bb4.y) * wc4.y
            + tanhf(bf2f(uu.z) + ba4.z) * sigmoidf_(bf2f(vv.z) + bb4.z) * wc4.z
            + tanhf(bf2f(uu.w) + ba4.w) * sigmoidf_(bf2f(vv.w) + bb4.w) * wc4.w;
    g = waveAllSum(g);
    if (lane == 0) evp[r] = expf(g + bcv);
  }
  __syncthreads();
  if (tid < 64) {
    float s = 0.f;
    #pragma unroll
    for (int r = 0; r < 16; r++) s += evp[r] * bf2f(Psh[r][tid]);
    atomicAdd(&w50p[part * 64 + tid], s);
    if (tid < 50) atomicAdd(&occdenp[part * 64 + tid], occs[tid]);
  }
  if (tid == 0) {
    float es = 0.f;
    #pragma unroll
    for (int r = 0; r < 16; r++) es += evp[r];
    atomicAdd(&edenp[part], es);
  }
}

// ---------- occ numerator ----------
__global__ void __launch_bounds__(256) k_occnum(const float* __restrict__ E, const unsigned short* __restrict__ vph,
                                                float* __restrict__ occraw){
  int d = threadIdx.x;
  int j0 = blockIdx.x * 256;
  __shared__ float Es[32][64];
  float acc[52];
  #pragma unroll
  for (int i = 0; i < 52; i++) acc[i] = 0.f;
  for (int s = 0; s < 8; s++) {
    for (int l = threadIdx.x; l < 512; l += 256) {
      int jj = l >> 4, cq = l & 15;
      *(float4*)&Es[jj][cq * 4] = ((const float4*)(E + (size_t)(j0 + s * 32 + jj) * 64))[cq];
    }
    __syncthreads();
    for (int jj = 0; jj < 32; jj++) {
      float vv = bf2f(vph[(size_t)(j0 + s * 32 + jj) * DD + d]);
      #pragma unroll
      for (int q = 0; q < 13; q++) {
        float4 e4 = *(const float4*)&Es[jj][q * 4];
        acc[q * 4 + 0] += e4.x * vv; acc[q * 4 + 1] += e4.y * vv;
        acc[q * 4 + 2] += e4.z * vv; acc[q * 4 + 3] += e4.w * vv;
      }
    }
    __syncthreads();
  }
  for (int i = 0; i < 50; i++) atomicAdd(&occraw[i * DD + d], acc[i]);
}

// ---------- kv = kl^T @ vp: LDS-staged MFMA, 4 c-bands x 128 z-chunks ----------
// Block: 512 rows (16 steps x 32). LDS row-major tiles; fragments via ds_read_u16.
__global__ void __launch_bounds__(256) k_kv(const unsigned short* __restrict__ klh,
                                            const unsigned short* __restrict__ vph,
                                            unsigned short* __restrict__ PP,
                                            float* __restrict__ klsump){
  __shared__ unsigned short Akl[32][72];    // [j][c] 64 cols (stride 72 for b128 staging writes)
  __shared__ unsigned short Bvp[32][264];   // [j][d] 256 cols
  const int tid = threadIdx.x;
  const int lane = tid & 63;
  const int wvv = tid >> 6;
  const int cn = lane & 15;
  const int m0 = (lane >> 4) * 4;
  const int kq = (lane >> 4) * 8;
  const int cb = blockIdx.x;          // c band (64 wide)
  const int z  = blockIdx.y;          // j chunk (512 rows)
  const int jj = tid >> 3;            // staging row 0..31
  const int c8 = (tid & 7) * 8;       // staging col x8

  f32x4 acc[4][4];
  f32x4 acc1[4];
  #pragma unroll
  for (int mt = 0; mt < 4; mt++) {
    acc1[mt] = (f32x4){0.f,0.f,0.f,0.f};
    #pragma unroll
    for (int tl = 0; tl < 4; tl++) acc[mt][tl] = (f32x4){0.f,0.f,0.f,0.f};
  }
  bf16x8 ones;
  #pragma unroll
  for (int i = 0; i < 8; i++) ones[i] = (short)0x3F80;

  const int jbase = z * 512;
  #pragma unroll 1
  for (int step = 0; step < 16; step++) {
    const int j0 = jbase + step * 32;
    // stage kl band (32x64) and vp (32x256), coalesced 16B loads, b128 LDS writes
    {
      bf16x8 av = *(const bf16x8*)&klh[(size_t)(j0 + jj) * 256 + cb * 64 + c8];
      *(bf16x8*)&Akl[jj][c8] = av;
      #pragma unroll
      for (int rep = 0; rep < 4; rep++) {
        bf16x8 bv = *(const bf16x8*)&vph[(size_t)(j0 + jj) * 256 + rep * 64 + c8];
        *(bf16x8*)&Bvp[jj][rep * 64 + c8] = bv;
      }
    }
    __syncthreads();
    // fragments: A[m=kl-col][k=j], B[n=vp-col][k=j] via strided u16 LDS reads
    bf16x8 afr[4], bfr[4];
    #pragma unroll
    for (int mt = 0; mt < 4; mt++) {
      #pragma unroll
      for (int e = 0; e < 8; e++) afr[mt][e] = (short)Akl[kq + e][cn + mt * 16];
    }
    #pragma unroll
    for (int tl = 0; tl < 4; tl++) {
      #pragma unroll
      for (int e = 0; e < 8; e++) bfr[tl][e] = (short)Bvp[kq + e][wvv * 64 + tl * 16 + cn];
    }
    #pragma unroll
    for (int mt = 0; mt < 4; mt++) {
      acc1[mt] = mfma16(afr[mt], ones, acc1[mt]);
      #pragma unroll
      for (int tl = 0; tl < 4; tl++) acc[mt][tl] = mfma16(afr[mt], bfr[tl], acc[mt][tl]);
    }
    __syncthreads();
  }
  unsigned short* P = PP + ((size_t)(cb * 128 + z)) * 16384;
  #pragma unroll
  for (int mt = 0; mt < 4; mt++)
    #pragma unroll
    for (int tl = 0; tl < 4; tl++) {
      const int n = (wvv * 4 + tl) * 16 + cn;
      #pragma unroll
      for (int i = 0; i < 4; i++)
        P[(size_t)(mt * 16 + m0 + i) * 256 + n] = f2bf(acc[mt][tl][i]);
    }
  // klsum partials (acc1 identical across waves; n-col 0 lanes hold the m values)
  if (wvv == 0 && cn == 0) {
    #pragma unroll
    for (int mt = 0; mt < 4; mt++)
      #pragma unroll
      for (int i = 0; i < 4; i++)
        atomicAdd(&klsump[(z & 7) * 256 + cb * 64 + mt * 16 + m0 + i], acc1[mt][i]);
  }
}

// ---------- merged: kvred (0..255) + occfin (256..305) + klsum reduce (306) ----------
__global__ void __launch_bounds__(256) k_fin2(const unsigned short* __restrict__ PP,
                                              unsigned short* __restrict__ kvTh,
                                              const float* __restrict__ occraw,
                                              const float* __restrict__ occdenp,
                                              float* __restrict__ occ,
                                              const float* __restrict__ klsump,
                                              float* __restrict__ klsum){
  const int b = blockIdx.x, d = threadIdx.x;
  if (b < 256) {
    const int cb = b >> 6, m = b & 63;
    float s = 0.f;
    for (int z = 0; z < 128; z++)
      s += bf2f(PP[((size_t)(cb * 128 + z)) * 16384 + (size_t)m * 256 + d]);
    kvTh[(size_t)d * 256 + b] = f2bf(s);
  } else if (b < 306) {
    const int i = b - 256;
    float den = 0.f;
    #pragma unroll
    for (int p = 0; p < 8; p++) den += occdenp[p * 64 + i];
    occ[i * DD + d] = occraw[i * DD + d] / den;
  } else {
    float s = 0.f;
    #pragma unroll
    for (int p = 0; p < 8; p++) s += klsump[p * 256 + d];
    klsum[d] = s;
  }
}

// ---------- fused tail ----------
__global__ void __launch_bounds__(256) k_tail(const unsigned short* __restrict__ qlh,
                                              const unsigned short* __restrict__ kvTh,
                                              const float* __restrict__ klsum,
                                              const unsigned short* __restrict__ vph,
                                              const float* __restrict__ dwcw, const float* __restrict__ dwcb,
                                              const unsigned short* __restrict__ WfaTh,
                                              const unsigned short* __restrict__ WfbTh,
                                              const float* __restrict__ bfa, const float* __restrict__ bfb,
                                              const float* __restrict__ Wc, const float* __restrict__ bc,
                                              float* __restrict__ h2tp, float* __restrict__ h2denp){
  __shared__ unsigned short Tsh[16][264];
  __shared__ unsigned short OSb[16][264];
  __shared__ unsigned short aVb[16][264];
  __shared__ float zf[16];
  __shared__ float ev[16];
  const int tid = threadIdx.x;
  const int i0 = blockIdx.x * 16;
  const int part = blockIdx.x & 7;
  const int lane = tid & 63;
  const int wvv = tid >> 6;
  const int cn = lane & 15;
  const int m0 = (lane >> 4) * 4;
  const int kq = (lane >> 4) * 8;
  for (int l = tid; l < 1024; l += 256) {
    int r = l >> 6, c4 = (l & 63) * 4;
    *(ushort4*)&Tsh[r][c4] = *(const ushort4*)&qlh[(size_t)(i0 + r) * DD + c4];
  }
  __syncthreads();
  {
    bf16x8 afq[8];
    #pragma unroll
    for (int k0 = 0; k0 < 8; k0++) afq[k0] = *(const bf16x8*)&Tsh[cn][k0 * 32 + kq];
    #pragma unroll 1
    for (int tt = 0; tt < 4; tt++) {
      const int nt = wvv * 4 + tt;
      f32x4 acc = {0.f,0.f,0.f,0.f};
      #pragma unroll
      for (int k0 = 0; k0 < 8; k0++) {
        bf16x8 b = *(const bf16x8*)&kvTh[(size_t)(nt * 16 + cn) * 256 + k0 * 32 + kq];
        acc = mfma16(afq[k0], b, acc);
      }
      #pragma unroll
      for (int i = 0; i < 4; i++) OSb[m0 + i][nt * 16 + cn] = f2bf(acc[i]);
    }
  }
  {
    float4 ks4 = ((const float4*)klsum)[lane];
    #pragma unroll
    for (int rr = 0; rr < 4; rr++) {
      const int r = wvv * 4 + rr;
      ushort4 q4 = *(const ushort4*)&Tsh[r][lane * 4];
      float s = bf2f(q4.x)*ks4.x + bf2f(q4.y)*ks4.y + bf2f(q4.z)*ks4.z + bf2f(q4.w)*ks4.w;
      s = waveAllSum(s);
      if (lane == 0) zf[r] = 1.0f / (s + 1e-6f);
    }
  }
  __syncthreads();
  const int j = tid;
  float w[25];
  #pragma unroll
  for (int t = 0; t < 25; t++) w[t] = dwcw[j * 25 + t];
  const float bias = dwcb[j];
  const int y = i0 >> 8, x0 = i0 & 255;
  float fm[16];
  #pragma unroll
  for (int r = 0; r < 16; r++) fm[r] = bias;
  #pragma unroll
  for (int dy = -2; dy <= 2; dy++) {
    const int yy = y + dy;
    if ((unsigned)yy > 255u) continue;
    float buf[20];
    #pragma unroll
    for (int i = 0; i < 20; i++) {
      const int xx = x0 - 2 + i;
      buf[i] = ((unsigned)xx <= 255u) ? bf2f(vph[(size_t)((yy << 8) + xx) * DD + j]) : 0.f;
    }
    const float* wr = &w[(dy + 2) * 5];
    #pragma unroll
    for (int r = 0; r < 16; r++)
      fm[r] += buf[r] * wr[0] + buf[r+1] * wr[1] + buf[r+2] * wr[2]
             + buf[r+3] * wr[3] + buf[r+4] * wr[4];
  }
  float Tf[16];
  #pragma unroll
  for (int r = 0; r < 16; r++) {
    Tf[r] = bf2f(OSb[r][j]) * zf[r] + fm[r];
    Tsh[r][j] = f2bf(Tf[r]);
  }
  __syncthreads();
  {
    bf16x8 aft[8];
    #pragma unroll
    for (int k0 = 0; k0 < 8; k0++) aft[k0] = *(const bf16x8*)&Tsh[cn][k0 * 32 + kq];
    #pragma unroll 1
    for (int jb = 0; jb < 8; jb++) {
      const int nt = wvv * 4 + (jb & 3);
      const unsigned short* Bt = (jb < 4) ? WfaTh : WfbTh;
      f32x4 acc = {0.f,0.f,0.f,0.f};
      #pragma unroll
      for (int k0 = 0; k0 < 8; k0++) {
        bf16x8 b = *(const bf16x8*)&Bt[(size_t)(nt * 16 + cn) * 256 + k0 * 32 + kq];
        acc = mfma16(aft[k0], b, acc);
      }
      unsigned short (*dst)[264] = (jb < 4) ? OSb : aVb;
      #pragma unroll
      for (int i = 0; i < 4; i++) dst[m0 + i][nt * 16 + cn] = f2bf(acc[i]);
    }
  }
  __syncthreads();
  {
    float4 bfa4 = ((const float4*)bfa)[lane];
    float4 bfb4 = ((const float4*)bfb)[lane];
    float4 wc4 = ((const float4*)Wc)[lane];
    const float bcv = bc[0];
    #pragma unroll
    for (int rr = 0; rr < 4; rr++) {
      const int r = wvv * 4 + rr;
      ushort4 uu = *(const ushort4*)&OSb[r][lane * 4];
      ushort4 vv = *(const ushort4*)&aVb[r][lane * 4];
      float g = tanhf(bf2f(uu.x) + bfa4.x) * sigmoidf_(bf2f(vv.x) + bfb4.x) * wc4.x
              + tanhf(bf2f(uu.y) + bfa4.y) * sigmoidf_(bf2f(vv.y) + bfb4.y) * wc4.y
              + tanhf(bf2f(uu.z) + bfa4.z) * sigmoidf_(bf2f(vv.z) + bfb4.z) * wc4.z
              + tanhf(bf2f(uu.w) + bfa4.w) * sigmoidf_(bf2f(vv.w) + bfb4.w) * wc4.w;
      g = waveAllSum(g);
      if (lane == 0) ev[r] = expf(g + bcv);
    }
  }
  __syncthreads();
  float hp = 0.f;
  #pragma unroll
  for (int r = 0; r < 16; r++) hp += ev[r] * Tf[r];
  atomicAdd(&h2tp[part * 256 + j], hp);
  if (tid == 0) {
    float es = 0.f;
    #pragma unroll
    for (int r = 0; r < 16; r++) es += ev[r];
    atomicAdd(&h2denp[part], es);
  }
}

// ---------- final tiny MLPs ----------
__global__ void __launch_bounds__(256) k_final(
    const float* __restrict__ A_cc, const float* __restrict__ occ,
    const float* __restrict__ A_sc, const float* __restrict__ osc,
    const float* __restrict__ w50p, const float* __restrict__ edenp,
    const float* __restrict__ h2tp, const float* __restrict__ h2denp,
    const float* __restrict__ vc, const float* __restrict__ Wf, const float* __restrict__ bf,
    const float* __restrict__ W1, const float* __restrict__ b1,
    const float* __restrict__ W2, const float* __restrict__ b2,
    const float* __restrict__ W3a, const float* __restrict__ b3a,
    const float* __restrict__ W3b, const float* __restrict__ b3b,
    float* __restrict__ out){
  int j = threadIdx.x;
  __shared__ float pw[64];
  __shared__ float w50t[64];
  __shared__ float t1[256], t2[256], h1[256], h2[256], fz[512], z1[256];
  // reduce partitioned accumulators
  if (j < 64) {
    float s = 0.f;
    #pragma unroll
    for (int p = 0; p < 8; p++) s += w50p[p * 64 + j];
    w50t[j] = s;
  }
  float edentot = 0.f, h2dentot = 0.f;
  #pragma unroll
  for (int p = 0; p < 8; p++) { edentot += edenp[p]; h2dentot += h2denp[p]; }
  // ===== CROSS =====
  if (j < 64) pw[j] = (j < 50) ? expf(A_cc[j]) : 0.f;
  __syncthreads();
  float den = 0.f;
  for (int i = 0; i < 50; i++) den += pw[i];
  float raw = 0.f;
  for (int i = 0; i < 50; i++) raw += pw[i] * occ[i * DD + j];
  t1[j] = raw / den;
  float r2 = 0.f;
  for (int i = 0; i < 50; i++) r2 += w50t[i] * vc[i * DD + j];
  t2[j] = r2 / edentot;
  __syncthreads();
  float a1 = 0.f, a2 = 0.f;
  for (int k = 0; k < DD; k++) { a1 += t1[k] * W1[k * DD + j]; a2 += t2[k] * W2[k * DD + j]; }
  h1[j] = fmaxf(a1 + b1[j], 0.f);
  h2[j] = fmaxf(a2 + b2[j], 0.f);
  __syncthreads();
  fz[j] = h1[j]; fz[256 + j] = h2[j];
  __syncthreads();
  float z = 0.f;
  for (int k = 0; k < 512; k++) z += fz[k] * W3a[k * DD + j];
  z1[j] = fmaxf(z + b3a[j], 0.f);
  __syncthreads();
  float o = 0.f;
  for (int k = 0; k < DD; k++) o += z1[k] * W3b[k * DD + j];
  out[j] = fmaxf(o + b3b[j], 0.f);
  __syncthreads();
  // ===== SELF =====
  if (j < 64) pw[j] = (j < 50) ? expf(A_sc[j]) : 0.f;
  __syncthreads();
  den = 0.f;
  for (int i = 0; i < 50; i++) den += pw[i];
  raw = 0.f;
  for (int i = 0; i < 50; i++) raw += pw[i] * osc[i * DD + j];
  t1[j] = raw / den;
  {
    float s = 0.f;
    #pragma unroll
    for (int p = 0; p < 8; p++) s += h2tp[p * 256 + j];
    t2[j] = s / h2dentot;
  }
  __syncthreads();
  float hs = 0.f;
  for (int k = 0; k < DD; k++) hs += t2[k] * Wf[k * DD + j];
  __syncthreads();
  t2[j] = hs + bf[j];
  __syncthreads();
  a1 = 0.f; a2 = 0.f;
  for (int k = 0; k < DD; k++) { a1 += t1[k] * W1[k * DD + j]; a2 += t2[k] * W2[k * DD + j]; }
  h1[j] = fmaxf(a1 + b1[j], 0.f);
  h2[j] = fmaxf(a2 + b2[j], 0.f);
  __syncthreads();
  fz[j] = h1[j]; fz[256 + j] = h2[j];
  __syncthreads();
  z = 0.f;
  for (int k = 0; k < 512; k++) z += fz[k] * W3a[k * DD + j];
  z1[j] = fmaxf(z + b3a[j], 0.f);
  __syncthreads();
  o = 0.f;
  for (int k = 0; k < DD; k++) o += z1[k] * W3b[k * DD + j];
  out[256 + j] = fmaxf(o + b3b[j], 0.f);
}

extern "C" void kernel_launch(void* const* d_in, const int* in_sizes, int n_in,
                              void* d_out, int out_size, void* d_ws, size_t ws_size,
                              hipStream_t stream) {
  if (ws_size < WS_NEEDED) return;
  const float* x   = (const float*)d_in[0];
  const float* Wqkv= (const float*)d_in[1];
  const float* sln = (const float*)d_in[2];
  const float* dwcw= (const float*)d_in[3];
  const float* dwcb= (const float*)d_in[4];
  const float* Wa  = (const float*)d_in[5];
  const float* ba  = (const float*)d_in[6];
  const float* Wb  = (const float*)d_in[7];
  const float* bb  = (const float*)d_in[8];
  const float* Wc  = (const float*)d_in[9];
  const float* bc  = (const float*)d_in[10];
  const float* W1  = (const float*)d_in[11];
  const float* b1  = (const float*)d_in[12];
  const float* W2  = (const float*)d_in[13];
  const float* b2  = (const float*)d_in[14];
  const float* W3a = (const float*)d_in[15];
  const float* b3a = (const float*)d_in[16];
  const float* W3b = (const float*)d_in[17];
  const float* b3b = (const float*)d_in[18];
  const float* Wf  = (const float*)d_in[19];
  const float* bf  = (const float*)d_in[20];

  char* wsb = (char*)d_ws;
  unsigned short* VPH = (unsigned short*)(wsb + B_VPH);
  unsigned short* QLH = (unsigned short*)(wsb + B_QLH);
  unsigned short* KLH = (unsigned short*)(wsb + B_KLH);
  float* EB = (float*)(wsb + B_E);
  float* SM = (float*)(wsb + B_SM);
  unsigned short* XT = (unsigned short*)(wsb + B_X);
  float* outp = (float*)d_out;

  hipMemsetAsync((void*)SM, 0, ZEND * sizeof(float), stream);

  k_prep0<<<98, 256, 0, stream>>>(x, Wqkv, SM + QC, SM + KC, SM + VC,
                                  XT + XT_QCH, XT + XT_KCH, XT + XT_WQKV);
  k_prep1<<<564, 256, 0, stream>>>(SM + VC, Wa, Wb, ba, bb, Wf, bf,
                                   SM + VCA, SM + VCB, XT + XT_VCAT, XT + XT_VCBT,
                                   SM + WFA, SM + WFB, SM + BFA, SM + BFB,
                                   XT + XT_WFAT, XT + XT_WFBT);
  k_osc<<<1, 256, 0, stream>>>(SM + QC, SM + KC, SM + VC, SM + OSCB);
  k_gated<<<50, 256, 0, stream>>>(SM + OSCB, Wa, Wb, ba, bb, Wc, bc, SM + ASC);

  k_path1<<<4096, 256, 0, stream>>>(x, XT + XT_WQKV, sln, XT + XT_KCH, XT + XT_QCH,
                                    XT + XT_VCAT, XT + XT_VCBT, ba, bb, Wc, bc,
                                    VPH, QLH, KLH, EB, SM + W50P, SM + EDENP, SM + OCCDENP);
  k_occnum<<<256, 256, 0, stream>>>(EB, VPH, SM + OCCRAW);
  k_kv<<<dim3(4, 128), 256, 0, stream>>>(KLH, VPH, (unsigned short*)EB, SM + KLSUMP);
  k_fin2<<<307, 256, 0, stream>>>((const unsigned short*)EB, XT + XT_KVT,
                                  SM + OCCRAW, SM + OCCDENP, SM + OCCB,
                                  SM + KLSUMP, SM + KLSUMR);
  k_gated<<<50, 256, 0, stream>>>(SM + OCCB, Wa, Wb, ba, bb, Wc, bc, SM + ACC50);

  k_tail<<<4096, 256, 0, stream>>>(QLH, XT + XT_KVT, SM + KLSUMR, VPH, dwcw, dwcb,
                                   XT + XT_WFAT, XT + XT_WFBT, SM + BFA, SM + BFB,
                                   Wc, bc, SM + H2TP, SM + H2DENP);

  k_final<<<1, 256, 0, stream>>>(SM + ACC50, SM + OCCB, SM + ASC, SM + OSCB,
                                 SM + W50P, SM + EDENP, SM + H2TP, SM + H2DENP,
                                 SM + VC, Wf, bf, W1, b1, W2, b2, W3a, b3a, W3b, b3b, outp);
}

// Round 8
// 744.686 us; speedup vs baseline: 2.7081x; 1.3040x over previous
//
#include <hip/hip_runtime.h>
#include <math.h>

// MixedAttentionLayer — R8: fragment-major MFMA B layouts everywhere
// (WqkvT, qc/kc, VcaT/VcbT, WfaT/WfbT, kvT). Each wave B-load = 1KB
// contiguous. Structure otherwise identical to R7.

constexpr int DD = 256;
constexpr int MM = 50;
constexpr float SCL = 0.0625f; // 256^-0.5

// ---- byte offsets in d_ws ----
constexpr size_t B_VPH = 0;
constexpr size_t B_QLH = (size_t)32 << 20;
constexpr size_t B_KLH = (size_t)64 << 20;
constexpr size_t B_E   = (size_t)96 << 20;
constexpr size_t B_SM  = (size_t)112 << 20;
constexpr size_t B_X   = B_SM + ((size_t)2 << 20);

// ---- float offsets within SM region (zeroed part first) ----
constexpr size_t KLSUMR = 0;
constexpr size_t KLSUMP = 256;
constexpr size_t OCCDENP= 2304;
constexpr size_t W50P   = 2816;
constexpr size_t EDENP  = 3328;
constexpr size_t H2TP   = 3336;
constexpr size_t H2DENP = 5384;
constexpr size_t OCCRAW = 5392;
constexpr size_t ZEND   = 18192;
constexpr size_t QC     = ZEND;
constexpr size_t KC     = QC + 12800;
constexpr size_t VC     = KC + 12800;
constexpr size_t VCA    = VC + 12800;
constexpr size_t VCB    = VCA + 12800;
constexpr size_t WFA    = VCB + 12800;
constexpr size_t WFB    = WFA + 65536;
constexpr size_t BFA    = WFB + 65536;
constexpr size_t BFB    = BFA + 256;
constexpr size_t OSCB   = BFB + 256;
constexpr size_t OCCB   = OSCB + 12800;
constexpr size_t ASC    = OCCB + 12800;
constexpr size_t ACC50  = ASC + 64;
constexpr size_t SMEND  = ACC50 + 64;

// ---- short offsets within X region (all fragment-major now) ----
constexpr size_t XT_WQKV = 0;          // 48t x 8k0 x 64 x 8 = 196608
constexpr size_t XT_WFAT = 196608;     // 16 x 8 x 64 x 8 = 65536
constexpr size_t XT_WFBT = 262144;
constexpr size_t XT_KVT  = 327680;     // 16 x 8 x 64 x 8
constexpr size_t XT_QCH  = 393216;     // 4 x 8 x 64 x 8 = 16384
constexpr size_t XT_KCH  = 409600;
constexpr size_t XT_VCAT = 425984;     // 16 x 2 x 64 x 8 = 16384
constexpr size_t XT_VCBT = 442368;
constexpr size_t XT_END  = 458752;
constexpr size_t WS_NEEDED = B_X + XT_END * 2;

typedef short bf16x8 __attribute__((ext_vector_type(8)));
typedef float f32x4 __attribute__((ext_vector_type(4)));

__device__ __forceinline__ float sigmoidf_(float x){ return 1.0f / (1.0f + expf(-x)); }

__device__ __forceinline__ float bf2f(unsigned short u){
  return __uint_as_float(((unsigned int)u) << 16);
}
__device__ __forceinline__ unsigned short f2bf(float f){
  unsigned int x = __float_as_uint(f);
  unsigned int r = (x + 0x7fffu + ((x >> 16) & 1u)) >> 16;
  return (unsigned short)r;
}
__device__ __forceinline__ f32x4 mfma16(bf16x8 a, bf16x8 b, f32x4 c){
  return __builtin_amdgcn_mfma_f32_16x16x32_bf16(a, b, c, 0, 0, 0);
}

__device__ __forceinline__ float waveAllSum(float v){
  #pragma unroll
  for (int m = 1; m < 64; m <<= 1) v += __shfl_xor(v, m, 64);
  return v;
}

// fragment-major index helper: element (n, k) of a B matrix with K8 k0-tiles
// -> frag row ((tile(n)*K8 + k0)*64 + lane), byte elem e
__device__ __forceinline__ size_t fragIdx(int n, int k, int K8){
  const int tile = n >> 4, cn = n & 15;
  const int k0 = k >> 5, kqi = (k >> 3) & 3, e = k & 7;
  return (((size_t)tile * K8 + k0) * 64 + (kqi * 16 + cn)) * 8 + e;
}

// ---------- prep0: fragment-major Wqkv^T (blocks 0..47) + qc/kc/vc (48..97) ----------
__global__ void __launch_bounds__(256) k_prep0(const float* __restrict__ x, const float* __restrict__ Wqkv,
                                               float* qc, float* kc, float* vc,
                                               unsigned short* qch, unsigned short* kch,
                                               unsigned short* __restrict__ WT){
  const int b = blockIdx.x, t = threadIdx.x;
  if (b < 48) {
    __shared__ unsigned short Tt[64][72];
    const int bn = b % 12, bk = b / 12;
    const int n0 = bn * 64, k0g = bk * 64;
    #pragma unroll
    for (int i = 0; i < 16; i++) {
      const int k_l = (t >> 6) + i * 4;
      const int n_l = t & 63;
      Tt[n_l][k_l] = f2bf(Wqkv[(size_t)(k0g + k_l) * 768 + n0 + n_l]);
    }
    __syncthreads();
    // 512 fragment-rows (4 t_l x 2 k0_l x 64 lanes), 2 per thread, 16B each
    #pragma unroll
    for (int i = 0; i < 2; i++) {
      const int fr = t * 2 + i;
      const int t_l = fr >> 7;
      const int k0_l = (fr >> 6) & 1;
      const int lane_f = fr & 63;
      const int n_l = t_l * 16 + (lane_f & 15);
      const int k_l = k0_l * 32 + (lane_f >> 4) * 8;
      const int tg = (n0 >> 4) + t_l;
      const int k0gl = (k0g >> 5) + k0_l;
      bf16x8 v = *(const bf16x8*)&Tt[n_l][k_l];
      *(bf16x8*)&WT[(((size_t)tg * 8 + k0gl) * 64 + lane_f) * 8] = v;
    }
    return;
  }
  __shared__ float xs[256];
  const int r = b - 48, j = t;
  xs[j] = x[r * DD + j];
  __syncthreads();
  float aq = 0.f, ak = 0.f, av = 0.f;
  for (int k = 0; k < DD; k++) {
    float xv = xs[k];
    aq += xv * Wqkv[k * 768 + j];
    ak += xv * Wqkv[k * 768 + 256 + j];
    av += xv * Wqkv[k * 768 + 512 + j];
  }
  qc[r * DD + j] = aq; kc[r * DD + j] = ak; vc[r * DD + j] = av;
  qch[fragIdx(r, j, 8)] = f2bf(aq);
  kch[fragIdx(r, j, 8)] = f2bf(ak);
  if (r == 0) {
    for (int c = 50; c < 64; c++) {
      qch[fragIdx(c, j, 8)] = 0;
      kch[fragIdx(c, j, 8)] = 0;
    }
  }
}

// ---------- prep1: Vca/Vcb (0..49) + Wfa/Wfb/bfa/bfb (50..563), fragment-major bf16 ----------
__global__ void __launch_bounds__(256) k_prep1(const float* vc, const float* Wa, const float* Wb,
                                               const float* ba, const float* bb,
                                               const float* Wf, const float* bf,
                                               float* Vca, float* Vcb,
                                               unsigned short* VcaTh, unsigned short* VcbTh,
                                               float* Wfa, float* Wfb, float* bfa, float* bfb,
                                               unsigned short* WfaTh, unsigned short* WfbTh){
  __shared__ float rs[256];
  const int b = blockIdx.x, j = threadIdx.x;
  if (b < 50) {
    const int r = b;
    rs[j] = vc[r * DD + j];
    __syncthreads();
    float a = 0.f, bv = 0.f;
    for (int k = 0; k < DD; k++) { float v = rs[k]; a += v * Wa[k * DD + j]; bv += v * Wb[k * DD + j]; }
    Vca[r * DD + j] = a; Vcb[r * DD + j] = bv;
    // element (n=j, k=r), K=64 -> K8=2
    VcaTh[fragIdx(j, r, 2)] = f2bf(a);
    VcbTh[fragIdx(j, r, 2)] = f2bf(bv);
    if (r == 0) {
      for (int c = 50; c < 64; c++) {
        VcaTh[fragIdx(j, c, 2)] = 0;
        VcbTh[fragIdx(j, c, 2)] = 0;
      }
    }
    return;
  }
  const int bb2 = b - 50;
  const float* src; const float* Wm;
  if (bb2 < 256)      { src = Wf + bb2 * DD;         Wm = Wa; }
  else if (bb2 < 512) { src = Wf + (bb2 - 256) * DD; Wm = Wb; }
  else if (bb2 == 512){ src = bf;                    Wm = Wa; }
  else                { src = bf;                    Wm = Wb; }
  rs[j] = src[j];
  __syncthreads();
  float a = 0.f;
  for (int k = 0; k < DD; k++) a += rs[k] * Wm[k * DD + j];
  if (bb2 < 256)      { Wfa[bb2 * DD + j] = a; WfaTh[fragIdx(j, bb2, 8)] = f2bf(a); }
  else if (bb2 < 512) { Wfb[(bb2 - 256) * DD + j] = a; WfbTh[fragIdx(j, bb2 - 256, 8)] = f2bf(a); }
  else if (bb2 == 512) bfa[j] = a + ba[j];
  else bfb[j] = a + bb[j];
}

// ---------- osc = softmax(scale*qc@kc^T)@vc ----------
__global__ void __launch_bounds__(256) k_osc(const float* qc, const float* kc, const float* vc, float* osc){
  __shared__ float S[50][64];
  __shared__ float P[50][64];
  int t = threadIdx.x;
  for (int p = t; p < 2500; p += 256) {
    int i = p / 50, jj = p % 50;
    float s = 0.f;
    for (int k = 0; k < DD; k++) s += qc[i * DD + k] * kc[jj * DD + k];
    S[i][jj] = s * SCL;
  }
  __syncthreads();
  if (t < 50) {
    float mx = -1e30f;
    for (int jj = 0; jj < 50; jj++) mx = fmaxf(mx, S[t][jj]);
    float den = 0.f;
    for (int jj = 0; jj < 50; jj++) { float e = expf(S[t][jj] - mx); P[t][jj] = e; den += e; }
    float inv = 1.0f / den;
    for (int jj = 0; jj < 50; jj++) P[t][jj] *= inv;
  }
  __syncthreads();
  for (int i = 0; i < 50; i++) {
    float a = 0.f;
    for (int jj = 0; jj < 50; jj++) a += P[i][jj] * vc[jj * DD + t];
    osc[i * DD + t] = a;
  }
}

// ---------- gated() on 50 rows ----------
__global__ void __launch_bounds__(256) k_gated(const float* __restrict__ tin,
                                               const float* __restrict__ Wa, const float* __restrict__ Wb,
                                               const float* __restrict__ ba, const float* __restrict__ bb,
                                               const float* __restrict__ Wc, const float* __restrict__ bc,
                                               float* __restrict__ A){
  int r = blockIdx.x, j = threadIdx.x;
  __shared__ float ts[256];
  __shared__ float red[4];
  ts[j] = tin[r * DD + j];
  __syncthreads();
  float u = 0.f, v = 0.f;
  for (int k = 0; k < DD; k++) { float tv = ts[k]; u += tv * Wa[k * DD + j]; v += tv * Wb[k * DD + j]; }
  float g = tanhf(u + ba[j]) * sigmoidf_(v + bb[j]) * Wc[j];
  g = waveAllSum(g);
  int lane = j & 63, wv = j >> 6;
  if (lane == 0) red[wv] = g;
  __syncthreads();
  if (j == 0) A[r] = red[0] + red[1] + red[2] + red[3] + bc[0];
}

// ---------- fused path kernel ----------
__global__ void __launch_bounds__(256) k_path1(
    const float* __restrict__ x, const unsigned short* __restrict__ WTf,
    const float* __restrict__ sln,
    const unsigned short* __restrict__ kchf, const unsigned short* __restrict__ qchf,
    const unsigned short* __restrict__ VcaTf, const unsigned short* __restrict__ VcbTf,
    const float* __restrict__ ba, const float* __restrict__ bb,
    const float* __restrict__ Wc, const float* __restrict__ bc,
    unsigned short* __restrict__ vph, unsigned short* __restrict__ qlh, unsigned short* __restrict__ klh,
    float* __restrict__ E, float* __restrict__ w50p, float* __restrict__ edenp, float* __restrict__ occdenp){
  __shared__ unsigned short xsh[16][264];
  __shared__ unsigned short qpsb[16][264];
  __shared__ unsigned short kpsb[16][264];
  __shared__ float scap[16][68];
  __shared__ float scac[16][68];
  __shared__ unsigned short Psh[16][72];
  __shared__ float occs[64];
  __shared__ float evp[16];
  const int tid = threadIdx.x;
  const int i0 = blockIdx.x * 16;
  const int part = blockIdx.x & 7;
  const int lane = tid & 63;
  const int wvv = tid >> 6;
  const int cn = lane & 15;
  const int m0 = (lane >> 4) * 4;
  const int kq = (lane >> 4) * 8;

  if (tid < 64) occs[tid] = 0.f;
  for (int l = tid; l < 4096; l += 256) {
    int r = l >> 8, c = l & 255;
    xsh[r][c] = f2bf(x[(size_t)(MM + i0 + r) * DD + c]);
  }
  __syncthreads();

  // ---- GEMM: [16 x 256] @ [256 x 768], fragment-major B, double-buffered ----
  bf16x8 af[8];
  #pragma unroll
  for (int k0 = 0; k0 < 8; k0++)
    af[k0] = *(const bf16x8*)&xsh[cn][k0 * 32 + kq];
  bf16x8 b0[8], b1[8];
  {
    const unsigned short* Bt = WTf + ((size_t)wvv * 8 * 64 + lane) * 8;
    #pragma unroll
    for (int k0 = 0; k0 < 8; k0++) b0[k0] = *(const bf16x8*)&Bt[(size_t)k0 * 512];
  }
  #pragma unroll 1
  for (int tt = 0; tt < 12; tt++) {
    const int t = wvv + 4 * tt;
    if (tt + 1 < 12) {
      const unsigned short* Bt = WTf + (((size_t)(t + 4) * 8) * 64 + lane) * 8;
      #pragma unroll
      for (int k0 = 0; k0 < 8; k0++) b1[k0] = *(const bf16x8*)&Bt[(size_t)k0 * 512];
    }
    f32x4 acc = {0.f, 0.f, 0.f, 0.f};
    #pragma unroll
    for (int k0 = 0; k0 < 8; k0++) acc = mfma16(af[k0], b0[k0], acc);
    if (t < 16) {
      int c = t * 16 + cn;
      #pragma unroll
      for (int i = 0; i < 4; i++) qpsb[m0 + i][c] = f2bf(acc[i]);
    } else if (t < 32) {
      int c = (t - 16) * 16 + cn;
      #pragma unroll
      for (int i = 0; i < 4; i++) kpsb[m0 + i][c] = f2bf(acc[i]);
    } else {
      int c = (t - 32) * 16 + cn;
      #pragma unroll
      for (int i = 0; i < 4; i++) vph[(size_t)(i0 + m0 + i) * DD + c] = f2bf(acc[i]);
    }
    #pragma unroll
    for (int k0 = 0; k0 < 8; k0++) b0[k0] = b1[k0];
  }
  __syncthreads();

  // ---- scores via MFMA (fragment-major B) ----
  {
    f32x4 accp = {0.f,0.f,0.f,0.f}, accc = {0.f,0.f,0.f,0.f};
    const unsigned short* Bk = kchf + (((size_t)wvv * 8) * 64 + lane) * 8;
    const unsigned short* Bq = qchf + (((size_t)wvv * 8) * 64 + lane) * 8;
    #pragma unroll
    for (int k0 = 0; k0 < 8; k0++) {
      bf16x8 aq = *(const bf16x8*)&qpsb[cn][k0 * 32 + kq];
      bf16x8 ak = *(const bf16x8*)&kpsb[cn][k0 * 32 + kq];
      bf16x8 bk = *(const bf16x8*)&Bk[(size_t)k0 * 512];
      bf16x8 bq = *(const bf16x8*)&Bq[(size_t)k0 * 512];
      accp = mfma16(aq, bk, accp);
      accc = mfma16(ak, bq, accc);
    }
    const int n0 = wvv * 16;
    #pragma unroll
    for (int i = 0; i < 4; i++) {
      scap[m0 + i][n0 + cn] = accp[i];
      scac[m0 + i][n0 + cn] = accc[i];
    }
  }
  __syncthreads();

  // ---- phase B: transforms + softmax p ----
  float4 sl4 = ((const float4*)sln)[lane];
  float4 rsp;
  rsp.x = 1.0f / log1pf(expf(sl4.x)); rsp.y = 1.0f / log1pf(expf(sl4.y));
  rsp.z = 1.0f / log1pf(expf(sl4.z)); rsp.w = 1.0f / log1pf(expf(sl4.w));
  float4 ba4 = ((const float4*)ba)[lane];
  float4 bb4 = ((const float4*)bb)[lane];
  float4 wc4 = ((const float4*)Wc)[lane];
  float bcv = bc[0];
  float occacc = 0.f;
  for (int rr = 0; rr < 4; rr++) {
    const int r = wvv * 4 + rr;
    const int row = i0 + r;
    ushort4 qu = *(const ushort4*)&qpsb[r][lane * 4];
    ushort4 ku = *(const ushort4*)&kpsb[r][lane * 4];
    float4 q4 = {bf2f(qu.x), bf2f(qu.y), bf2f(qu.z), bf2f(qu.w)};
    float4 k4 = {bf2f(ku.x), bf2f(ku.y), bf2f(ku.z), bf2f(ku.w)};
    float4 lq, lk;
    lq.x = (fmaxf(q4.x, 0.f) + 1e-6f) * rsp.x; lq.y = (fmaxf(q4.y, 0.f) + 1e-6f) * rsp.y;
    lq.z = (fmaxf(q4.z, 0.f) + 1e-6f) * rsp.z; lq.w = (fmaxf(q4.w, 0.f) + 1e-6f) * rsp.w;
    lk.x = (fmaxf(k4.x, 0.f) + 1e-6f) * rsp.x; lk.y = (fmaxf(k4.y, 0.f) + 1e-6f) * rsp.y;
    lk.z = (fmaxf(k4.z, 0.f) + 1e-6f) * rsp.z; lk.w = (fmaxf(k4.w, 0.f) + 1e-6f) * rsp.w;
    float4 q3, k3;
    q3.x = lq.x*lq.x*lq.x; q3.y = lq.y*lq.y*lq.y; q3.z = lq.z*lq.z*lq.z; q3.w = lq.w*lq.w*lq.w;
    k3.x = lk.x*lk.x*lk.x; k3.y = lk.y*lk.y*lk.y; k3.z = lk.z*lk.z*lk.z; k3.w = lk.w*lk.w*lk.w;
    float n1q = lq.x*lq.x + lq.y*lq.y + lq.z*lq.z + lq.w*lq.w;
    float n3q = q3.x*q3.x + q3.y*q3.y + q3.z*q3.z + q3.w*q3.w;
    float n1k = lk.x*lk.x + lk.y*lk.y + lk.z*lk.z + lk.w*lk.w;
    float n3k = k3.x*k3.x + k3.y*k3.y + k3.z*k3.z + k3.w*k3.w;
    n1q = waveAllSum(n1q); n3q = waveAllSum(n3q);
    n1k = waveAllSum(n1k); n3k = waveAllSum(n3k);
    float fq = sqrtf(n1q / n3q);
    float fk = sqrtf(n1k / n3k);
    ushort4 qo, ko;
    qo.x = f2bf(q3.x * fq); qo.y = f2bf(q3.y * fq); qo.z = f2bf(q3.z * fq); qo.w = f2bf(q3.w * fq);
    ko.x = f2bf(k3.x * fk); ko.y = f2bf(k3.y * fk); ko.z = f2bf(k3.z * fk); ko.w = f2bf(k3.w * fk);
    *(ushort4*)&qlh[(size_t)row * DD + lane * 4] = qo;
    *(ushort4*)&klh[(size_t)row * DD + lane * 4] = ko;
    float ecap = (lane < 50) ? expf(scap[r][lane] * SCL) : 0.f;
    float ecac = (lane < 50) ? expf(scac[r][lane] * SCL) : 0.f;
    E[(size_t)row * 64 + lane] = ecac;
    occacc += ecac;
    float den = waveAllSum(ecap);
    Psh[r][lane] = f2bf(ecap / den);
  }
  atomicAdd(&occs[lane], occacc);
  __syncthreads();

  // ---- gate via MFMA: u = P@Vca, v = P@Vcb (fragment-major B, K8=2) ----
  {
    bf16x8 ap[2];
    #pragma unroll
    for (int k0 = 0; k0 < 2; k0++) ap[k0] = *(const bf16x8*)&Psh[cn][k0 * 32 + kq];
    #pragma unroll 1
    for (int tt = 0; tt < 4; tt++) {
      const int nt = wvv * 4 + tt;
      const unsigned short* Bu = VcaTf + (((size_t)nt * 2) * 64 + lane) * 8;
      const unsigned short* Bv = VcbTf + (((size_t)nt * 2) * 64 + lane) * 8;
      f32x4 au = {0.f,0.f,0.f,0.f}, av = {0.f,0.f,0.f,0.f};
      #pragma unroll
      for (int k0 = 0; k0 < 2; k0++) {
        bf16x8 bu = *(const bf16x8*)&Bu[(size_t)k0 * 512];
        bf16x8 bv = *(const bf16x8*)&Bv[(size_t)k0 * 512];
        au = mfma16(ap[k0], bu, au);
        av = mfma16(ap[k0], bv, av);
      }
      #pragma unroll
      for (int i = 0; i < 4; i++) {
        qpsb[m0 + i][nt * 16 + cn] = f2bf(au[i]);
        kpsb[m0 + i][nt * 16 + cn] = f2bf(av[i]);
      }
    }
  }
  __syncthreads();

  // ---- gate eval ----
  #pragma unroll
  for (int rr = 0; rr < 4; rr++) {
    const int r = wvv * 4 + rr;
    ushort4 uu = *(const ushort4*)&qpsb[r][lane * 4];
    ushort4 vv = *(const ushort4*)&kpsb[r][lane * 4];
    float g = tanhf(bf2f(uu.x) + ba4.x) * sigmoidf_(bf2f(vv.x) + bb4.x) * wc4.x
            + tanhf(bf2f(uu.y) + ba4.y) * sigmoidf_(bf2f(vv.y) + bb4.y) * wc4.y
            + tanhf(bf2f(uu.z) + ba4.z) * sigmoidf_(bf2f(vv.z) + bb4.z) * wc4.z
            + tanhf(bf2f(uu.w) + ba4.w) * sigmoidf_(bf2f(vv.w) + bb4.w) * wc4.w;
    g = waveAllSum(g);
    if (lane == 0) evp[r] = expf(g + bcv);
  }
  __syncthreads();
  if (tid < 64) {
    float s = 0.f;
    #pragma unroll
    for (int r = 0; r < 16; r++) s += evp[r] * bf2f(Psh[r][tid]);
    atomicAdd(&w50p[part * 64 + tid], s);
    if (tid < 50) atomicAdd(&occdenp[part * 64 + tid], occs[tid]);
  }
  if (tid == 0) {
    float es = 0.f;
    #pragma unroll
    for (int r = 0; r < 16; r++) es += evp[r];
    atomicAdd(&edenp[part], es);
  }
}

// ---------- occ numerator ----------
__global__ void __launch_bounds__(256) k_occnum(const float* __restrict__ E, const unsigned short* __restrict__ vph,
                                                float* __restrict__ occraw){
  int d = threadIdx.x;
  int j0 = blockIdx.x * 256;
  __shared__ float Es[32][64];
  float acc[52];
  #pragma unroll
  for (int i = 0; i < 52; i++) acc[i] = 0.f;
  for (int s = 0; s < 8; s++) {
    for (int l = threadIdx.x; l < 512; l += 256) {
      int jj = l >> 4, cq = l & 15;
      *(float4*)&Es[jj][cq * 4] = ((const float4*)(E + (size_t)(j0 + s * 32 + jj) * 64))[cq];
    }
    __syncthreads();
    for (int jj = 0; jj < 32; jj++) {
      float vv = bf2f(vph[(size_t)(j0 + s * 32 + jj) * DD + d]);
      #pragma unroll
      for (int q = 0; q < 13; q++) {
        float4 e4 = *(const float4*)&Es[jj][q * 4];
        acc[q * 4 + 0] += e4.x * vv; acc[q * 4 + 1] += e4.y * vv;
        acc[q * 4 + 2] += e4.z * vv; acc[q * 4 + 3] += e4.w * vv;
      }
    }
    __syncthreads();
  }
  for (int i = 0; i < 50; i++) atomicAdd(&occraw[i * DD + d], acc[i]);
}

// ---------- kv = kl^T @ vp: LDS-staged MFMA, 4 c-bands x 128 z-chunks ----------
__global__ void __launch_bounds__(256) k_kv(const unsigned short* __restrict__ klh,
                                            const unsigned short* __restrict__ vph,
                                            unsigned short* __restrict__ PP,
                                            float* __restrict__ klsump){
  __shared__ unsigned short Akl[32][72];
  __shared__ unsigned short Bvp[32][264];
  const int tid = threadIdx.x;
  const int lane = tid & 63;
  const int wvv = tid >> 6;
  const int cn = lane & 15;
  const int m0 = (lane >> 4) * 4;
  const int kq = (lane >> 4) * 8;
  const int cb = blockIdx.x;
  const int z  = blockIdx.y;
  const int jj = tid >> 3;
  const int c8 = (tid & 7) * 8;

  f32x4 acc[4][4];
  f32x4 acc1[4];
  #pragma unroll
  for (int mt = 0; mt < 4; mt++) {
    acc1[mt] = (f32x4){0.f,0.f,0.f,0.f};
    #pragma unroll
    for (int tl = 0; tl < 4; tl++) acc[mt][tl] = (f32x4){0.f,0.f,0.f,0.f};
  }
  bf16x8 ones;
  #pragma unroll
  for (int i = 0; i < 8; i++) ones[i] = (short)0x3F80;

  const int jbase = z * 512;
  #pragma unroll 1
  for (int step = 0; step < 16; step++) {
    const int j0 = jbase + step * 32;
    {
      bf16x8 av = *(const bf16x8*)&klh[(size_t)(j0 + jj) * 256 + cb * 64 + c8];
      *(bf16x8*)&Akl[jj][c8] = av;
      #pragma unroll
      for (int rep = 0; rep < 4; rep++) {
        bf16x8 bv = *(const bf16x8*)&vph[(size_t)(j0 + jj) * 256 + rep * 64 + c8];
        *(bf16x8*)&Bvp[jj][rep * 64 + c8] = bv;
      }
    }
    __syncthreads();
    bf16x8 afr[4], bfr[4];
    #pragma unroll
    for (int mt = 0; mt < 4; mt++) {
      #pragma unroll
      for (int e = 0; e < 8; e++) afr[mt][e] = (short)Akl[kq + e][cn + mt * 16];
    }
    #pragma unroll
    for (int tl = 0; tl < 4; tl++) {
      #pragma unroll
      for (int e = 0; e < 8; e++) bfr[tl][e] = (short)Bvp[kq + e][wvv * 64 + tl * 16 + cn];
    }
    #pragma unroll
    for (int mt = 0; mt < 4; mt++) {
      acc1[mt] = mfma16(afr[mt], ones, acc1[mt]);
      #pragma unroll
      for (int tl = 0; tl < 4; tl++) acc[mt][tl] = mfma16(afr[mt], bfr[tl], acc[mt][tl]);
    }
    __syncthreads();
  }
  unsigned short* P = PP + ((size_t)(cb * 128 + z)) * 16384;
  #pragma unroll
  for (int mt = 0; mt < 4; mt++)
    #pragma unroll
    for (int tl = 0; tl < 4; tl++) {
      const int n = (wvv * 4 + tl) * 16 + cn;
      #pragma unroll
      for (int i = 0; i < 4; i++)
        P[(size_t)(mt * 16 + m0 + i) * 256 + n] = f2bf(acc[mt][tl][i]);
    }
  if (wvv == 0 && cn == 0) {
    #pragma unroll
    for (int mt = 0; mt < 4; mt++)
      #pragma unroll
      for (int i = 0; i < 4; i++)
        atomicAdd(&klsump[(z & 7) * 256 + cb * 64 + mt * 16 + m0 + i], acc1[mt][i]);
  }
}

// ---------- merged: kvred (0..255) + occfin (256..305) + klsum reduce (306) ----------
__global__ void __launch_bounds__(256) k_fin2(const unsigned short* __restrict__ PP,
                                              unsigned short* __restrict__ kvTf,
                                              const float* __restrict__ occraw,
                                              const float* __restrict__ occdenp,
                                              float* __restrict__ occ,
                                              const float* __restrict__ klsump,
                                              float* __restrict__ klsum){
  const int b = blockIdx.x, d = threadIdx.x;
  if (b < 256) {
    const int cb = b >> 6, m = b & 63;
    float s = 0.f;
    for (int z = 0; z < 128; z++)
      s += bf2f(PP[((size_t)(cb * 128 + z)) * 16384 + (size_t)m * 256 + d]);
    // kv^T element (n=d, k=c=b), fragment-major K8=8
    kvTf[fragIdx(d, b, 8)] = f2bf(s);
  } else if (b < 306) {
    const int i = b - 256;
    float den = 0.f;
    #pragma unroll
    for (int p = 0; p < 8; p++) den += occdenp[p * 64 + i];
    occ[i * DD + d] = occraw[i * DD + d] / den;
  } else {
    float s = 0.f;
    #pragma unroll
    for (int p = 0; p < 8; p++) s += klsump[p * 256 + d];
    klsum[d] = s;
  }
}

// ---------- fused tail ----------
__global__ void __launch_bounds__(256) k_tail(const unsigned short* __restrict__ qlh,
                                              const unsigned short* __restrict__ kvTf,
                                              const float* __restrict__ klsum,
                                              const unsigned short* __restrict__ vph,
                                              const float* __restrict__ dwcw, const float* __restrict__ dwcb,
                                              const unsigned short* __restrict__ WfaTf,
                                              const unsigned short* __restrict__ WfbTf,
                                              const float* __restrict__ bfa, const float* __restrict__ bfb,
                                              const float* __restrict__ Wc, const float* __restrict__ bc,
                                              float* __restrict__ h2tp, float* __restrict__ h2denp){
  __shared__ unsigned short Tsh[16][264];
  __shared__ unsigned short OSb[16][264];
  __shared__ unsigned short aVb[16][264];
  __shared__ float zf[16];
  __shared__ float ev[16];
  const int tid = threadIdx.x;
  const int i0 = blockIdx.x * 16;
  const int part = blockIdx.x & 7;
  const int lane = tid & 63;
  const int wvv = tid >> 6;
  const int cn = lane & 15;
  const int m0 = (lane >> 4) * 4;
  const int kq = (lane >> 4) * 8;
  for (int l = tid; l < 1024; l += 256) {
    int r = l >> 6, c4 = (l & 63) * 4;
    *(ushort4*)&Tsh[r][c4] = *(const ushort4*)&qlh[(size_t)(i0 + r) * DD + c4];
  }
  __syncthreads();
  {
    bf16x8 afq[8];
    #pragma unroll
    for (int k0 = 0; k0 < 8; k0++) afq[k0] = *(const bf16x8*)&Tsh[cn][k0 * 32 + kq];
    #pragma unroll 1
    for (int tt = 0; tt < 4; tt++) {
      const int nt = wvv * 4 + tt;
      const unsigned short* Bt = kvTf + (((size_t)nt * 8) * 64 + lane) * 8;
      f32x4 acc = {0.f,0.f,0.f,0.f};
      #pragma unroll
      for (int k0 = 0; k0 < 8; k0++) {
        bf16x8 b = *(const bf16x8*)&Bt[(size_t)k0 * 512];
        acc = mfma16(afq[k0], b, acc);
      }
      #pragma unroll
      for (int i = 0; i < 4; i++) OSb[m0 + i][nt * 16 + cn] = f2bf(acc[i]);
    }
  }
  {
    float4 ks4 = ((const float4*)klsum)[lane];
    #pragma unroll
    for (int rr = 0; rr < 4; rr++) {
      const int r = wvv * 4 + rr;
      ushort4 q4 = *(const ushort4*)&Tsh[r][lane * 4];
      float s = bf2f(q4.x)*ks4.x + bf2f(q4.y)*ks4.y + bf2f(q4.z)*ks4.z + bf2f(q4.w)*ks4.w;
      s = waveAllSum(s);
      if (lane == 0) zf[r] = 1.0f / (s + 1e-6f);
    }
  }
  __syncthreads();
  const int j = tid;
  float w[25];
  #pragma unroll
  for (int t = 0; t < 25; t++) w[t] = dwcw[j * 25 + t];
  const float bias = dwcb[j];
  const int y = i0 >> 8, x0 = i0 & 255;
  float fm[16];
  #pragma unroll
  for (int r = 0; r < 16; r++) fm[r] = bias;
  #pragma unroll
  for (int dy = -2; dy <= 2; dy++) {
    const int yy = y + dy;
    if ((unsigned)yy > 255u) continue;
    float buf[20];
    #pragma unroll
    for (int i = 0; i < 20; i++) {
      const int xx = x0 - 2 + i;
      buf[i] = ((unsigned)xx <= 255u) ? bf2f(vph[(size_t)((yy << 8) + xx) * DD + j]) : 0.f;
    }
    const float* wr = &w[(dy + 2) * 5];
    #pragma unroll
    for (int r = 0; r < 16; r++)
      fm[r] += buf[r] * wr[0] + buf[r+1] * wr[1] + buf[r+2] * wr[2]
             + buf[r+3] * wr[3] + buf[r+4] * wr[4];
  }
  float Tf[16];
  #pragma unroll
  for (int r = 0; r < 16; r++) {
    Tf[r] = bf2f(OSb[r][j]) * zf[r] + fm[r];
    Tsh[r][j] = f2bf(Tf[r]);
  }
  __syncthreads();
  {
    bf16x8 aft[8];
    #pragma unroll
    for (int k0 = 0; k0 < 8; k0++) aft[k0] = *(const bf16x8*)&Tsh[cn][k0 * 32 + kq];
    #pragma unroll 1
    for (int jb = 0; jb < 8; jb++) {
      const int nt = wvv * 4 + (jb & 3);
      const unsigned short* Bt = ((jb < 4) ? WfaTf : WfbTf) + (((size_t)nt * 8) * 64 + lane) * 8;
      f32x4 acc = {0.f,0.f,0.f,0.f};
      #pragma unroll
      for (int k0 = 0; k0 < 8; k0++) {
        bf16x8 b = *(const bf16x8*)&Bt[(size_t)k0 * 512];
        acc = mfma16(aft[k0], b, acc);
      }
      unsigned short (*dst)[264] = (jb < 4) ? OSb : aVb;
      #pragma unroll
      for (int i = 0; i < 4; i++) dst[m0 + i][nt * 16 + cn] = f2bf(acc[i]);
    }
  }
  __syncthreads();
  {
    float4 bfa4 = ((const float4*)bfa)[lane];
    float4 bfb4 = ((const float4*)bfb)[lane];
    float4 wc4 = ((const float4*)Wc)[lane];
    const float bcv = bc[0];
    #pragma unroll
    for (int rr = 0; rr < 4; rr++) {
      const int r = wvv * 4 + rr;
      ushort4 uu = *(const ushort4*)&OSb[r][lane * 4];
      ushort4 vv = *(const ushort4*)&aVb[r][lane * 4];
      float g = tanhf(bf2f(uu.x) + bfa4.x) * sigmoidf_(bf2f(vv.x) + bfb4.x) * wc4.x
              + tanhf(bf2f(uu.y) + bfa4.y) * sigmoidf_(bf2f(vv.y) + bfb4.y) * wc4.y
              + tanhf(bf2f(uu.z) + bfa4.z) * sigmoidf_(bf2f(vv.z) + bfb4.z) * wc4.z
              + tanhf(bf2f(uu.w) + bfa4.w) * sigmoidf_(bf2f(vv.w) + bfb4.w) * wc4.w;
      g = waveAllSum(g);
      if (lane == 0) ev[r] = expf(g + bcv);
    }
  }
  __syncthreads();
  float hp = 0.f;
  #pragma unroll
  for (int r = 0; r < 16; r++) hp += ev[r] * Tf[r];
  atomicAdd(&h2tp[part * 256 + j], hp);
  if (tid == 0) {
    float es = 0.f;
    #pragma unroll
    for (int r = 0; r < 16; r++) es += ev[r];
    atomicAdd(&h2denp[part], es);
  }
}

// ---------- final tiny MLPs ----------
__global__ void __launch_bounds__(256) k_final(
    const float* __restrict__ A_cc, const float* __restrict__ occ,
    const float* __restrict__ A_sc, const float* __restrict__ osc,
    const float* __restrict__ w50p, const float* __restrict__ edenp,
    const float* __restrict__ h2tp, const float* __restrict__ h2denp,
    const float* __restrict__ vc, const float* __restrict__ Wf, const float* __restrict__ bf,
    const float* __restrict__ W1, const float* __restrict__ b1,
    const float* __restrict__ W2, const float* __restrict__ b2,
    const float* __restrict__ W3a, const float* __restrict__ b3a,
    const float* __restrict__ W3b, const float* __restrict__ b3b,
    float* __restrict__ out){
  int j = threadIdx.x;
  __shared__ float pw[64];
  __shared__ float w50t[64];
  __shared__ float t1[256], t2[256], h1[256], h2[256], fz[512], z1[256];
  if (j < 64) {
    float s = 0.f;
    #pragma unroll
    for (int p = 0; p < 8; p++) s += w50p[p * 64 + j];
    w50t[j] = s;
  }
  float edentot = 0.f, h2dentot = 0.f;
  #pragma unroll
  for (int p = 0; p < 8; p++) { edentot += edenp[p]; h2dentot += h2denp[p]; }
  // ===== CROSS =====
  if (j < 64) pw[j] = (j < 50) ? expf(A_cc[j]) : 0.f;
  __syncthreads();
  float den = 0.f;
  for (int i = 0; i < 50; i++) den += pw[i];
  float raw = 0.f;
  for (int i = 0; i < 50; i++) raw += pw[i] * occ[i * DD + j];
  t1[j] = raw / den;
  float r2 = 0.f;
  for (int i = 0; i < 50; i++) r2 += w50t[i] * vc[i * DD + j];
  t2[j] = r2 / edentot;
  __syncthreads();
  float a1 = 0.f, a2 = 0.f;
  for (int k = 0; k < DD; k++) { a1 += t1[k] * W1[k * DD + j]; a2 += t2[k] * W2[k * DD + j]; }
  h1[j] = fmaxf(a1 + b1[j], 0.f);
  h2[j] = fmaxf(a2 + b2[j], 0.f);
  __syncthreads();
  fz[j] = h1[j]; fz[256 + j] = h2[j];
  __syncthreads();
  float z = 0.f;
  for (int k = 0; k < 512; k++) z += fz[k] * W3a[k * DD + j];
  z1[j] = fmaxf(z + b3a[j], 0.f);
  __syncthreads();
  float o = 0.f;
  for (int k = 0; k < DD; k++) o += z1[k] * W3b[k * DD + j];
  out[j] = fmaxf(o + b3b[j], 0.f);
  __syncthreads();
  // ===== SELF =====
  if (j < 64) pw[j] = (j < 50) ? expf(A_sc[j]) : 0.f;
  __syncthreads();
  den = 0.f;
  for (int i = 0; i < 50; i++) den += pw[i];
  raw = 0.f;
  for (int i = 0; i < 50; i++) raw += pw[i] * osc[i * DD + j];
  t1[j] = raw / den;
  {
    float s = 0.f;
    #pragma unroll
    for (int p = 0; p < 8; p++) s += h2tp[p * 256 + j];
    t2[j] = s / h2dentot;
  }
  __syncthreads();
  float hs = 0.f;
  for (int k = 0; k < DD; k++) hs += t2[k] * Wf[k * DD + j];
  __syncthreads();
  t2[j] = hs + bf[j];
  __syncthreads();
  a1 = 0.f; a2 = 0.f;
  for (int k = 0; k < DD; k++) { a1 += t1[k] * W1[k * DD + j]; a2 += t2[k] * W2[k * DD + j]; }
  h1[j] = fmaxf(a1 + b1[j], 0.f);
  h2[j] = fmaxf(a2 + b2[j], 0.f);
  __syncthreads();
  fz[j] = h1[j]; fz[256 + j] = h2[j];
  __syncthreads();
  z = 0.f;
  for (int k = 0; k < 512; k++) z += fz[k] * W3a[k * DD + j];
  z1[j] = fmaxf(z + b3a[j], 0.f);
  __syncthreads();
  o = 0.f;
  for (int k = 0; k < DD; k++) o += z1[k] * W3b[k * DD + j];
  out[256 + j] = fmaxf(o + b3b[j], 0.f);
}

extern "C" void kernel_launch(void* const* d_in, const int* in_sizes, int n_in,
                              void* d_out, int out_size, void* d_ws, size_t ws_size,
                              hipStream_t stream) {
  if (ws_size < WS_NEEDED) return;
  const float* x   = (const float*)d_in[0];
  const float* Wqkv= (const float*)d_in[1];
  const float* sln = (const float*)d_in[2];
  const float* dwcw= (const float*)d_in[3];
  const float* dwcb= (const float*)d_in[4];
  const float* Wa  = (const float*)d_in[5];
  const float* ba  = (const float*)d_in[6];
  const float* Wb  = (const float*)d_in[7];
  const float* bb  = (const float*)d_in[8];
  const float* Wc  = (const float*)d_in[9];
  const float* bc  = (const float*)d_in[10];
  const float* W1  = (const float*)d_in[11];
  const float* b1  = (const float*)d_in[12];
  const float* W2  = (const float*)d_in[13];
  const float* b2  = (const float*)d_in[14];
  const float* W3a = (const float*)d_in[15];
  const float* b3a = (const float*)d_in[16];
  const float* W3b = (const float*)d_in[17];
  const float* b3b = (const float*)d_in[18];
  const float* Wf  = (const float*)d_in[19];
  const float* bf  = (const float*)d_in[20];

  char* wsb = (char*)d_ws;
  unsigned short* VPH = (unsigned short*)(wsb + B_VPH);
  unsigned short* QLH = (unsigned short*)(wsb + B_QLH);
  unsigned short* KLH = (unsigned short*)(wsb + B_KLH);
  float* EB = (float*)(wsb + B_E);
  float* SM = (float*)(wsb + B_SM);
  unsigned short* XT = (unsigned short*)(wsb + B_X);
  float* outp = (float*)d_out;

  hipMemsetAsync((void*)SM, 0, ZEND * sizeof(float), stream);

  k_prep0<<<98, 256, 0, stream>>>(x, Wqkv, SM + QC, SM + KC, SM + VC,
                                  XT + XT_QCH, XT + XT_KCH, XT + XT_WQKV);
  k_prep1<<<564, 256, 0, stream>>>(SM + VC, Wa, Wb, ba, bb, Wf, bf,
                                   SM + VCA, SM + VCB, XT + XT_VCAT, XT + XT_VCBT,
                                   SM + WFA, SM + WFB, SM + BFA, SM + BFB,
                                   XT + XT_WFAT, XT + XT_WFBT);
  k_osc<<<1, 256, 0, stream>>>(SM + QC, SM + KC, SM + VC, SM + OSCB);
  k_gated<<<50, 256, 0, stream>>>(SM + OSCB, Wa, Wb, ba, bb, Wc, bc, SM + ASC);

  k_path1<<<4096, 256, 0, stream>>>(x, XT + XT_WQKV, sln, XT + XT_KCH, XT + XT_QCH,
                                    XT + XT_VCAT, XT + XT_VCBT, ba, bb, Wc, bc,
                                    VPH, QLH, KLH, EB, SM + W50P, SM + EDENP, SM + OCCDENP);
  k_occnum<<<256, 256, 0, stream>>>(EB, VPH, SM + OCCRAW);
  k_kv<<<dim3(4, 128), 256, 0, stream>>>(KLH, VPH, (unsigned short*)EB, SM + KLSUMP);
  k_fin2<<<307, 256, 0, stream>>>((const unsigned short*)EB, XT + XT_KVT,
                                  SM + OCCRAW, SM + OCCDENP, SM + OCCB,
                                  SM + KLSUMP, SM + KLSUMR);
  k_gated<<<50, 256, 0, stream>>>(SM + OCCB, Wa, Wb, ba, bb, Wc, bc, SM + ACC50);

  k_tail<<<4096, 256, 0, stream>>>(QLH, XT + XT_KVT, SM + KLSUMR, VPH, dwcw, dwcb,
                                   XT + XT_WFAT, XT + XT_WFBT, SM + BFA, SM + BFB,
                                   Wc, bc, SM + H2TP, SM + H2DENP);

  k_final<<<1, 256, 0, stream>>>(SM + ACC50, SM + OCCB, SM + ASC, SM + OSCB,
                                 SM + W50P, SM + EDENP, SM + H2TP, SM + H2DENP,
                                 SM + VC, Wf, bf, W1, b1, W2, b2, W3a, b3a, W3b, b3b, outp);
}